// Round 30
// baseline (291.400 us; speedup 1.0000x reference)
//
#include <hip/hip_runtime.h>

#define B_  8
#define L_  2048
#define C_  512
#define R_  256
#define H_  8
#define DK_ 64
#define HD_ 512
#define MASK_NEG (-32767.0f)

typedef __attribute__((ext_vector_type(8))) short short8;
typedef __attribute__((ext_vector_type(8))) unsigned short ushort8;
typedef __attribute__((ext_vector_type(4))) unsigned short ushort4_t;
typedef __attribute__((ext_vector_type(4))) float f32x4;
typedef unsigned short u16;

__device__ inline u16 bf16_rne(float x) {
    unsigned u = __float_as_uint(x);
    return (u16)((u + 0x7FFFu + ((u >> 16) & 1u)) >> 16);
}
__device__ inline unsigned cvt_hl(float x) {
    u16 hh = bf16_rne(x);
    float hf = __uint_as_float(((unsigned)hh) << 16);
    u16 ll = bf16_rne(x - hf);
    return (unsigned)hh | ((unsigned)ll << 16);
}

struct Ptr3 { const void* p0; const void* p1; const void* p2; };

// async global->LDS, 16B per lane; LDS dest = wave-uniform base + lane*16
#define GLL16(g, l) __builtin_amdgcn_global_load_lds( \
    (const __attribute__((address_space(1))) void*)(g), \
    (__attribute__((address_space(3))) void*)(l), 16, 0, 0)

// ---------------- 64x64-tile MFMA plane GEMM (small/medium paths) ----------------
// XCD-swizzled (caller guarantees nwg%8==0).
// EPI: 0 = fp32 C; 2 = hi/lo planes; 3 = fp32 C + fp32 C^T; 4 = planes + transposed planes;
//      5 = transposed planes ONLY.
template<int BN, int AMODE, int BMODE, int EPI, bool TRIPLE, int NTERM = 3, int KSPLIT = 1>
__global__ __launch_bounds__(256) void gemm_pl(
    Ptr3 aH, Ptr3 aL, Ptr3 bH, Ptr3 bL, Ptr3 cH, Ptr3 cL,
    Ptr3 cT1, Ptr3 cT2, int ldct, long long csT,
    int K, int lda, int ldb, int ldc, int divz,
    long long ash, long long bsh, long long csh,
    long long asb, long long bsb, long long csb,
    long long ksa, long long ksb, long long ksc,
    float scale)
{
    constexpr int NF = BN / 32;
    constexpr int XA = (NTERM == 3) ? 64 : 1;
    constexpr int XB = (NTERM == 3) ? BN : 1;
    __shared__ u16 Ahs[64][40], Als[XA][40];
    __shared__ u16 Bhs[BN][40], Bls[XB][40];

    const int gx = gridDim.x, gy = gridDim.y;
    const int nwg = gx * gy * gridDim.z;
    int flat = blockIdx.x + gx * (blockIdx.y + gy * blockIdx.z);
    {
        int q = nwg >> 3;
        int xcd = flat & 7, idx = flat >> 3;
        flat = xcd * q + idx;
    }
    const int bx = flat % gx;
    const int by = (flat / gx) % gy;
    const int z  = flat / (gx * gy);

    const int zb = z / divz;
    const int rem = z - zb * divz;
    const int zh = rem / KSPLIT, ks = rem - zh * KSPLIT;
    const int Keff = K / KSPLIT;
    const void* avH = TRIPLE ? (zb == 0 ? aH.p0 : zb == 1 ? aH.p1 : aH.p2) : aH.p0;
    const void* avL = TRIPLE ? (zb == 0 ? aL.p0 : zb == 1 ? aL.p1 : aL.p2) : aL.p0;
    const void* bvH = TRIPLE ? (zb == 0 ? bH.p0 : zb == 1 ? bH.p1 : bH.p2) : bH.p0;
    const void* bvL = TRIPLE ? (zb == 0 ? bL.p0 : zb == 1 ? bL.p1 : bL.p2) : bL.p0;
    void* cvH = (void*)(TRIPLE ? (zb == 0 ? cH.p0 : zb == 1 ? cH.p1 : cH.p2) : cH.p0);
    void* cvL = (void*)(TRIPLE ? (zb == 0 ? cL.p0 : zb == 1 ? cL.p1 : cL.p2) : cL.p0);
    void* cvT1 = (void*)(TRIPLE ? (zb == 0 ? cT1.p0 : zb == 1 ? cT1.p1 : cT1.p2) : cT1.p0);
    void* cvT2 = (void*)(TRIPLE ? (zb == 0 ? cT2.p0 : zb == 1 ? cT2.p1 : cT2.p2) : cT2.p0);
    const long long ao = (TRIPLE ? 0 : (long long)zb * asb) + (long long)zh * ash + (long long)ks * ksa;
    const long long bo = (TRIPLE ? 0 : (long long)zb * bsb) + (long long)zh * bsh + (long long)ks * ksb;
    const long long co = (TRIPLE ? 0 : (long long)zb * csb) + (long long)zh * csh + (long long)ks * ksc;
    const long long coT = (long long)zh * csT;

    const u16*   AHg = (const u16*)avH + ao;
    const u16*   ALg = (const u16*)avL + ao;
    const u16*   BHg = (const u16*)bvH + bo;
    const u16*   BLg = (const u16*)bvL + bo;
    const float* Bfg = (const float*)bvH + bo;
    float* Cf  = (float*)cvH + co;
    u16*   CHg = (u16*)cvH + co;
    u16*   CLg = (u16*)cvL + co;

    const int m0 = by * 64, n0 = bx * BN;
    const int tid = threadIdx.x;
    const int lane = tid & 63, w = tid >> 6;
    const int wrow = (w >> 1) * 32, wcol = (w & 1) * (BN / 2);
    const int l15 = lane & 15, lg = lane >> 4;

    f32x4 zero = {0.f, 0.f, 0.f, 0.f};
    f32x4 acc[2][NF];
    #pragma unroll
    for (int mf = 0; mf < 2; ++mf)
        #pragma unroll
        for (int nf = 0; nf < NF; ++nf) acc[mf][nf] = zero;

    for (int k0 = 0; k0 < Keff; k0 += 32) {
        {
            int row = tid >> 2, kc = (tid & 3) << 3;
            long long off = (long long)(m0 + row) * lda + (k0 + kc);
            *(ushort8*)&Ahs[row][kc] = *(const ushort8*)(AHg + off);
            if constexpr (NTERM == 3)
                *(ushort8*)&Als[row][kc] = *(const ushort8*)(ALg + off);
        }
        if (BMODE == 0) {
            #pragma unroll
            for (int t = tid; t < BN * 4; t += 256) {
                int row = t >> 2, kc = (t & 3) << 3;
                long long off = (long long)(n0 + row) * ldb + (k0 + kc);
                *(ushort8*)&Bhs[row][kc] = *(const ushort8*)(BHg + off);
                if constexpr (NTERM == 3)
                    *(ushort8*)&Bls[row][kc] = *(const ushort8*)(BLg + off);
            }
        } else { // BMODE == 2: fp32 [N][K]
            #pragma unroll
            for (int t = tid; t < BN * 4; t += 256) {
                int row = t >> 2, kc = (t & 3) << 3;
                const float* s = Bfg + (long long)(n0 + row) * ldb + (k0 + kc);
                float4 v0 = *(const float4*)s, v1 = *(const float4*)(s + 4);
                unsigned p0 = cvt_hl(v0.x), p1 = cvt_hl(v0.y), p2 = cvt_hl(v0.z), p3 = cvt_hl(v0.w);
                unsigned p4 = cvt_hl(v1.x), p5 = cvt_hl(v1.y), p6 = cvt_hl(v1.z), p7 = cvt_hl(v1.w);
                ushort8 h, l;
                h[0]=(u16)p0; h[1]=(u16)p1; h[2]=(u16)p2; h[3]=(u16)p3;
                h[4]=(u16)p4; h[5]=(u16)p5; h[6]=(u16)p6; h[7]=(u16)p7;
                l[0]=(u16)(p0>>16); l[1]=(u16)(p1>>16); l[2]=(u16)(p2>>16); l[3]=(u16)(p3>>16);
                l[4]=(u16)(p4>>16); l[5]=(u16)(p5>>16); l[6]=(u16)(p6>>16); l[7]=(u16)(p7>>16);
                *(ushort8*)&Bhs[row][kc] = h;
                if constexpr (NTERM == 3)
                    *(ushort8*)&Bls[row][kc] = l;
            }
        }
        __syncthreads();

        short8 a_h[2], a_l[2];
        a_h[0] = *(const short8*)&Ahs[wrow +      l15][lg * 8];
        a_h[1] = *(const short8*)&Ahs[wrow + 16 + l15][lg * 8];
        if constexpr (NTERM == 3) {
            a_l[0] = *(const short8*)&Als[wrow +      l15][lg * 8];
            a_l[1] = *(const short8*)&Als[wrow + 16 + l15][lg * 8];
        }
        #pragma unroll
        for (int nf = 0; nf < NF; ++nf) {
            short8 b_h = *(const short8*)&Bhs[wcol + nf * 16 + l15][lg * 8];
            if constexpr (NTERM == 3) {
                short8 b_l = *(const short8*)&Bls[wcol + nf * 16 + l15][lg * 8];
                #pragma unroll
                for (int mf = 0; mf < 2; ++mf) {
                    acc[mf][nf] = __builtin_amdgcn_mfma_f32_16x16x32_bf16(a_h[mf], b_h, acc[mf][nf], 0, 0, 0);
                    acc[mf][nf] = __builtin_amdgcn_mfma_f32_16x16x32_bf16(a_h[mf], b_l, acc[mf][nf], 0, 0, 0);
                    acc[mf][nf] = __builtin_amdgcn_mfma_f32_16x16x32_bf16(a_l[mf], b_h, acc[mf][nf], 0, 0, 0);
                }
            } else {
                #pragma unroll
                for (int mf = 0; mf < 2; ++mf)
                    acc[mf][nf] = __builtin_amdgcn_mfma_f32_16x16x32_bf16(a_h[mf], b_h, acc[mf][nf], 0, 0, 0);
            }
        }
        __syncthreads();
    }

    #pragma unroll
    for (int mf = 0; mf < 2; ++mf)
        #pragma unroll
        for (int nf = 0; nf < NF; ++nf) {
            int row = m0 + wrow + mf * 16 + lg * 4;
            int col = n0 + wcol + nf * 16 + l15;
            if constexpr (EPI == 0 || EPI == 3) {
                #pragma unroll
                for (int j = 0; j < 4; ++j)
                    Cf[(long long)(row + j) * ldc + col] = acc[mf][nf][j] * scale;
                if constexpr (EPI == 3) {
                    float* CfT = (float*)cvT1 + coT;
                    float4 v = make_float4(acc[mf][nf][0] * scale, acc[mf][nf][1] * scale,
                                           acc[mf][nf][2] * scale, acc[mf][nf][3] * scale);
                    *(float4*)(CfT + (long long)col * ldct + row) = v;
                }
            } else {  // EPI 2, 4, 5: planes
                unsigned p[4];
                #pragma unroll
                for (int j = 0; j < 4; ++j) {
                    p[j] = cvt_hl(acc[mf][nf][j] * scale);
                    if constexpr (EPI != 5) {
                        CHg[(long long)(row + j) * ldc + col] = (u16)p[j];
                        CLg[(long long)(row + j) * ldc + col] = (u16)(p[j] >> 16);
                    }
                }
                if constexpr (EPI == 4 || EPI == 5) {
                    u16* CTH = (u16*)cvT1 + coT;
                    u16* CTL = (u16*)cvT2 + coT;
                    ushort4_t h, l;
                    #pragma unroll
                    for (int j = 0; j < 4; ++j) { h[j] = (u16)p[j]; l[j] = (u16)(p[j] >> 16); }
                    *(ushort4_t*)(CTH + (long long)col * ldct + row) = h;
                    *(ushort4_t*)(CTL + (long long)col * ldct + row) = l;
                }
            }
        }
}

// ---------------- 128x128-tile GEMM: gll + counted-vmcnt pipeline ----------------
// EPI: 0 = fp32 C; 2 = planes; 3 = planes + transposed planes.
// Both plain (cH) and transposed (cT1) outputs are null-guarded in EPI>=2 paths.
// TRIANG: grid x enumerates 3 lower-triangle 128^2 tiles of a symmetric 256^2 output.
template<int EPI, bool TRIPLE, int NTERM, int KSPLIT, bool TRIANG = false>
__global__ __launch_bounds__(256) void gemm_gll(
    Ptr3 aH, Ptr3 aL, Ptr3 bH, Ptr3 bL, Ptr3 cH, Ptr3 cL,
    Ptr3 cT1, Ptr3 cT2, int ldct, long long csT,
    int K, int lda, int ldb, int ldc, int divz,
    long long ash, long long bsh, long long csh,
    long long ksa, long long ksb, long long ksc,
    float scale)
{
    constexpr int XA = (NTERM == 3) ? 128 : 1;
    __shared__ u16 Ahs[2][128][32];
    __shared__ u16 Bhs[2][128][32];
    __shared__ u16 Als[XA][32], Bls[XA][32];   // single-buffered lo planes

    const int gx = gridDim.x, gy = gridDim.y;
    const int nwg = gx * gy * gridDim.z;
    int flat = blockIdx.x + gx * (blockIdx.y + gy * blockIdx.z);
    {
        int q = nwg >> 3;                       // nwg % 8 == 0 guaranteed by caller
        int xcd = flat & 7, idx = flat >> 3;
        flat = xcd * q + idx;
    }
    const int bx = flat % gx;
    const int by = (flat / gx) % gy;
    const int z  = flat / (gx * gy);

    const int zb = z / divz;
    const int rem = z - zb * divz;
    const int zh = rem / KSPLIT, ks = rem - zh * KSPLIT;
    const int Keff = K / KSPLIT;
    const void* avH = TRIPLE ? (zb == 0 ? aH.p0 : zb == 1 ? aH.p1 : aH.p2) : aH.p0;
    const void* avL = TRIPLE ? (zb == 0 ? aL.p0 : zb == 1 ? aL.p1 : aL.p2) : aL.p0;
    const void* bvH = TRIPLE ? (zb == 0 ? bH.p0 : zb == 1 ? bH.p1 : bH.p2) : bH.p0;
    const void* bvL = TRIPLE ? (zb == 0 ? bL.p0 : zb == 1 ? bL.p1 : bL.p2) : bL.p0;
    void* cvH = (void*)(TRIPLE ? (zb == 0 ? cH.p0 : zb == 1 ? cH.p1 : cH.p2) : cH.p0);
    void* cvL = (void*)(TRIPLE ? (zb == 0 ? cL.p0 : zb == 1 ? cL.p1 : cL.p2) : cL.p0);
    void* cvT1 = (void*)(TRIPLE ? (zb == 0 ? cT1.p0 : zb == 1 ? cT1.p1 : cT1.p2) : cT1.p0);
    void* cvT2 = (void*)(TRIPLE ? (zb == 0 ? cT2.p0 : zb == 1 ? cT2.p1 : cT2.p2) : cT2.p0);
    const long long ao = (long long)zh * ash + (long long)ks * ksa;
    const long long bo = (long long)zh * bsh + (long long)ks * ksb;
    const long long co = (long long)zh * csh + (long long)ks * ksc;
    const long long coT = (long long)zh * csT;

    const u16* AHg = (const u16*)avH + ao;
    const u16* ALg = (const u16*)avL + ao;
    const u16* BHg = (const u16*)bvH + bo;
    const u16* BLg = (const u16*)bvL + bo;
    float* Cf  = (float*)cvH + co;
    u16*   CHg = (u16*)cvH + co;
    u16*   CLg = (u16*)cvL + co;

    int m0, n0;
    if constexpr (TRIANG) {
        m0 = (bx >= 1) ? 128 : 0;
        n0 = (bx == 2) ? 128 : 0;
    } else {
        m0 = by * 128; n0 = bx * 128;
    }
    const int tid = threadIdx.x;
    const int lane = tid & 63, w = tid >> 6;
    const int wrow = (w >> 1) * 64, wcol = (w & 1) * 64;
    const int l15 = lane & 15, lg = lane >> 4;

    f32x4 zero = {0.f, 0.f, 0.f, 0.f};
    f32x4 acc[4][4];
    #pragma unroll
    for (int mf = 0; mf < 4; ++mf)
        #pragma unroll
        for (int nf = 0; nf < 4; ++nf) acc[mf][nf] = zero;

    const int ric = lane >> 2;
    const int cc  = lane & 3;

    auto STAGE_HI = [&](int bufsel, int k0) {
        #pragma unroll
        for (int i = 0; i < 2; ++i) {
            int chunk = w * 2 + i;
            int row = chunk * 16 + ric;
            int gcol = ((cc ^ ((row >> 1) & 3)) << 3);
            GLL16(AHg + (long long)(m0 + row) * lda + (k0 + gcol), &Ahs[bufsel][chunk * 16][0]);
            GLL16(BHg + (long long)(n0 + row) * ldb + (k0 + gcol), &Bhs[bufsel][chunk * 16][0]);
        }
    };
    auto STAGE_LO = [&](int k0) {
        #pragma unroll
        for (int i = 0; i < 2; ++i) {
            int chunk = w * 2 + i;
            int row = chunk * 16 + ric;
            int gcol = ((cc ^ ((row >> 1) & 3)) << 3);
            GLL16(ALg + (long long)(m0 + row) * lda + (k0 + gcol), &Als[chunk * 16][0]);
            GLL16(BLg + (long long)(n0 + row) * ldb + (k0 + gcol), &Bls[chunk * 16][0]);
        }
    };

    const int nt = Keff / 32;
    int cur = 0;
    STAGE_HI(0, 0);

    for (int t = 0; t < nt; ++t) {
        if constexpr (NTERM == 3) STAGE_LO(t * 32);
        if (t + 1 < nt) {
            STAGE_HI(cur ^ 1, (t + 1) * 32);
            asm volatile("s_waitcnt vmcnt(4)" ::: "memory");
        } else {
            asm volatile("s_waitcnt vmcnt(0)" ::: "memory");
        }
        __builtin_amdgcn_s_barrier();

        short8 a_h[4], a_l[4];
        #pragma unroll
        for (int mf = 0; mf < 4; ++mf) {
            int ar = wrow + mf * 16 + l15;
            int ac = (lg ^ ((ar >> 1) & 3)) << 3;
            a_h[mf] = *(const short8*)&Ahs[cur][ar][ac];
            if constexpr (NTERM == 3) a_l[mf] = *(const short8*)&Als[ar][ac];
        }
        __builtin_amdgcn_s_setprio(1);
        #pragma unroll
        for (int nf = 0; nf < 4; ++nf) {
            int br = wcol + nf * 16 + l15;
            int bc = (lg ^ ((br >> 1) & 3)) << 3;
            short8 b_h = *(const short8*)&Bhs[cur][br][bc];
            if constexpr (NTERM == 3) {
                short8 b_l = *(const short8*)&Bls[br][bc];
                #pragma unroll
                for (int mf = 0; mf < 4; ++mf) {
                    acc[mf][nf] = __builtin_amdgcn_mfma_f32_16x16x32_bf16(a_h[mf], b_h, acc[mf][nf], 0, 0, 0);
                    acc[mf][nf] = __builtin_amdgcn_mfma_f32_16x16x32_bf16(a_h[mf], b_l, acc[mf][nf], 0, 0, 0);
                    acc[mf][nf] = __builtin_amdgcn_mfma_f32_16x16x32_bf16(a_l[mf], b_h, acc[mf][nf], 0, 0, 0);
                }
            } else {
                #pragma unroll
                for (int mf = 0; mf < 4; ++mf)
                    acc[mf][nf] = __builtin_amdgcn_mfma_f32_16x16x32_bf16(a_h[mf], b_h, acc[mf][nf], 0, 0, 0);
            }
        }
        __builtin_amdgcn_s_setprio(0);
        __builtin_amdgcn_s_barrier();
        cur ^= 1;
    }

    #pragma unroll
    for (int mf = 0; mf < 4; ++mf)
        #pragma unroll
        for (int nf = 0; nf < 4; ++nf) {
            int row = m0 + wrow + mf * 16 + lg * 4;
            int col = n0 + wcol + nf * 16 + l15;
            if constexpr (EPI == 0) {
                #pragma unroll
                for (int j = 0; j < 4; ++j)
                    Cf[(long long)(row + j) * ldc + col] = acc[mf][nf][j] * scale;
            } else {  // EPI 2 or 3
                unsigned p[4];
                #pragma unroll
                for (int j = 0; j < 4; ++j) p[j] = cvt_hl(acc[mf][nf][j] * scale);
                if (cvH) {   // null for members whose plain planes are dead
                    #pragma unroll
                    for (int j = 0; j < 4; ++j) {
                        CHg[(long long)(row + j) * ldc + col] = (u16)p[j];
                        CLg[(long long)(row + j) * ldc + col] = (u16)(p[j] >> 16);
                    }
                }
                if constexpr (EPI == 3) {
                    if (cvT1) {  // null for members that don't need the transpose
                        u16* CTH = (u16*)cvT1 + coT;
                        u16* CTL = (u16*)cvT2 + coT;
                        ushort4_t h, l;
                        #pragma unroll
                        for (int j = 0; j < 4; ++j) { h[j] = (u16)p[j]; l[j] = (u16)(p[j] >> 16); }
                        *(ushort4_t*)(CTH + (long long)col * ldct + row) = h;
                        *(ushort4_t*)(CTL + (long long)col * ldct + row) = l;
                    }
                }
            }
        }
}

// ---------------- merged reduce: loss (both Grams, triangular) + qkv split-K ----------------
#define KS_ 8
#define NKS6_ 2
// blocks [0, 1024): loss reduce; blocks [1024, 1024 + 3*T/1024): qkv reduce
__global__ __launch_bounds__(256) void reduce_all(
    const float* __restrict__ G1, const float* __restrict__ G2,
    int nks, float* __restrict__ lossBase,
    const float* __restrict__ Cpart, Ptr3 dstH, Ptr3 dstL)
{
    __shared__ float red[4];
    int lane = threadIdx.x & 63, wid = threadIdx.x >> 6;
    if (blockIdx.x < 1024) {
        const long long N = (long long)B_ * R_ * R_;
        int seg = blockIdx.x >> 9;                 // 0 or 1 (512 blocks each)
        const float* G = seg ? G2 : G1;
        float* lossDst = lossBase + (seg ? 2 : 0);
        long long i4 = ((long long)(blockIdx.x & 511) * 256 + threadIdx.x) << 2;
        float s = 0.0f;
        if (i4 < N) {
            int e = (int)(i4 & (long long)(R_ * R_ - 1));
            int row = e >> 8, c0 = e & 255;
            // upper-right block (row<128, col>=128) never computed: lower mirror counts x2.
            if (!(row < 128 && c0 >= 128)) {
                float4 g = make_float4(0.f, 0.f, 0.f, 0.f);
                for (int ks = 0; ks < nks; ++ks) {
                    float4 v = *(const float4*)(G + (long long)ks * N + i4);
                    g.x += v.x; g.y += v.y; g.z += v.z; g.w += v.w;
                }
                float wgt = (row >= 128 && c0 < 128) ? 2.0f : 1.0f;
                if (row != c0 + 0) s += wgt * g.x * g.x;
                if (row != c0 + 1) s += wgt * g.y * g.y;
                if (row != c0 + 2) s += wgt * g.z * g.z;
                if (row != c0 + 3) s += wgt * g.w * g.w;
            }
        }
        #pragma unroll
        for (int o = 32; o; o >>= 1) s += __shfl_down(s, o, 64);
        if (lane == 0) red[wid] = s;
        __syncthreads();
        if (threadIdx.x == 0) atomicAdd(lossDst, red[0] + red[1] + red[2] + red[3]);
    } else {
        const long long T = (long long)B_ * R_ * C_;
        long long i4 = (long long)(blockIdx.x - 1024) * 256 + threadIdx.x;
        if (i4 >= 3 * (T >> 2)) return;
        int member = (int)(i4 / (T >> 2));
        long long rem = (i4 - (long long)member * (T >> 2)) << 2;
        float4 a = *(const float4*)(Cpart + (long long)member * T + rem);
        #pragma unroll
        for (int ks = 1; ks < NKS6_; ++ks) {
            float4 b = *(const float4*)(Cpart + (long long)ks * 3 * T + (long long)member * T + rem);
            a.x += b.x; a.y += b.y; a.z += b.z; a.w += b.w;
        }
        unsigned q0 = cvt_hl(a.x), q1 = cvt_hl(a.y), q2 = cvt_hl(a.z), q3 = cvt_hl(a.w);
        ushort4_t h, l;
        h[0]=(u16)q0; h[1]=(u16)q1; h[2]=(u16)q2; h[3]=(u16)q3;
        l[0]=(u16)(q0>>16); l[1]=(u16)(q1>>16); l[2]=(u16)(q2>>16); l[3]=(u16)(q3>>16);
        u16* dH = (u16*)(member == 0 ? dstH.p0 : member == 1 ? dstH.p1 : dstH.p2);
        u16* dL = (u16*)(member == 0 ? dstL.p0 : member == 1 ? dstL.p1 : dstL.p2);
        *(ushort4_t*)(dH + rem) = h;
        *(ushort4_t*)(dL + rem) = l;
    }
}

// ---------------- transpose kernels ----------------
__global__ __launch_bounds__(256) void xpose_f32p3(
    Ptr3 src, Ptr3 dstH, Ptr3 dstL,
    int M, int N, long long ibs, long long obs, int divz)
{
    __shared__ float S[64][65];
    int z = blockIdx.z;
    int m = z / divz, b = z - m * divz;
    const float* ip = (const float*)(m == 0 ? src.p0 : m == 1 ? src.p1 : src.p2)
                      + (long long)b * ibs;
    u16* opH = (u16*)(m == 0 ? dstH.p0 : m == 1 ? dstH.p1 : dstH.p2) + (long long)b * obs;
    u16* opL = (u16*)(m == 0 ? dstL.p0 : m == 1 ? dstL.p1 : dstL.p2) + (long long)b * obs;
    int n0 = blockIdx.x * 64, m0 = blockIdx.y * 64;
    int t = threadIdx.x;
    int c4 = (t & 15) << 2, rq = t >> 4;
    #pragma unroll
    for (int p = 0; p < 4; ++p) {
        int r = p * 16 + rq;
        float4 v = *(const float4*)(ip + (long long)(m0 + r) * N + n0 + c4);
        S[r][c4+0]=v.x; S[r][c4+1]=v.y; S[r][c4+2]=v.z; S[r][c4+3]=v.w;
    }
    __syncthreads();
    #pragma unroll
    for (int p = 0; p < 4; ++p) {
        int nr = p * 16 + rq;
        unsigned q0 = cvt_hl(S[c4+0][nr]), q1 = cvt_hl(S[c4+1][nr]);
        unsigned q2 = cvt_hl(S[c4+2][nr]), q3 = cvt_hl(S[c4+3][nr]);
        ushort4_t h, l;
        h[0]=(u16)q0; h[1]=(u16)q1; h[2]=(u16)q2; h[3]=(u16)q3;
        l[0]=(u16)(q0>>16); l[1]=(u16)(q1>>16); l[2]=(u16)(q2>>16); l[3]=(u16)(q3>>16);
        long long ob = (long long)(n0 + nr) * M + m0 + c4;
        *(ushort4_t*)(opH + ob) = h;
        *(ushort4_t*)(opL + ob) = l;
    }
}

__global__ __launch_bounds__(256) void xpose_u16p(
    const u16* __restrict__ inH, const u16* __restrict__ inL,
    u16* __restrict__ outH, u16* __restrict__ outL,
    int M, int N, long long ibs, long long obs)
{
    __shared__ u16 SH[64][66], SL[64][66];
    const u16* ipH = inH + (long long)blockIdx.z * ibs;
    const u16* ipL = inL + (long long)blockIdx.z * ibs;
    u16* opH = outH + (long long)blockIdx.z * obs;
    u16* opL = outL + (long long)blockIdx.z * obs;
    int n0 = blockIdx.x * 64, m0 = blockIdx.y * 64;
    int t = threadIdx.x;
    int c4 = (t & 15) << 2, rq = t >> 4;
    #pragma unroll
    for (int p = 0; p < 4; ++p) {
        int r = p * 16 + rq;
        long long ib = (long long)(m0 + r) * N + n0 + c4;
        ushort4_t vh = *(const ushort4_t*)(ipH + ib);
        ushort4_t vl = *(const ushort4_t*)(ipL + ib);
        SH[r][c4+0]=vh[0]; SH[r][c4+1]=vh[1]; SH[r][c4+2]=vh[2]; SH[r][c4+3]=vh[3];
        SL[r][c4+0]=vl[0]; SL[r][c4+1]=vl[1]; SL[r][c4+2]=vl[2]; SL[r][c4+3]=vl[3];
    }
    __syncthreads();
    #pragma unroll
    for (int p = 0; p < 4; ++p) {
        int nr = p * 16 + rq;
        ushort4_t h, l;
        h[0]=SH[c4+0][nr]; h[1]=SH[c4+1][nr]; h[2]=SH[c4+2][nr]; h[3]=SH[c4+3][nr];
        l[0]=SL[c4+0][nr]; l[1]=SL[c4+1][nr]; l[2]=SL[c4+2][nr]; l[3]=SL[c4+3][nr];
        long long ob = (long long)(n0 + nr) * M + m0 + c4;
        *(ushort4_t*)(opH + ob) = h;
        *(ushort4_t*)(opL + ob) = l;
    }
}

// ---------------- helpers ----------------
__device__ inline float waveMax(float v) {
    #pragma unroll
    for (int o = 32; o; o >>= 1) v = fmaxf(v, __shfl_xor(v, o, 64));
    return v;
}
__device__ inline float waveSum(float v) {
    #pragma unroll
    for (int o = 32; o; o >>= 1) v += __shfl_xor(v, o, 64);
    return v;
}

// fused: all five weights -> hi/lo planes in one launch.
__global__ __launch_bounds__(256) void conv_planes5(
    const float* __restrict__ s0, const float* __restrict__ s1, const float* __restrict__ s2,
    const float* __restrict__ s3, const float* __restrict__ s4,
    u16* h0, u16* l0, u16* h1, u16* l1, u16* h2, u16* l2,
    u16* h3, u16* l3, u16* h4, u16* l4)
{
    const int N0 = 32768, NW = 65536;
    int i = blockIdx.x * 256 + threadIdx.x;
    if (i >= N0 + 4 * NW) return;
    const float* s; u16* h; u16* l; int off;
    if (i < N0) { s = s0; h = h0; l = l0; off = i; }
    else {
        int j = i - N0, seg = j / NW;
        off = j - seg * NW;
        s = seg == 0 ? s1 : seg == 1 ? s2 : seg == 2 ? s3 : s4;
        h = seg == 0 ? h1 : seg == 1 ? h2 : seg == 2 ? h3 : h4;
        l = seg == 0 ? l1 : seg == 1 ? l2 : seg == 2 ? l3 : l4;
    }
    float4 v = ((const float4*)s)[off];
    unsigned p0 = cvt_hl(v.x), p1 = cvt_hl(v.y), p2 = cvt_hl(v.z), p3 = cvt_hl(v.w);
    ushort4_t hv, lv;
    hv[0]=(u16)p0; hv[1]=(u16)p1; hv[2]=(u16)p2; hv[3]=(u16)p3;
    lv[0]=(u16)(p0>>16); lv[1]=(u16)(p1>>16); lv[2]=(u16)(p2>>16); lv[3]=(u16)(p3>>16);
    ((ushort4_t*)h)[off] = hv;
    ((ushort4_t*)l)[off] = lv;
}

// merged: blocks [0, B*R) do the LT softmax (rows of pScoreT, len L);
// blocks [B*R, B*R + B*L/4) do the R softmax, 4 rows/block, one wave per row.
__global__ __launch_bounds__(256) void softmax_both(
    const float* __restrict__ pT, const float* __restrict__ pScore,
    const int* __restrict__ mask,
    u16* __restrict__ ltH, u16* __restrict__ ltL,
    u16* __restrict__ rH, u16* __restrict__ rL)
{
    __shared__ float sm[4], ss[4];
    int bxid = blockIdx.x;
    int lane = threadIdx.x & 63, wid = threadIdx.x >> 6;
    if (bxid < B_ * R_) {
        int zi = bxid;                // b*R + r
        int b = zi >> 8;
        const float* row = pT + (long long)zi * L_;
        const int* mk = mask + (long long)b * L_ * L_;   // row 0 of [L,L]
        float vals[8];
        float mx = -3.4e38f;
        #pragma unroll
        for (int i = 0; i < 8; ++i) {
            int l = threadIdx.x + i * 256;
            float v = row[l];
            if (mk[l] == 0) v = MASK_NEG;
            vals[i] = v; mx = fmaxf(mx, v);
        }
        mx = waveMax(mx);
        if (lane == 0) sm[wid] = mx;
        __syncthreads();
        mx = fmaxf(fmaxf(sm[0], sm[1]), fmaxf(sm[2], sm[3]));
        float sum = 0.0f;
        #pragma unroll
        for (int i = 0; i < 8; ++i) { float e = __expf(vals[i] - mx); vals[i] = e; sum += e; }
        sum = waveSum(sum);
        if (lane == 0) ss[wid] = sum;
        __syncthreads();
        sum = ss[0] + ss[1] + ss[2] + ss[3];
        float inv = 1.0f / sum;
        long long base = (long long)zi * L_;
        #pragma unroll
        for (int i = 0; i < 8; ++i) {
            unsigned p = cvt_hl(vals[i] * inv);
            ltH[base + threadIdx.x + i * 256] = (u16)p;
            ltL[base + threadIdx.x + i * 256] = (u16)(p >> 16);
        }
    } else {
        // R path: wave-per-row, 4 rows/block, float4 loads, no barriers
        long long z = (long long)(bxid - B_ * R_) * 4 + wid;   // b*L + l
        int b = (int)(z >> 11), l = (int)(z & 2047);
        bool pad = (mask[(long long)b * L_ * L_ + l] == 0);
        float4 v = *(const float4*)(pScore + z * R_ + lane * 4);
        if (pad) { v.x = MASK_NEG; v.y = MASK_NEG; v.z = MASK_NEG; v.w = MASK_NEG; }
        float mx = waveMax(fmaxf(fmaxf(v.x, v.y), fmaxf(v.z, v.w)));
        float e0 = __expf(v.x - mx), e1 = __expf(v.y - mx);
        float e2 = __expf(v.z - mx), e3 = __expf(v.w - mx);
        float inv = 1.0f / waveSum(e0 + e1 + e2 + e3);
        unsigned p0 = cvt_hl(e0 * inv), p1 = cvt_hl(e1 * inv);
        unsigned p2 = cvt_hl(e2 * inv), p3 = cvt_hl(e3 * inv);
        ushort4_t h, lo;
        h[0]=(u16)p0; h[1]=(u16)p1; h[2]=(u16)p2; h[3]=(u16)p3;
        lo[0]=(u16)(p0>>16); lo[1]=(u16)(p1>>16); lo[2]=(u16)(p2>>16); lo[3]=(u16)(p3>>16);
        *(ushort4_t*)(rH + z * R_ + lane * 4) = h;
        *(ushort4_t*)(rL + z * R_ + lane * 4) = lo;
    }
}

// wave-per-row softmax over scores (256 cols), 4 rows/block, + offArr
__global__ __launch_bounds__(256) void softmax_alpha4(
    const float* __restrict__ scores, u16* __restrict__ aH, u16* __restrict__ aL,
    float* __restrict__ offArr)
{
    int lane = threadIdx.x & 63, wid = threadIdx.x >> 6;
    long long row = (long long)blockIdx.x * 4 + wid;  // over B*H*R
    int r = (int)(row & 255);
    float4 v = *(const float4*)(scores + row * 256 + lane * 4);
    float mx = waveMax(fmaxf(fmaxf(v.x, v.y), fmaxf(v.z, v.w)));
    float e0 = __expf(v.x - mx), e1 = __expf(v.y - mx);
    float e2 = __expf(v.z - mx), e3 = __expf(v.w - mx);
    float inv = 1.0f / waveSum(e0 + e1 + e2 + e3);
    float a0 = e0 * inv, a1 = e1 * inv, a2 = e2 * inv, a3 = e3 * inv;
    unsigned p0 = cvt_hl(a0), p1 = cvt_hl(a1), p2 = cvt_hl(a2), p3 = cvt_hl(a3);
    ushort4_t h, lo;
    h[0]=(u16)p0; h[1]=(u16)p1; h[2]=(u16)p2; h[3]=(u16)p3;
    lo[0]=(u16)(p0>>16); lo[1]=(u16)(p1>>16); lo[2]=(u16)(p2>>16); lo[3]=(u16)(p3>>16);
    *(ushort4_t*)(aH + row * 256 + lane * 4) = h;
    *(ushort4_t*)(aL + row * 256 + lane * 4) = lo;
    int c = lane * 4;
    float off = (c + 0 == r ? 0.0f : a0) + (c + 1 == r ? 0.0f : a1)
              + (c + 2 == r ? 0.0f : a2) + (c + 3 == r ? 0.0f : a3);
    off = waveSum(off);
    if (lane == 0) offArr[row] = off;
}

__global__ __launch_bounds__(256) void finalize_loss(
    const float* __restrict__ addLossIn, const float* __restrict__ lossAcc,
    const float* __restrict__ offArr, float* __restrict__ out)
{
    __shared__ float red[4];
    float s = 0.0f;
    for (int i = threadIdx.x; i < B_ * H_ * R_; i += 256) s += offArr[i];
    int lane = threadIdx.x & 63, wid = threadIdx.x >> 6;
    s = waveSum(s);
    if (lane == 0) red[wid] = s;
    __syncthreads();
    if (threadIdx.x == 0) {
        float total = red[0] + red[1] + red[2] + red[3];
        out[0] = addLossIn[0]
               + lossAcc[0] * (1.0f / ((float)B_ * R_ * R_))
               + total      * (1.0f / ((float)B_ * H_ * R_ * R_))
               + lossAcc[2] * (1.0f / ((float)B_ * R_ * R_));
    }
}

// ---------------- launch ----------------
extern "C" void kernel_launch(void* const* d_in, const int* in_sizes, int n_in,
                              void* d_out, int out_size, void* d_ws, size_t ws_size,
                              hipStream_t stream)
{
    const float* qx = (const float*)d_in[0];
    const float* kx = (const float*)d_in[1];
    const float* vx = (const float*)d_in[2];
    const float* addLossIn = (const float*)d_in[3];
    const int* mask = (const int*)d_in[4];
    const float* Wp = (const float*)d_in[5];
    const float* WQ = (const float*)d_in[6];
    const float* WK = (const float*)d_in[7];
    const float* WV = (const float*)d_in[8];
    const float* WO = (const float*)d_in[9];

    float* zOut      = (float*)d_out;                             // [B,L,C]
    float* scoresOut = zOut + (long long)B_ * L_ * C_;            // [B,H,R,R]
    float* lossOut   = scoresOut + (long long)B_ * H_ * R_ * R_;  // [1]

    const long long S = (long long)B_ * L_ * R_;    // 4,194,304
    const long long T = (long long)B_ * R_ * C_;    // 1,048,576
    u16* cur = (u16*)d_ws;
    auto takeU = [&](long long n) { u16* p = cur; cur += n; return p; };
    auto takeF = [&](long long n) { float* p = (float*)cur; cur += 2 * n; return p; };

    float* pScore   = takeF(S);          // [B,L,R]
    float* pScoreT  = takeF(S);          // [B,R,L]
    u16* pAlphaH  = takeU(S);            // [B,R,L]
    u16* pAlphaL  = takeU(S);
    u16* pAlpha_H = takeU(S);            // [B,L,R]
    u16* pAlpha_L = takeU(S);
    u16* pATH     = takeU(S);            // [B,R,L]
    u16* pATL     = takeU(S);
    u16* xTH0 = takeU(2*S); u16* xTL0 = takeU(2*S);   // [B,C,L] = 2S per plane
    u16* xTH1 = takeU(2*S); u16* xTL1 = takeU(2*S);
    u16* xTH2 = takeU(2*S); u16* xTL2 = takeU(2*S);
    const long long llRR = (long long)R_ * R_;
    float* Gpart  = takeF(2LL * KS_ * B_ * llRR);   // [2 losses][KS][B][R][R]
    float* Cpart6 = takeF((long long)NKS6_ * 3 * T); // 6b split-K partials
    u16* qrH = takeU(T); u16* qrL = takeU(T);
    u16* krH = takeU(T); u16* krL = takeU(T);
    u16* vrH = takeU(T); u16* vrL = takeU(T);
    u16* qpH = takeU(T); u16* qpL = takeU(T);
    u16* kpH = takeU(T); u16* kpL = takeU(T);
    u16* vpTH = takeU(T); u16* vpTL = takeU(T);
    u16* z1H = takeU(T); u16* z1L = takeU(T);
    u16* z2TH = takeU(T); u16* z2TL = takeU(T);
    u16* alphaH = takeU(S); u16* alphaL = takeU(S);
    u16* WpH = takeU((long long)R_ * C_); u16* WpL = takeU((long long)R_ * C_);
    u16* WQH = takeU((long long)HD_ * C_); u16* WQL = takeU((long long)HD_ * C_);
    u16* WKH = takeU((long long)HD_ * C_); u16* WKL = takeU((long long)HD_ * C_);
    u16* WVH = takeU((long long)HD_ * C_); u16* WVL = takeU((long long)HD_ * C_);
    u16* WOH = takeU((long long)HD_ * C_); u16* WOL = takeU((long long)HD_ * C_);
    float* loss   = takeF(16);
    float* offArr = takeF(B_ * H_ * R_);

    const Ptr3 N3{nullptr, nullptr, nullptr};
    auto P1 = [](const void* p) { return Ptr3{p, p, p}; };
    const long long llRL = (long long)R_ * L_, llLC = (long long)L_ * C_;
    const long long llRC = (long long)R_ * C_, llRHD = (long long)R_ * HD_;
    const long long llHRR = (long long)H_ * R_ * R_;
    const long long llCL = (long long)C_ * L_;
    float* Gpart2 = Gpart + (long long)KS_ * B_ * llRR;

    (void)hipMemsetAsync(loss, 0, 3 * sizeof(float), stream);

    // 0) all weights -> planes, ONE launch (1152 blocks)
    conv_planes5<<<1152, 256, 0, stream>>>(
        Wp, WQ, WK, WV, WO,
        WpH, WpL, WQH, WQL, WKH, WKL, WVH, WVL, WOH, WOL);

    // 1) pScoreT = Wp @ vx^T AND pScore = transposed, fused epilogue (EPI=3)
    gemm_pl<64, 0, 2, 3, false><<<dim3(L_/64, R_/64, B_), 256, 0, stream>>>(
        P1(WpH), P1(WpL), P1(vx), N3, P1(pScoreT), N3,
        P1(pScore), N3, R_, llRL,
        C_, C_, C_, L_, B_,
        0, llLC, llRL, 0, 0, 0, 0, 0, 0, 1.0f);

    // 3) both softmaxes in ONE launch: 2048 LT blocks + 4096 R blocks (wave/row)
    softmax_both<<<B_ * R_ + B_ * L_ / 4, 256, 0, stream>>>(
        pScoreT, pScore, mask, pAlphaH, pAlphaL, pAlpha_H, pAlpha_L);

    // 3b) pAT = transpose(pAlpha_) planes: [L,R] -> [R,L]
    xpose_u16p<<<dim3(R_/64, L_/64, B_), 256, 0, stream>>>(
        pAlpha_H, pAlpha_L, pATH, pATL, L_, R_, llRL, llRL);

    // 4+5) both loss Grams, triangular, KS=8: grid (3,1,2*8*8)=384 blocks (1.5/CU),
    //      K-chunk 256 (nt=8). R29 post-mortem: 192 blocks = 0.75/CU was latency-bound.
    gemm_gll<0, true, 1, KS_, true><<<dim3(3, 1, 2 * B_ * KS_), 256, 0, stream>>>(
        Ptr3{pAlphaH, pATH, pATH}, N3, Ptr3{pAlphaH, pATH, pATH}, N3,
        Ptr3{Gpart, Gpart2, Gpart2}, N3,
        N3, N3, 0, 0,
        L_, L_, L_, R_, B_ * KS_,
        llRL, llRL, llRR,
        L_ / KS_, L_ / KS_, (long long)B_ * llRR, 1.0f);

    // 6) xT = transpose all three inputs -> planes [C][L] (one launch, z=24)
    //    IMMEDIATELY before 6b: producer->consumer L2 adjacency (R28 lesson)
    xpose_f32p3<<<dim3(C_/64, L_/64, 3 * B_), 256, 0, stream>>>(
        Ptr3{qx, kx, vx}, Ptr3{xTH0, xTH1, xTH2}, Ptr3{xTL0, xTL1, xTL2},
        L_, C_, llLC, llCL, B_);

    // 6b) {q,k,v}r partials = pAlpha @ x : 128^2 gll, KSPLIT=2 -> 384 blocks (nt=32)
    gemm_gll<0, true, 3, NKS6_><<<dim3(C_/128, R_/128, 3 * B_ * NKS6_), 256, 0, stream>>>(
        P1(pAlphaH), P1(pAlphaL),
        Ptr3{xTH0, xTH1, xTH2}, Ptr3{xTL0, xTL1, xTL2},
        Ptr3{Cpart6, Cpart6 + T, Cpart6 + 2 * T}, N3,
        N3, N3, 0, 0,
        L_, L_, L_, C_, B_ * NKS6_,
        llRL, llCL, llRC,
        L_ / NKS6_, L_ / NKS6_, 3 * T, 1.0f);

    // 6c) merged reduce: loss (1024 blocks) + qkv partials (3072 blocks), ONE launch
    reduce_all<<<1024 + (int)(3 * (T >> 2) / 256), 256, 0, stream>>>(
        Gpart, Gpart2, KS_, loss,
        Cpart6, Ptr3{qrH, krH, vrH}, Ptr3{qrL, krL, vrL});

    // 7) projections; vp plain planes are DEAD (only vpT is read) -> null cH for member 2;
    //    fused vpT transpose only for vp (null-guarded cT): grid (4,2,24)
    gemm_gll<3, true, 3, 1><<<dim3(HD_/128, 2, 3 * B_), 256, 0, stream>>>(
        Ptr3{qrH, krH, vrH}, Ptr3{qrL, krL, vrL},
        Ptr3{WQH, WKH, WVH}, Ptr3{WQL, WKL, WVL},
        Ptr3{qpH, kpH, nullptr}, Ptr3{qpL, kpL, nullptr},
        Ptr3{nullptr, nullptr, vpTH}, Ptr3{nullptr, nullptr, vpTL}, R_, llRHD,
        C_, C_, C_, HD_, B_,
        llRC, 0, llRHD,
        0, 0, 0, 1.0f);

    // 8) scores = qp_h @ kp_h^T / 8 : [256,256] x64, K=64 (XCD-swizzled)
    gemm_pl<64, 0, 0, 0, false><<<dim3(4, 4, 64), 256, 0, stream>>>(
        P1(qpH), P1(qpL), P1(kpH), P1(kpL), P1(scoresOut), N3,
        N3, N3, 0, 0,
        DK_, HD_, HD_, R_, 8, 64, 64, llRR, llRHD, llRHD, llHRR,
        0, 0, 0, 0.125f);

    // 9) alpha = softmax(scores) -> planes + offArr (wave/row, 4096 blocks)
    softmax_alpha4<<<B_ * H_ * R_ / 4, 256, 0, stream>>>(scoresOut, alphaH, alphaL, offArr);

    // 10) z1 = alpha @ vp_h : [256,64] x64, K=256 (B = vpT slice, XCD-swizzled)
    gemm_pl<64, 0, 0, 2, false><<<dim3(1, 4, 64), 256, 0, stream>>>(
        P1(alphaH), P1(alphaL), P1(vpTH), P1(vpTL), P1(z1H), P1(z1L),
        N3, N3, 0, 0,
        R_, R_, R_, HD_, 8, llRR, (long long)64 * R_, 64, llHRR, llRHD, llRHD,
        0, 0, 0, 1.0f);

    // 11) z2T only (EPI=5): z2 plain planes are never read; batched grid (8,4,8)
    gemm_pl<64, 0, 0, 5, false><<<dim3(HD_/64, R_/64, B_), 256, 0, stream>>>(
        P1(z1H), P1(z1L), P1(WOH), P1(WOL), N3, N3,
        P1(z2TH), P1(z2TL), R_, llRC,
        HD_, HD_, HD_, C_, B_,
        llRHD, 0, llRC, 0, 0, 0, 0, 0, 0, 1.0f);

    // 12) z = pAlpha_ @ z2 : 128^2 gll counted-vmcnt, grid (4,16,8) = 512 blocks
    gemm_gll<0, false, 3, 1><<<dim3(C_/128, L_/128, B_), 256, 0, stream>>>(
        P1(pAlpha_H), P1(pAlpha_L), P1(z2TH), P1(z2TL), P1(zOut), N3,
        N3, N3, 0, 0,
        R_, R_, R_, C_, B_,
        llRL, llRC, llLC,
        0, 0, 0, 1.0f);

    // 13) addLoss
    finalize_loss<<<1, 256, 0, stream>>>(addLossIn, loss, offArr, lossOut);
}

// Round 31
// 286.871 us; speedup vs baseline: 1.0158x; 1.0158x over previous
//
#include <hip/hip_runtime.h>

#define B_  8
#define L_  2048
#define C_  512
#define R_  256
#define H_  8
#define DK_ 64
#define HD_ 512
#define MASK_NEG (-32767.0f)

typedef __attribute__((ext_vector_type(8))) short short8;
typedef __attribute__((ext_vector_type(8))) unsigned short ushort8;
typedef __attribute__((ext_vector_type(4))) unsigned short ushort4_t;
typedef __attribute__((ext_vector_type(4))) float f32x4;
typedef unsigned short u16;

__device__ inline u16 bf16_rne(float x) {
    unsigned u = __float_as_uint(x);
    return (u16)((u + 0x7FFFu + ((u >> 16) & 1u)) >> 16);
}
__device__ inline unsigned cvt_hl(float x) {
    u16 hh = bf16_rne(x);
    float hf = __uint_as_float(((unsigned)hh) << 16);
    u16 ll = bf16_rne(x - hf);
    return (unsigned)hh | ((unsigned)ll << 16);
}

struct Ptr3 { const void* p0; const void* p1; const void* p2; };

// async global->LDS, 16B per lane; LDS dest = wave-uniform base + lane*16
#define GLL16(g, l) __builtin_amdgcn_global_load_lds( \
    (const __attribute__((address_space(1))) void*)(g), \
    (__attribute__((address_space(3))) void*)(l), 16, 0, 0)

// ---------------- 64x64-tile MFMA plane GEMM (small/medium paths) ----------------
// XCD-swizzled (caller guarantees nwg%8==0).
// EPI: 0 = fp32 C; 2 = hi/lo planes; 3 = fp32 C + fp32 C^T; 4 = planes + transposed planes;
//      5 = transposed planes ONLY.
template<int BN, int AMODE, int BMODE, int EPI, bool TRIPLE, int NTERM = 3, int KSPLIT = 1>
__global__ __launch_bounds__(256) void gemm_pl(
    Ptr3 aH, Ptr3 aL, Ptr3 bH, Ptr3 bL, Ptr3 cH, Ptr3 cL,
    Ptr3 cT1, Ptr3 cT2, int ldct, long long csT,
    int K, int lda, int ldb, int ldc, int divz,
    long long ash, long long bsh, long long csh,
    long long asb, long long bsb, long long csb,
    long long ksa, long long ksb, long long ksc,
    float scale)
{
    constexpr int NF = BN / 32;
    constexpr int XA = (NTERM == 3) ? 64 : 1;
    constexpr int XB = (NTERM == 3) ? BN : 1;
    __shared__ u16 Ahs[64][40], Als[XA][40];
    __shared__ u16 Bhs[BN][40], Bls[XB][40];

    const int gx = gridDim.x, gy = gridDim.y;
    const int nwg = gx * gy * gridDim.z;
    int flat = blockIdx.x + gx * (blockIdx.y + gy * blockIdx.z);
    {
        int q = nwg >> 3;
        int xcd = flat & 7, idx = flat >> 3;
        flat = xcd * q + idx;
    }
    const int bx = flat % gx;
    const int by = (flat / gx) % gy;
    const int z  = flat / (gx * gy);

    const int zb = z / divz;
    const int rem = z - zb * divz;
    const int zh = rem / KSPLIT, ks = rem - zh * KSPLIT;
    const int Keff = K / KSPLIT;
    const void* avH = TRIPLE ? (zb == 0 ? aH.p0 : zb == 1 ? aH.p1 : aH.p2) : aH.p0;
    const void* avL = TRIPLE ? (zb == 0 ? aL.p0 : zb == 1 ? aL.p1 : aL.p2) : aL.p0;
    const void* bvH = TRIPLE ? (zb == 0 ? bH.p0 : zb == 1 ? bH.p1 : bH.p2) : bH.p0;
    const void* bvL = TRIPLE ? (zb == 0 ? bL.p0 : zb == 1 ? bL.p1 : bL.p2) : bL.p0;
    void* cvH = (void*)(TRIPLE ? (zb == 0 ? cH.p0 : zb == 1 ? cH.p1 : cH.p2) : cH.p0);
    void* cvL = (void*)(TRIPLE ? (zb == 0 ? cL.p0 : zb == 1 ? cL.p1 : cL.p2) : cL.p0);
    void* cvT1 = (void*)(TRIPLE ? (zb == 0 ? cT1.p0 : zb == 1 ? cT1.p1 : cT1.p2) : cT1.p0);
    void* cvT2 = (void*)(TRIPLE ? (zb == 0 ? cT2.p0 : zb == 1 ? cT2.p1 : cT2.p2) : cT2.p0);
    const long long ao = (TRIPLE ? 0 : (long long)zb * asb) + (long long)zh * ash + (long long)ks * ksa;
    const long long bo = (TRIPLE ? 0 : (long long)zb * bsb) + (long long)zh * bsh + (long long)ks * ksb;
    const long long co = (TRIPLE ? 0 : (long long)zb * csb) + (long long)zh * csh + (long long)ks * ksc;
    const long long coT = (long long)zh * csT;

    const u16*   AHg = (const u16*)avH + ao;
    const u16*   ALg = (const u16*)avL + ao;
    const u16*   BHg = (const u16*)bvH + bo;
    const u16*   BLg = (const u16*)bvL + bo;
    const float* Bfg = (const float*)bvH + bo;
    float* Cf  = (float*)cvH + co;
    u16*   CHg = (u16*)cvH + co;
    u16*   CLg = (u16*)cvL + co;

    const int m0 = by * 64, n0 = bx * BN;
    const int tid = threadIdx.x;
    const int lane = tid & 63, w = tid >> 6;
    const int wrow = (w >> 1) * 32, wcol = (w & 1) * (BN / 2);
    const int l15 = lane & 15, lg = lane >> 4;

    f32x4 zero = {0.f, 0.f, 0.f, 0.f};
    f32x4 acc[2][NF];
    #pragma unroll
    for (int mf = 0; mf < 2; ++mf)
        #pragma unroll
        for (int nf = 0; nf < NF; ++nf) acc[mf][nf] = zero;

    for (int k0 = 0; k0 < Keff; k0 += 32) {
        {
            int row = tid >> 2, kc = (tid & 3) << 3;
            long long off = (long long)(m0 + row) * lda + (k0 + kc);
            *(ushort8*)&Ahs[row][kc] = *(const ushort8*)(AHg + off);
            if constexpr (NTERM == 3)
                *(ushort8*)&Als[row][kc] = *(const ushort8*)(ALg + off);
        }
        if (BMODE == 0) {
            #pragma unroll
            for (int t = tid; t < BN * 4; t += 256) {
                int row = t >> 2, kc = (t & 3) << 3;
                long long off = (long long)(n0 + row) * ldb + (k0 + kc);
                *(ushort8*)&Bhs[row][kc] = *(const ushort8*)(BHg + off);
                if constexpr (NTERM == 3)
                    *(ushort8*)&Bls[row][kc] = *(const ushort8*)(BLg + off);
            }
        } else { // BMODE == 2: fp32 [N][K]
            #pragma unroll
            for (int t = tid; t < BN * 4; t += 256) {
                int row = t >> 2, kc = (t & 3) << 3;
                const float* s = Bfg + (long long)(n0 + row) * ldb + (k0 + kc);
                float4 v0 = *(const float4*)s, v1 = *(const float4*)(s + 4);
                unsigned p0 = cvt_hl(v0.x), p1 = cvt_hl(v0.y), p2 = cvt_hl(v0.z), p3 = cvt_hl(v0.w);
                unsigned p4 = cvt_hl(v1.x), p5 = cvt_hl(v1.y), p6 = cvt_hl(v1.z), p7 = cvt_hl(v1.w);
                ushort8 h, l;
                h[0]=(u16)p0; h[1]=(u16)p1; h[2]=(u16)p2; h[3]=(u16)p3;
                h[4]=(u16)p4; h[5]=(u16)p5; h[6]=(u16)p6; h[7]=(u16)p7;
                l[0]=(u16)(p0>>16); l[1]=(u16)(p1>>16); l[2]=(u16)(p2>>16); l[3]=(u16)(p3>>16);
                l[4]=(u16)(p4>>16); l[5]=(u16)(p5>>16); l[6]=(u16)(p6>>16); l[7]=(u16)(p7>>16);
                *(ushort8*)&Bhs[row][kc] = h;
                if constexpr (NTERM == 3)
                    *(ushort8*)&Bls[row][kc] = l;
            }
        }
        __syncthreads();

        short8 a_h[2], a_l[2];
        a_h[0] = *(const short8*)&Ahs[wrow +      l15][lg * 8];
        a_h[1] = *(const short8*)&Ahs[wrow + 16 + l15][lg * 8];
        if constexpr (NTERM == 3) {
            a_l[0] = *(const short8*)&Als[wrow +      l15][lg * 8];
            a_l[1] = *(const short8*)&Als[wrow + 16 + l15][lg * 8];
        }
        #pragma unroll
        for (int nf = 0; nf < NF; ++nf) {
            short8 b_h = *(const short8*)&Bhs[wcol + nf * 16 + l15][lg * 8];
            if constexpr (NTERM == 3) {
                short8 b_l = *(const short8*)&Bls[wcol + nf * 16 + l15][lg * 8];
                #pragma unroll
                for (int mf = 0; mf < 2; ++mf) {
                    acc[mf][nf] = __builtin_amdgcn_mfma_f32_16x16x32_bf16(a_h[mf], b_h, acc[mf][nf], 0, 0, 0);
                    acc[mf][nf] = __builtin_amdgcn_mfma_f32_16x16x32_bf16(a_h[mf], b_l, acc[mf][nf], 0, 0, 0);
                    acc[mf][nf] = __builtin_amdgcn_mfma_f32_16x16x32_bf16(a_l[mf], b_h, acc[mf][nf], 0, 0, 0);
                }
            } else {
                #pragma unroll
                for (int mf = 0; mf < 2; ++mf)
                    acc[mf][nf] = __builtin_amdgcn_mfma_f32_16x16x32_bf16(a_h[mf], b_h, acc[mf][nf], 0, 0, 0);
            }
        }
        __syncthreads();
    }

    #pragma unroll
    for (int mf = 0; mf < 2; ++mf)
        #pragma unroll
        for (int nf = 0; nf < NF; ++nf) {
            int row = m0 + wrow + mf * 16 + lg * 4;
            int col = n0 + wcol + nf * 16 + l15;
            if constexpr (EPI == 0 || EPI == 3) {
                #pragma unroll
                for (int j = 0; j < 4; ++j)
                    Cf[(long long)(row + j) * ldc + col] = acc[mf][nf][j] * scale;
                if constexpr (EPI == 3) {
                    float* CfT = (float*)cvT1 + coT;
                    float4 v = make_float4(acc[mf][nf][0] * scale, acc[mf][nf][1] * scale,
                                           acc[mf][nf][2] * scale, acc[mf][nf][3] * scale);
                    *(float4*)(CfT + (long long)col * ldct + row) = v;
                }
            } else {  // EPI 2, 4, 5: planes
                unsigned p[4];
                #pragma unroll
                for (int j = 0; j < 4; ++j) {
                    p[j] = cvt_hl(acc[mf][nf][j] * scale);
                    if constexpr (EPI != 5) {
                        CHg[(long long)(row + j) * ldc + col] = (u16)p[j];
                        CLg[(long long)(row + j) * ldc + col] = (u16)(p[j] >> 16);
                    }
                }
                if constexpr (EPI == 4 || EPI == 5) {
                    u16* CTH = (u16*)cvT1 + coT;
                    u16* CTL = (u16*)cvT2 + coT;
                    ushort4_t h, l;
                    #pragma unroll
                    for (int j = 0; j < 4; ++j) { h[j] = (u16)p[j]; l[j] = (u16)(p[j] >> 16); }
                    *(ushort4_t*)(CTH + (long long)col * ldct + row) = h;
                    *(ushort4_t*)(CTL + (long long)col * ldct + row) = l;
                }
            }
        }
}

// ---------------- 128x128-tile GEMM: gll + counted-vmcnt pipeline ----------------
// EPI: 0 = fp32 C; 2 = planes; 3 = planes + transposed planes.
// Both plain (cH) and transposed (cT1) outputs are null-guarded in EPI>=2 paths.
// TRIANG: grid x enumerates 3 lower-triangle 128^2 tiles of a symmetric 256^2 output.
template<int EPI, bool TRIPLE, int NTERM, int KSPLIT, bool TRIANG = false>
__global__ __launch_bounds__(256) void gemm_gll(
    Ptr3 aH, Ptr3 aL, Ptr3 bH, Ptr3 bL, Ptr3 cH, Ptr3 cL,
    Ptr3 cT1, Ptr3 cT2, int ldct, long long csT,
    int K, int lda, int ldb, int ldc, int divz,
    long long ash, long long bsh, long long csh,
    long long ksa, long long ksb, long long ksc,
    float scale)
{
    constexpr int XA = (NTERM == 3) ? 128 : 1;
    __shared__ u16 Ahs[2][128][32];
    __shared__ u16 Bhs[2][128][32];
    __shared__ u16 Als[XA][32], Bls[XA][32];   // single-buffered lo planes

    const int gx = gridDim.x, gy = gridDim.y;
    const int nwg = gx * gy * gridDim.z;
    int flat = blockIdx.x + gx * (blockIdx.y + gy * blockIdx.z);
    {
        int q = nwg >> 3;                       // nwg % 8 == 0 guaranteed by caller
        int xcd = flat & 7, idx = flat >> 3;
        flat = xcd * q + idx;
    }
    const int bx = flat % gx;
    const int by = (flat / gx) % gy;
    const int z  = flat / (gx * gy);

    const int zb = z / divz;
    const int rem = z - zb * divz;
    const int zh = rem / KSPLIT, ks = rem - zh * KSPLIT;
    const int Keff = K / KSPLIT;
    const void* avH = TRIPLE ? (zb == 0 ? aH.p0 : zb == 1 ? aH.p1 : aH.p2) : aH.p0;
    const void* avL = TRIPLE ? (zb == 0 ? aL.p0 : zb == 1 ? aL.p1 : aL.p2) : aL.p0;
    const void* bvH = TRIPLE ? (zb == 0 ? bH.p0 : zb == 1 ? bH.p1 : bH.p2) : bH.p0;
    const void* bvL = TRIPLE ? (zb == 0 ? bL.p0 : zb == 1 ? bL.p1 : bL.p2) : bL.p0;
    void* cvH = (void*)(TRIPLE ? (zb == 0 ? cH.p0 : zb == 1 ? cH.p1 : cH.p2) : cH.p0);
    void* cvL = (void*)(TRIPLE ? (zb == 0 ? cL.p0 : zb == 1 ? cL.p1 : cL.p2) : cL.p0);
    void* cvT1 = (void*)(TRIPLE ? (zb == 0 ? cT1.p0 : zb == 1 ? cT1.p1 : cT1.p2) : cT1.p0);
    void* cvT2 = (void*)(TRIPLE ? (zb == 0 ? cT2.p0 : zb == 1 ? cT2.p1 : cT2.p2) : cT2.p0);
    const long long ao = (long long)zh * ash + (long long)ks * ksa;
    const long long bo = (long long)zh * bsh + (long long)ks * ksb;
    const long long co = (long long)zh * csh + (long long)ks * ksc;
    const long long coT = (long long)zh * csT;

    const u16* AHg = (const u16*)avH + ao;
    const u16* ALg = (const u16*)avL + ao;
    const u16* BHg = (const u16*)bvH + bo;
    const u16* BLg = (const u16*)bvL + bo;
    float* Cf  = (float*)cvH + co;
    u16*   CHg = (u16*)cvH + co;
    u16*   CLg = (u16*)cvL + co;

    int m0, n0;
    if constexpr (TRIANG) {
        m0 = (bx >= 1) ? 128 : 0;
        n0 = (bx == 2) ? 128 : 0;
    } else {
        m0 = by * 128; n0 = bx * 128;
    }
    const int tid = threadIdx.x;
    const int lane = tid & 63, w = tid >> 6;
    const int wrow = (w >> 1) * 64, wcol = (w & 1) * 64;
    const int l15 = lane & 15, lg = lane >> 4;

    f32x4 zero = {0.f, 0.f, 0.f, 0.f};
    f32x4 acc[4][4];
    #pragma unroll
    for (int mf = 0; mf < 4; ++mf)
        #pragma unroll
        for (int nf = 0; nf < 4; ++nf) acc[mf][nf] = zero;

    const int ric = lane >> 2;
    const int cc  = lane & 3;

    auto STAGE_HI = [&](int bufsel, int k0) {
        #pragma unroll
        for (int i = 0; i < 2; ++i) {
            int chunk = w * 2 + i;
            int row = chunk * 16 + ric;
            int gcol = ((cc ^ ((row >> 1) & 3)) << 3);
            GLL16(AHg + (long long)(m0 + row) * lda + (k0 + gcol), &Ahs[bufsel][chunk * 16][0]);
            GLL16(BHg + (long long)(n0 + row) * ldb + (k0 + gcol), &Bhs[bufsel][chunk * 16][0]);
        }
    };
    auto STAGE_LO = [&](int k0) {
        #pragma unroll
        for (int i = 0; i < 2; ++i) {
            int chunk = w * 2 + i;
            int row = chunk * 16 + ric;
            int gcol = ((cc ^ ((row >> 1) & 3)) << 3);
            GLL16(ALg + (long long)(m0 + row) * lda + (k0 + gcol), &Als[chunk * 16][0]);
            GLL16(BLg + (long long)(n0 + row) * ldb + (k0 + gcol), &Bls[chunk * 16][0]);
        }
    };

    const int nt = Keff / 32;
    int cur = 0;
    STAGE_HI(0, 0);

    for (int t = 0; t < nt; ++t) {
        if constexpr (NTERM == 3) STAGE_LO(t * 32);
        if (t + 1 < nt) {
            STAGE_HI(cur ^ 1, (t + 1) * 32);
            asm volatile("s_waitcnt vmcnt(4)" ::: "memory");
        } else {
            asm volatile("s_waitcnt vmcnt(0)" ::: "memory");
        }
        __builtin_amdgcn_s_barrier();

        short8 a_h[4], a_l[4];
        #pragma unroll
        for (int mf = 0; mf < 4; ++mf) {
            int ar = wrow + mf * 16 + l15;
            int ac = (lg ^ ((ar >> 1) & 3)) << 3;
            a_h[mf] = *(const short8*)&Ahs[cur][ar][ac];
            if constexpr (NTERM == 3) a_l[mf] = *(const short8*)&Als[ar][ac];
        }
        __builtin_amdgcn_s_setprio(1);
        #pragma unroll
        for (int nf = 0; nf < 4; ++nf) {
            int br = wcol + nf * 16 + l15;
            int bc = (lg ^ ((br >> 1) & 3)) << 3;
            short8 b_h = *(const short8*)&Bhs[cur][br][bc];
            if constexpr (NTERM == 3) {
                short8 b_l = *(const short8*)&Bls[br][bc];
                #pragma unroll
                for (int mf = 0; mf < 4; ++mf) {
                    acc[mf][nf] = __builtin_amdgcn_mfma_f32_16x16x32_bf16(a_h[mf], b_h, acc[mf][nf], 0, 0, 0);
                    acc[mf][nf] = __builtin_amdgcn_mfma_f32_16x16x32_bf16(a_h[mf], b_l, acc[mf][nf], 0, 0, 0);
                    acc[mf][nf] = __builtin_amdgcn_mfma_f32_16x16x32_bf16(a_l[mf], b_h, acc[mf][nf], 0, 0, 0);
                }
            } else {
                #pragma unroll
                for (int mf = 0; mf < 4; ++mf)
                    acc[mf][nf] = __builtin_amdgcn_mfma_f32_16x16x32_bf16(a_h[mf], b_h, acc[mf][nf], 0, 0, 0);
            }
        }
        __builtin_amdgcn_s_setprio(0);
        __builtin_amdgcn_s_barrier();
        cur ^= 1;
    }

    #pragma unroll
    for (int mf = 0; mf < 4; ++mf)
        #pragma unroll
        for (int nf = 0; nf < 4; ++nf) {
            int row = m0 + wrow + mf * 16 + lg * 4;
            int col = n0 + wcol + nf * 16 + l15;
            if constexpr (EPI == 0) {
                #pragma unroll
                for (int j = 0; j < 4; ++j)
                    Cf[(long long)(row + j) * ldc + col] = acc[mf][nf][j] * scale;
            } else {  // EPI 2 or 3
                unsigned p[4];
                #pragma unroll
                for (int j = 0; j < 4; ++j) p[j] = cvt_hl(acc[mf][nf][j] * scale);
                if (cvH) {   // null for members whose plain planes are dead
                    #pragma unroll
                    for (int j = 0; j < 4; ++j) {
                        CHg[(long long)(row + j) * ldc + col] = (u16)p[j];
                        CLg[(long long)(row + j) * ldc + col] = (u16)(p[j] >> 16);
                    }
                }
                if constexpr (EPI == 3) {
                    if (cvT1) {  // null for members that don't need the transpose
                        u16* CTH = (u16*)cvT1 + coT;
                        u16* CTL = (u16*)cvT2 + coT;
                        ushort4_t h, l;
                        #pragma unroll
                        for (int j = 0; j < 4; ++j) { h[j] = (u16)p[j]; l[j] = (u16)(p[j] >> 16); }
                        *(ushort4_t*)(CTH + (long long)col * ldct + row) = h;
                        *(ushort4_t*)(CTL + (long long)col * ldct + row) = l;
                    }
                }
            }
        }
}

// ---------------- merged reduce: loss (both Grams, triangular) + qkv split-K ----------------
#define KS_ 4
#define NKS6_ 2
// blocks [0, 1024): loss reduce; blocks [1024, 1024 + 3*T/1024): qkv reduce
__global__ __launch_bounds__(256) void reduce_all(
    const float* __restrict__ G1, const float* __restrict__ G2,
    int nks, float* __restrict__ lossBase,
    const float* __restrict__ Cpart, Ptr3 dstH, Ptr3 dstL)
{
    __shared__ float red[4];
    int lane = threadIdx.x & 63, wid = threadIdx.x >> 6;
    if (blockIdx.x < 1024) {
        const long long N = (long long)B_ * R_ * R_;
        int seg = blockIdx.x >> 9;                 // 0 or 1 (512 blocks each)
        const float* G = seg ? G2 : G1;
        float* lossDst = lossBase + (seg ? 2 : 0);
        long long i4 = ((long long)(blockIdx.x & 511) * 256 + threadIdx.x) << 2;
        float s = 0.0f;
        if (i4 < N) {
            int e = (int)(i4 & (long long)(R_ * R_ - 1));
            int row = e >> 8, c0 = e & 255;
            // upper-right block (row<128, col>=128) never computed: lower mirror counts x2.
            if (!(row < 128 && c0 >= 128)) {
                float4 g = make_float4(0.f, 0.f, 0.f, 0.f);
                for (int ks = 0; ks < nks; ++ks) {
                    float4 v = *(const float4*)(G + (long long)ks * N + i4);
                    g.x += v.x; g.y += v.y; g.z += v.z; g.w += v.w;
                }
                float wgt = (row >= 128 && c0 < 128) ? 2.0f : 1.0f;
                if (row != c0 + 0) s += wgt * g.x * g.x;
                if (row != c0 + 1) s += wgt * g.y * g.y;
                if (row != c0 + 2) s += wgt * g.z * g.z;
                if (row != c0 + 3) s += wgt * g.w * g.w;
            }
        }
        #pragma unroll
        for (int o = 32; o; o >>= 1) s += __shfl_down(s, o, 64);
        if (lane == 0) red[wid] = s;
        __syncthreads();
        if (threadIdx.x == 0) atomicAdd(lossDst, red[0] + red[1] + red[2] + red[3]);
    } else {
        const long long T = (long long)B_ * R_ * C_;
        long long i4 = (long long)(blockIdx.x - 1024) * 256 + threadIdx.x;
        if (i4 >= 3 * (T >> 2)) return;
        int member = (int)(i4 / (T >> 2));
        long long rem = (i4 - (long long)member * (T >> 2)) << 2;
        float4 a = *(const float4*)(Cpart + (long long)member * T + rem);
        #pragma unroll
        for (int ks = 1; ks < NKS6_; ++ks) {
            float4 b = *(const float4*)(Cpart + (long long)ks * 3 * T + (long long)member * T + rem);
            a.x += b.x; a.y += b.y; a.z += b.z; a.w += b.w;
        }
        unsigned q0 = cvt_hl(a.x), q1 = cvt_hl(a.y), q2 = cvt_hl(a.z), q3 = cvt_hl(a.w);
        ushort4_t h, l;
        h[0]=(u16)q0; h[1]=(u16)q1; h[2]=(u16)q2; h[3]=(u16)q3;
        l[0]=(u16)(q0>>16); l[1]=(u16)(q1>>16); l[2]=(u16)(q2>>16); l[3]=(u16)(q3>>16);
        u16* dH = (u16*)(member == 0 ? dstH.p0 : member == 1 ? dstH.p1 : dstH.p2);
        u16* dL = (u16*)(member == 0 ? dstL.p0 : member == 1 ? dstL.p1 : dstL.p2);
        *(ushort4_t*)(dH + rem) = h;
        *(ushort4_t*)(dL + rem) = l;
    }
}

// ---------------- transpose kernels ----------------
__global__ __launch_bounds__(256) void xpose_f32p3(
    Ptr3 src, Ptr3 dstH, Ptr3 dstL,
    int M, int N, long long ibs, long long obs, int divz)
{
    __shared__ float S[64][65];
    int z = blockIdx.z;
    int m = z / divz, b = z - m * divz;
    const float* ip = (const float*)(m == 0 ? src.p0 : m == 1 ? src.p1 : src.p2)
                      + (long long)b * ibs;
    u16* opH = (u16*)(m == 0 ? dstH.p0 : m == 1 ? dstH.p1 : dstH.p2) + (long long)b * obs;
    u16* opL = (u16*)(m == 0 ? dstL.p0 : m == 1 ? dstL.p1 : dstL.p2) + (long long)b * obs;
    int n0 = blockIdx.x * 64, m0 = blockIdx.y * 64;
    int t = threadIdx.x;
    int c4 = (t & 15) << 2, rq = t >> 4;
    #pragma unroll
    for (int p = 0; p < 4; ++p) {
        int r = p * 16 + rq;
        float4 v = *(const float4*)(ip + (long long)(m0 + r) * N + n0 + c4);
        S[r][c4+0]=v.x; S[r][c4+1]=v.y; S[r][c4+2]=v.z; S[r][c4+3]=v.w;
    }
    __syncthreads();
    #pragma unroll
    for (int p = 0; p < 4; ++p) {
        int nr = p * 16 + rq;
        unsigned q0 = cvt_hl(S[c4+0][nr]), q1 = cvt_hl(S[c4+1][nr]);
        unsigned q2 = cvt_hl(S[c4+2][nr]), q3 = cvt_hl(S[c4+3][nr]);
        ushort4_t h, l;
        h[0]=(u16)q0; h[1]=(u16)q1; h[2]=(u16)q2; h[3]=(u16)q3;
        l[0]=(u16)(q0>>16); l[1]=(u16)(q1>>16); l[2]=(u16)(q2>>16); l[3]=(u16)(q3>>16);
        long long ob = (long long)(n0 + nr) * M + m0 + c4;
        *(ushort4_t*)(opH + ob) = h;
        *(ushort4_t*)(opL + ob) = l;
    }
}

__global__ __launch_bounds__(256) void xpose_u16p(
    const u16* __restrict__ inH, const u16* __restrict__ inL,
    u16* __restrict__ outH, u16* __restrict__ outL,
    int M, int N, long long ibs, long long obs)
{
    __shared__ u16 SH[64][66], SL[64][66];
    const u16* ipH = inH + (long long)blockIdx.z * ibs;
    const u16* ipL = inL + (long long)blockIdx.z * ibs;
    u16* opH = outH + (long long)blockIdx.z * obs;
    u16* opL = outL + (long long)blockIdx.z * obs;
    int n0 = blockIdx.x * 64, m0 = blockIdx.y * 64;
    int t = threadIdx.x;
    int c4 = (t & 15) << 2, rq = t >> 4;
    #pragma unroll
    for (int p = 0; p < 4; ++p) {
        int r = p * 16 + rq;
        long long ib = (long long)(m0 + r) * N + n0 + c4;
        ushort4_t vh = *(const ushort4_t*)(ipH + ib);
        ushort4_t vl = *(const ushort4_t*)(ipL + ib);
        SH[r][c4+0]=vh[0]; SH[r][c4+1]=vh[1]; SH[r][c4+2]=vh[2]; SH[r][c4+3]=vh[3];
        SL[r][c4+0]=vl[0]; SL[r][c4+1]=vl[1]; SL[r][c4+2]=vl[2]; SL[r][c4+3]=vl[3];
    }
    __syncthreads();
    #pragma unroll
    for (int p = 0; p < 4; ++p) {
        int nr = p * 16 + rq;
        ushort4_t h, l;
        h[0]=SH[c4+0][nr]; h[1]=SH[c4+1][nr]; h[2]=SH[c4+2][nr]; h[3]=SH[c4+3][nr];
        l[0]=SL[c4+0][nr]; l[1]=SL[c4+1][nr]; l[2]=SL[c4+2][nr]; l[3]=SL[c4+3][nr];
        long long ob = (long long)(n0 + nr) * M + m0 + c4;
        *(ushort4_t*)(opH + ob) = h;
        *(ushort4_t*)(opL + ob) = l;
    }
}

// ---------------- helpers ----------------
__device__ inline float waveMax(float v) {
    #pragma unroll
    for (int o = 32; o; o >>= 1) v = fmaxf(v, __shfl_xor(v, o, 64));
    return v;
}
__device__ inline float waveSum(float v) {
    #pragma unroll
    for (int o = 32; o; o >>= 1) v += __shfl_xor(v, o, 64);
    return v;
}

// fused: all five weights -> hi/lo planes in one launch.
__global__ __launch_bounds__(256) void conv_planes5(
    const float* __restrict__ s0, const float* __restrict__ s1, const float* __restrict__ s2,
    const float* __restrict__ s3, const float* __restrict__ s4,
    u16* h0, u16* l0, u16* h1, u16* l1, u16* h2, u16* l2,
    u16* h3, u16* l3, u16* h4, u16* l4)
{
    const int N0 = 32768, NW = 65536;
    int i = blockIdx.x * 256 + threadIdx.x;
    if (i >= N0 + 4 * NW) return;
    const float* s; u16* h; u16* l; int off;
    if (i < N0) { s = s0; h = h0; l = l0; off = i; }
    else {
        int j = i - N0, seg = j / NW;
        off = j - seg * NW;
        s = seg == 0 ? s1 : seg == 1 ? s2 : seg == 2 ? s3 : s4;
        h = seg == 0 ? h1 : seg == 1 ? h2 : seg == 2 ? h3 : h4;
        l = seg == 0 ? l1 : seg == 1 ? l2 : seg == 2 ? l3 : l4;
    }
    float4 v = ((const float4*)s)[off];
    unsigned p0 = cvt_hl(v.x), p1 = cvt_hl(v.y), p2 = cvt_hl(v.z), p3 = cvt_hl(v.w);
    ushort4_t hv, lv;
    hv[0]=(u16)p0; hv[1]=(u16)p1; hv[2]=(u16)p2; hv[3]=(u16)p3;
    lv[0]=(u16)(p0>>16); lv[1]=(u16)(p1>>16); lv[2]=(u16)(p2>>16); lv[3]=(u16)(p3>>16);
    ((ushort4_t*)h)[off] = hv;
    ((ushort4_t*)l)[off] = lv;
}

// merged: blocks [0, B*R) do the LT softmax (rows of pScoreT, len L);
// blocks [B*R, B*R + B*L/4) do the R softmax, 4 rows/block, one wave per row.
__global__ __launch_bounds__(256) void softmax_both(
    const float* __restrict__ pT, const float* __restrict__ pScore,
    const int* __restrict__ mask,
    u16* __restrict__ ltH, u16* __restrict__ ltL,
    u16* __restrict__ rH, u16* __restrict__ rL)
{
    __shared__ float sm[4], ss[4];
    int bxid = blockIdx.x;
    int lane = threadIdx.x & 63, wid = threadIdx.x >> 6;
    if (bxid < B_ * R_) {
        int zi = bxid;                // b*R + r
        int b = zi >> 8;
        const float* row = pT + (long long)zi * L_;
        const int* mk = mask + (long long)b * L_ * L_;   // row 0 of [L,L]
        float vals[8];
        float mx = -3.4e38f;
        #pragma unroll
        for (int i = 0; i < 8; ++i) {
            int l = threadIdx.x + i * 256;
            float v = row[l];
            if (mk[l] == 0) v = MASK_NEG;
            vals[i] = v; mx = fmaxf(mx, v);
        }
        mx = waveMax(mx);
        if (lane == 0) sm[wid] = mx;
        __syncthreads();
        mx = fmaxf(fmaxf(sm[0], sm[1]), fmaxf(sm[2], sm[3]));
        float sum = 0.0f;
        #pragma unroll
        for (int i = 0; i < 8; ++i) { float e = __expf(vals[i] - mx); vals[i] = e; sum += e; }
        sum = waveSum(sum);
        if (lane == 0) ss[wid] = sum;
        __syncthreads();
        sum = ss[0] + ss[1] + ss[2] + ss[3];
        float inv = 1.0f / sum;
        long long base = (long long)zi * L_;
        #pragma unroll
        for (int i = 0; i < 8; ++i) {
            unsigned p = cvt_hl(vals[i] * inv);
            ltH[base + threadIdx.x + i * 256] = (u16)p;
            ltL[base + threadIdx.x + i * 256] = (u16)(p >> 16);
        }
    } else {
        // R path: wave-per-row, 4 rows/block, float4 loads, no barriers
        long long z = (long long)(bxid - B_ * R_) * 4 + wid;   // b*L + l
        int b = (int)(z >> 11), l = (int)(z & 2047);
        bool pad = (mask[(long long)b * L_ * L_ + l] == 0);
        float4 v = *(const float4*)(pScore + z * R_ + lane * 4);
        if (pad) { v.x = MASK_NEG; v.y = MASK_NEG; v.z = MASK_NEG; v.w = MASK_NEG; }
        float mx = waveMax(fmaxf(fmaxf(v.x, v.y), fmaxf(v.z, v.w)));
        float e0 = __expf(v.x - mx), e1 = __expf(v.y - mx);
        float e2 = __expf(v.z - mx), e3 = __expf(v.w - mx);
        float inv = 1.0f / waveSum(e0 + e1 + e2 + e3);
        unsigned p0 = cvt_hl(e0 * inv), p1 = cvt_hl(e1 * inv);
        unsigned p2 = cvt_hl(e2 * inv), p3 = cvt_hl(e3 * inv);
        ushort4_t h, lo;
        h[0]=(u16)p0; h[1]=(u16)p1; h[2]=(u16)p2; h[3]=(u16)p3;
        lo[0]=(u16)(p0>>16); lo[1]=(u16)(p1>>16); lo[2]=(u16)(p2>>16); lo[3]=(u16)(p3>>16);
        *(ushort4_t*)(rH + z * R_ + lane * 4) = h;
        *(ushort4_t*)(rL + z * R_ + lane * 4) = lo;
    }
}

// wave-per-row softmax over scores (256 cols), 4 rows/block, + offArr
__global__ __launch_bounds__(256) void softmax_alpha4(
    const float* __restrict__ scores, u16* __restrict__ aH, u16* __restrict__ aL,
    float* __restrict__ offArr)
{
    int lane = threadIdx.x & 63, wid = threadIdx.x >> 6;
    long long row = (long long)blockIdx.x * 4 + wid;  // over B*H*R
    int r = (int)(row & 255);
    float4 v = *(const float4*)(scores + row * 256 + lane * 4);
    float mx = waveMax(fmaxf(fmaxf(v.x, v.y), fmaxf(v.z, v.w)));
    float e0 = __expf(v.x - mx), e1 = __expf(v.y - mx);
    float e2 = __expf(v.z - mx), e3 = __expf(v.w - mx);
    float inv = 1.0f / waveSum(e0 + e1 + e2 + e3);
    float a0 = e0 * inv, a1 = e1 * inv, a2 = e2 * inv, a3 = e3 * inv;
    unsigned p0 = cvt_hl(a0), p1 = cvt_hl(a1), p2 = cvt_hl(a2), p3 = cvt_hl(a3);
    ushort4_t h, lo;
    h[0]=(u16)p0; h[1]=(u16)p1; h[2]=(u16)p2; h[3]=(u16)p3;
    lo[0]=(u16)(p0>>16); lo[1]=(u16)(p1>>16); lo[2]=(u16)(p2>>16); lo[3]=(u16)(p3>>16);
    *(ushort4_t*)(aH + row * 256 + lane * 4) = h;
    *(ushort4_t*)(aL + row * 256 + lane * 4) = lo;
    int c = lane * 4;
    float off = (c + 0 == r ? 0.0f : a0) + (c + 1 == r ? 0.0f : a1)
              + (c + 2 == r ? 0.0f : a2) + (c + 3 == r ? 0.0f : a3);
    off = waveSum(off);
    if (lane == 0) offArr[row] = off;
}

__global__ __launch_bounds__(256) void finalize_loss(
    const float* __restrict__ addLossIn, const float* __restrict__ lossAcc,
    const float* __restrict__ offArr, float* __restrict__ out)
{
    __shared__ float red[4];
    float s = 0.0f;
    for (int i = threadIdx.x; i < B_ * H_ * R_; i += 256) s += offArr[i];
    int lane = threadIdx.x & 63, wid = threadIdx.x >> 6;
    s = waveSum(s);
    if (lane == 0) red[wid] = s;
    __syncthreads();
    if (threadIdx.x == 0) {
        float total = red[0] + red[1] + red[2] + red[3];
        out[0] = addLossIn[0]
               + lossAcc[0] * (1.0f / ((float)B_ * R_ * R_))
               + total      * (1.0f / ((float)B_ * H_ * R_ * R_))
               + lossAcc[2] * (1.0f / ((float)B_ * R_ * R_));
    }
}

// ---------------- launch ----------------
extern "C" void kernel_launch(void* const* d_in, const int* in_sizes, int n_in,
                              void* d_out, int out_size, void* d_ws, size_t ws_size,
                              hipStream_t stream)
{
    const float* qx = (const float*)d_in[0];
    const float* kx = (const float*)d_in[1];
    const float* vx = (const float*)d_in[2];
    const float* addLossIn = (const float*)d_in[3];
    const int* mask = (const int*)d_in[4];
    const float* Wp = (const float*)d_in[5];
    const float* WQ = (const float*)d_in[6];
    const float* WK = (const float*)d_in[7];
    const float* WV = (const float*)d_in[8];
    const float* WO = (const float*)d_in[9];

    float* zOut      = (float*)d_out;                             // [B,L,C]
    float* scoresOut = zOut + (long long)B_ * L_ * C_;            // [B,H,R,R]
    float* lossOut   = scoresOut + (long long)B_ * H_ * R_ * R_;  // [1]

    const long long S = (long long)B_ * L_ * R_;    // 4,194,304
    const long long T = (long long)B_ * R_ * C_;    // 1,048,576
    u16* cur = (u16*)d_ws;
    auto takeU = [&](long long n) { u16* p = cur; cur += n; return p; };
    auto takeF = [&](long long n) { float* p = (float*)cur; cur += 2 * n; return p; };

    float* pScore   = takeF(S);          // [B,L,R]
    float* pScoreT  = takeF(S);          // [B,R,L]
    u16* pAlphaH  = takeU(S);            // [B,R,L]
    u16* pAlphaL  = takeU(S);
    u16* pAlpha_H = takeU(S);            // [B,L,R]
    u16* pAlpha_L = takeU(S);
    u16* pATH     = takeU(S);            // [B,R,L]
    u16* pATL     = takeU(S);
    u16* xTH0 = takeU(2*S); u16* xTL0 = takeU(2*S);   // [B,C,L] = 2S per plane
    u16* xTH1 = takeU(2*S); u16* xTL1 = takeU(2*S);
    u16* xTH2 = takeU(2*S); u16* xTL2 = takeU(2*S);
    const long long llRR = (long long)R_ * R_;
    float* Gpart  = takeF(2LL * KS_ * B_ * llRR);   // [2 losses][KS][B][R][R]
    float* Cpart6 = takeF((long long)NKS6_ * 3 * T); // 6b split-K partials
    u16* qrH = takeU(T); u16* qrL = takeU(T);
    u16* krH = takeU(T); u16* krL = takeU(T);
    u16* vrH = takeU(T); u16* vrL = takeU(T);
    u16* qpH = takeU(T); u16* qpL = takeU(T);
    u16* kpH = takeU(T); u16* kpL = takeU(T);
    u16* vpTH = takeU(T); u16* vpTL = takeU(T);
    u16* z1H = takeU(T); u16* z1L = takeU(T);
    u16* z2TH = takeU(T); u16* z2TL = takeU(T);
    u16* alphaH = takeU(S); u16* alphaL = takeU(S);
    u16* WpH = takeU((long long)R_ * C_); u16* WpL = takeU((long long)R_ * C_);
    u16* WQH = takeU((long long)HD_ * C_); u16* WQL = takeU((long long)HD_ * C_);
    u16* WKH = takeU((long long)HD_ * C_); u16* WKL = takeU((long long)HD_ * C_);
    u16* WVH = takeU((long long)HD_ * C_); u16* WVL = takeU((long long)HD_ * C_);
    u16* WOH = takeU((long long)HD_ * C_); u16* WOL = takeU((long long)HD_ * C_);
    float* loss   = takeF(16);
    float* offArr = takeF(B_ * H_ * R_);

    const Ptr3 N3{nullptr, nullptr, nullptr};
    auto P1 = [](const void* p) { return Ptr3{p, p, p}; };
    const long long llRL = (long long)R_ * L_, llLC = (long long)L_ * C_;
    const long long llRC = (long long)R_ * C_, llRHD = (long long)R_ * HD_;
    const long long llHRR = (long long)H_ * R_ * R_;
    const long long llCL = (long long)C_ * L_;
    float* Gpart2 = Gpart + (long long)KS_ * B_ * llRR;

    (void)hipMemsetAsync(loss, 0, 3 * sizeof(float), stream);

    // 0) all weights -> planes, ONE launch (1152 blocks)
    conv_planes5<<<1152, 256, 0, stream>>>(
        Wp, WQ, WK, WV, WO,
        WpH, WpL, WQH, WQL, WKH, WKL, WVH, WVL, WOH, WOL);

    // 1) pScoreT = Wp @ vx^T AND pScore = transposed, fused epilogue (EPI=3)
    gemm_pl<64, 0, 2, 3, false><<<dim3(L_/64, R_/64, B_), 256, 0, stream>>>(
        P1(WpH), P1(WpL), P1(vx), N3, P1(pScoreT), N3,
        P1(pScore), N3, R_, llRL,
        C_, C_, C_, L_, B_,
        0, llLC, llRL, 0, 0, 0, 0, 0, 0, 1.0f);

    // 3) both softmaxes in ONE launch: 2048 LT blocks + 4096 R blocks (wave/row)
    softmax_both<<<B_ * R_ + B_ * L_ / 4, 256, 0, stream>>>(
        pScoreT, pScore, mask, pAlphaH, pAlphaL, pAlpha_H, pAlpha_L);

    // 3b) pAT = transpose(pAlpha_) planes: [L,R] -> [R,L]
    xpose_u16p<<<dim3(R_/64, L_/64, B_), 256, 0, stream>>>(
        pAlpha_H, pAlpha_L, pATH, pATL, L_, R_, llRL, llRL);

    // 4+5) both loss Grams, triangular (3 of 4 tiles), KS=4: grid (3,1,64)=192 blocks,
    //      K-chunk 512 (nt=16, deep pipeline). R30 post-mortem: KS=8 lost to Gpart traffic.
    gemm_gll<0, true, 1, KS_, true><<<dim3(3, 1, 2 * B_ * KS_), 256, 0, stream>>>(
        Ptr3{pAlphaH, pATH, pATH}, N3, Ptr3{pAlphaH, pATH, pATH}, N3,
        Ptr3{Gpart, Gpart2, Gpart2}, N3,
        N3, N3, 0, 0,
        L_, L_, L_, R_, B_ * KS_,
        llRL, llRL, llRR,
        L_ / KS_, L_ / KS_, (long long)B_ * llRR, 1.0f);

    // 6) xT = transpose all three inputs -> planes [C][L] (one launch, z=24)
    //    IMMEDIATELY before 6b: producer->consumer L2 adjacency (R28 lesson)
    xpose_f32p3<<<dim3(C_/64, L_/64, 3 * B_), 256, 0, stream>>>(
        Ptr3{qx, kx, vx}, Ptr3{xTH0, xTH1, xTH2}, Ptr3{xTL0, xTL1, xTL2},
        L_, C_, llLC, llCL, B_);

    // 6b) {q,k,v}r partials = pAlpha @ x : 128^2 gll, KSPLIT=2 -> 384 blocks (nt=32)
    gemm_gll<0, true, 3, NKS6_><<<dim3(C_/128, R_/128, 3 * B_ * NKS6_), 256, 0, stream>>>(
        P1(pAlphaH), P1(pAlphaL),
        Ptr3{xTH0, xTH1, xTH2}, Ptr3{xTL0, xTL1, xTL2},
        Ptr3{Cpart6, Cpart6 + T, Cpart6 + 2 * T}, N3,
        N3, N3, 0, 0,
        L_, L_, L_, C_, B_ * NKS6_,
        llRL, llCL, llRC,
        L_ / NKS6_, L_ / NKS6_, 3 * T, 1.0f);

    // 6c) merged reduce: loss (1024 blocks) + qkv partials (3072 blocks), ONE launch
    reduce_all<<<1024 + (int)(3 * (T >> 2) / 256), 256, 0, stream>>>(
        Gpart, Gpart2, KS_, loss,
        Cpart6, Ptr3{qrH, krH, vrH}, Ptr3{qrL, krL, vrL});

    // 7) projections; vp plain planes are DEAD (only vpT is read) -> null cH for member 2;
    //    fused vpT transpose only for vp (null-guarded cT): grid (4,2,24)
    gemm_gll<3, true, 3, 1><<<dim3(HD_/128, 2, 3 * B_), 256, 0, stream>>>(
        Ptr3{qrH, krH, vrH}, Ptr3{qrL, krL, vrL},
        Ptr3{WQH, WKH, WVH}, Ptr3{WQL, WKL, WVL},
        Ptr3{qpH, kpH, nullptr}, Ptr3{qpL, kpL, nullptr},
        Ptr3{nullptr, nullptr, vpTH}, Ptr3{nullptr, nullptr, vpTL}, R_, llRHD,
        C_, C_, C_, HD_, B_,
        llRC, 0, llRHD,
        0, 0, 0, 1.0f);

    // 8) scores = qp_h @ kp_h^T / 8 : [256,256] x64, K=64 (XCD-swizzled)
    gemm_pl<64, 0, 0, 0, false><<<dim3(4, 4, 64), 256, 0, stream>>>(
        P1(qpH), P1(qpL), P1(kpH), P1(kpL), P1(scoresOut), N3,
        N3, N3, 0, 0,
        DK_, HD_, HD_, R_, 8, 64, 64, llRR, llRHD, llRHD, llHRR,
        0, 0, 0, 0.125f);

    // 9) alpha = softmax(scores) -> planes + offArr (wave/row, 4096 blocks)
    softmax_alpha4<<<B_ * H_ * R_ / 4, 256, 0, stream>>>(scoresOut, alphaH, alphaL, offArr);

    // 10) z1 = alpha @ vp_h : [256,64] x64, K=256 (B = vpT slice, XCD-swizzled)
    gemm_pl<64, 0, 0, 2, false><<<dim3(1, 4, 64), 256, 0, stream>>>(
        P1(alphaH), P1(alphaL), P1(vpTH), P1(vpTL), P1(z1H), P1(z1L),
        N3, N3, 0, 0,
        R_, R_, R_, HD_, 8, llRR, (long long)64 * R_, 64, llHRR, llRHD, llRHD,
        0, 0, 0, 1.0f);

    // 11) z2T only (EPI=5): z2 plain planes are never read; batched grid (8,4,8)
    gemm_pl<64, 0, 0, 5, false><<<dim3(HD_/64, R_/64, B_), 256, 0, stream>>>(
        P1(z1H), P1(z1L), P1(WOH), P1(WOL), N3, N3,
        P1(z2TH), P1(z2TL), R_, llRC,
        HD_, HD_, HD_, C_, B_,
        llRHD, 0, llRC, 0, 0, 0, 0, 0, 0, 1.0f);

    // 12) z = pAlpha_ @ z2 : 128^2 gll counted-vmcnt, grid (4,16,8) = 512 blocks
    gemm_gll<0, false, 3, 1><<<dim3(C_/128, L_/128, B_), 256, 0, stream>>>(
        P1(pAlpha_H), P1(pAlpha_L), P1(z2TH), P1(z2TL), P1(zOut), N3,
        N3, N3, 0, 0,
        R_, R_, R_, C_, B_,
        llRL, llRC, llLC,
        0, 0, 0, 1.0f);

    // 13) addLoss
    finalize_loss<<<1, 256, 0, stream>>>(addLossIn, loss, offArr, lossOut);
}

// Round 32
// 283.718 us; speedup vs baseline: 1.0271x; 1.0111x over previous
//
#include <hip/hip_runtime.h>

#define B_  8
#define L_  2048
#define C_  512
#define R_  256
#define H_  8
#define DK_ 64
#define HD_ 512
#define MASK_NEG (-32767.0f)

typedef __attribute__((ext_vector_type(8))) short short8;
typedef __attribute__((ext_vector_type(8))) unsigned short ushort8;
typedef __attribute__((ext_vector_type(4))) unsigned short ushort4_t;
typedef __attribute__((ext_vector_type(4))) float f32x4;
typedef unsigned short u16;

__device__ inline u16 bf16_rne(float x) {
    unsigned u = __float_as_uint(x);
    return (u16)((u + 0x7FFFu + ((u >> 16) & 1u)) >> 16);
}
__device__ inline unsigned cvt_hl(float x) {
    u16 hh = bf16_rne(x);
    float hf = __uint_as_float(((unsigned)hh) << 16);
    u16 ll = bf16_rne(x - hf);
    return (unsigned)hh | ((unsigned)ll << 16);
}

struct Ptr3 { const void* p0; const void* p1; const void* p2; };

// async global->LDS, 16B per lane; LDS dest = wave-uniform base + lane*16
#define GLL16(g, l) __builtin_amdgcn_global_load_lds( \
    (const __attribute__((address_space(1))) void*)(g), \
    (__attribute__((address_space(3))) void*)(l), 16, 0, 0)

// ---------------- 64x64-tile MFMA plane GEMM (small/medium paths) ----------------
// XCD-swizzled (caller guarantees nwg%8==0).
// EPI: 0 = fp32 C; 2 = hi/lo planes; 3 = fp32 C + fp32 C^T; 4 = planes + transposed planes;
//      5 = transposed planes ONLY.
template<int BN, int AMODE, int BMODE, int EPI, bool TRIPLE, int NTERM = 3, int KSPLIT = 1>
__global__ __launch_bounds__(256) void gemm_pl(
    Ptr3 aH, Ptr3 aL, Ptr3 bH, Ptr3 bL, Ptr3 cH, Ptr3 cL,
    Ptr3 cT1, Ptr3 cT2, int ldct, long long csT,
    int K, int lda, int ldb, int ldc, int divz,
    long long ash, long long bsh, long long csh,
    long long asb, long long bsb, long long csb,
    long long ksa, long long ksb, long long ksc,
    float scale)
{
    constexpr int NF = BN / 32;
    constexpr int XA = (NTERM == 3) ? 64 : 1;
    constexpr int XB = (NTERM == 3) ? BN : 1;
    __shared__ u16 Ahs[64][40], Als[XA][40];
    __shared__ u16 Bhs[BN][40], Bls[XB][40];

    const int gx = gridDim.x, gy = gridDim.y;
    const int nwg = gx * gy * gridDim.z;
    int flat = blockIdx.x + gx * (blockIdx.y + gy * blockIdx.z);
    {
        int q = nwg >> 3;
        int xcd = flat & 7, idx = flat >> 3;
        flat = xcd * q + idx;
    }
    const int bx = flat % gx;
    const int by = (flat / gx) % gy;
    const int z  = flat / (gx * gy);

    const int zb = z / divz;
    const int rem = z - zb * divz;
    const int zh = rem / KSPLIT, ks = rem - zh * KSPLIT;
    const int Keff = K / KSPLIT;
    const void* avH = TRIPLE ? (zb == 0 ? aH.p0 : zb == 1 ? aH.p1 : aH.p2) : aH.p0;
    const void* avL = TRIPLE ? (zb == 0 ? aL.p0 : zb == 1 ? aL.p1 : aL.p2) : aL.p0;
    const void* bvH = TRIPLE ? (zb == 0 ? bH.p0 : zb == 1 ? bH.p1 : bH.p2) : bH.p0;
    const void* bvL = TRIPLE ? (zb == 0 ? bL.p0 : zb == 1 ? bL.p1 : bL.p2) : bL.p0;
    void* cvH = (void*)(TRIPLE ? (zb == 0 ? cH.p0 : zb == 1 ? cH.p1 : cH.p2) : cH.p0);
    void* cvL = (void*)(TRIPLE ? (zb == 0 ? cL.p0 : zb == 1 ? cL.p1 : cL.p2) : cL.p0);
    void* cvT1 = (void*)(TRIPLE ? (zb == 0 ? cT1.p0 : zb == 1 ? cT1.p1 : cT1.p2) : cT1.p0);
    void* cvT2 = (void*)(TRIPLE ? (zb == 0 ? cT2.p0 : zb == 1 ? cT2.p1 : cT2.p2) : cT2.p0);
    const long long ao = (TRIPLE ? 0 : (long long)zb * asb) + (long long)zh * ash + (long long)ks * ksa;
    const long long bo = (TRIPLE ? 0 : (long long)zb * bsb) + (long long)zh * bsh + (long long)ks * ksb;
    const long long co = (TRIPLE ? 0 : (long long)zb * csb) + (long long)zh * csh + (long long)ks * ksc;
    const long long coT = (long long)zh * csT;

    const u16*   AHg = (const u16*)avH + ao;
    const u16*   ALg = (const u16*)avL + ao;
    const u16*   BHg = (const u16*)bvH + bo;
    const u16*   BLg = (const u16*)bvL + bo;
    const float* Bfg = (const float*)bvH + bo;
    float* Cf  = (float*)cvH + co;
    u16*   CHg = (u16*)cvH + co;
    u16*   CLg = (u16*)cvL + co;

    const int m0 = by * 64, n0 = bx * BN;
    const int tid = threadIdx.x;
    const int lane = tid & 63, w = tid >> 6;
    const int wrow = (w >> 1) * 32, wcol = (w & 1) * (BN / 2);
    const int l15 = lane & 15, lg = lane >> 4;

    f32x4 zero = {0.f, 0.f, 0.f, 0.f};
    f32x4 acc[2][NF];
    #pragma unroll
    for (int mf = 0; mf < 2; ++mf)
        #pragma unroll
        for (int nf = 0; nf < NF; ++nf) acc[mf][nf] = zero;

    for (int k0 = 0; k0 < Keff; k0 += 32) {
        {
            int row = tid >> 2, kc = (tid & 3) << 3;
            long long off = (long long)(m0 + row) * lda + (k0 + kc);
            *(ushort8*)&Ahs[row][kc] = *(const ushort8*)(AHg + off);
            if constexpr (NTERM == 3)
                *(ushort8*)&Als[row][kc] = *(const ushort8*)(ALg + off);
        }
        if (BMODE == 0) {
            #pragma unroll
            for (int t = tid; t < BN * 4; t += 256) {
                int row = t >> 2, kc = (t & 3) << 3;
                long long off = (long long)(n0 + row) * ldb + (k0 + kc);
                *(ushort8*)&Bhs[row][kc] = *(const ushort8*)(BHg + off);
                if constexpr (NTERM == 3)
                    *(ushort8*)&Bls[row][kc] = *(const ushort8*)(BLg + off);
            }
        } else { // BMODE == 2: fp32 [N][K]
            #pragma unroll
            for (int t = tid; t < BN * 4; t += 256) {
                int row = t >> 2, kc = (t & 3) << 3;
                const float* s = Bfg + (long long)(n0 + row) * ldb + (k0 + kc);
                float4 v0 = *(const float4*)s, v1 = *(const float4*)(s + 4);
                unsigned p0 = cvt_hl(v0.x), p1 = cvt_hl(v0.y), p2 = cvt_hl(v0.z), p3 = cvt_hl(v0.w);
                unsigned p4 = cvt_hl(v1.x), p5 = cvt_hl(v1.y), p6 = cvt_hl(v1.z), p7 = cvt_hl(v1.w);
                ushort8 h, l;
                h[0]=(u16)p0; h[1]=(u16)p1; h[2]=(u16)p2; h[3]=(u16)p3;
                h[4]=(u16)p4; h[5]=(u16)p5; h[6]=(u16)p6; h[7]=(u16)p7;
                l[0]=(u16)(p0>>16); l[1]=(u16)(p1>>16); l[2]=(u16)(p2>>16); l[3]=(u16)(p3>>16);
                l[4]=(u16)(p4>>16); l[5]=(u16)(p5>>16); l[6]=(u16)(p6>>16); l[7]=(u16)(p7>>16);
                *(ushort8*)&Bhs[row][kc] = h;
                if constexpr (NTERM == 3)
                    *(ushort8*)&Bls[row][kc] = l;
            }
        }
        __syncthreads();

        short8 a_h[2], a_l[2];
        a_h[0] = *(const short8*)&Ahs[wrow +      l15][lg * 8];
        a_h[1] = *(const short8*)&Ahs[wrow + 16 + l15][lg * 8];
        if constexpr (NTERM == 3) {
            a_l[0] = *(const short8*)&Als[wrow +      l15][lg * 8];
            a_l[1] = *(const short8*)&Als[wrow + 16 + l15][lg * 8];
        }
        #pragma unroll
        for (int nf = 0; nf < NF; ++nf) {
            short8 b_h = *(const short8*)&Bhs[wcol + nf * 16 + l15][lg * 8];
            if constexpr (NTERM == 3) {
                short8 b_l = *(const short8*)&Bls[wcol + nf * 16 + l15][lg * 8];
                #pragma unroll
                for (int mf = 0; mf < 2; ++mf) {
                    acc[mf][nf] = __builtin_amdgcn_mfma_f32_16x16x32_bf16(a_h[mf], b_h, acc[mf][nf], 0, 0, 0);
                    acc[mf][nf] = __builtin_amdgcn_mfma_f32_16x16x32_bf16(a_h[mf], b_l, acc[mf][nf], 0, 0, 0);
                    acc[mf][nf] = __builtin_amdgcn_mfma_f32_16x16x32_bf16(a_l[mf], b_h, acc[mf][nf], 0, 0, 0);
                }
            } else {
                #pragma unroll
                for (int mf = 0; mf < 2; ++mf)
                    acc[mf][nf] = __builtin_amdgcn_mfma_f32_16x16x32_bf16(a_h[mf], b_h, acc[mf][nf], 0, 0, 0);
            }
        }
        __syncthreads();
    }

    #pragma unroll
    for (int mf = 0; mf < 2; ++mf)
        #pragma unroll
        for (int nf = 0; nf < NF; ++nf) {
            int row = m0 + wrow + mf * 16 + lg * 4;
            int col = n0 + wcol + nf * 16 + l15;
            if constexpr (EPI == 0 || EPI == 3) {
                #pragma unroll
                for (int j = 0; j < 4; ++j)
                    Cf[(long long)(row + j) * ldc + col] = acc[mf][nf][j] * scale;
                if constexpr (EPI == 3) {
                    float* CfT = (float*)cvT1 + coT;
                    float4 v = make_float4(acc[mf][nf][0] * scale, acc[mf][nf][1] * scale,
                                           acc[mf][nf][2] * scale, acc[mf][nf][3] * scale);
                    *(float4*)(CfT + (long long)col * ldct + row) = v;
                }
            } else {  // EPI 2, 4, 5: planes
                unsigned p[4];
                #pragma unroll
                for (int j = 0; j < 4; ++j) {
                    p[j] = cvt_hl(acc[mf][nf][j] * scale);
                    if constexpr (EPI != 5) {
                        CHg[(long long)(row + j) * ldc + col] = (u16)p[j];
                        CLg[(long long)(row + j) * ldc + col] = (u16)(p[j] >> 16);
                    }
                }
                if constexpr (EPI == 4 || EPI == 5) {
                    u16* CTH = (u16*)cvT1 + coT;
                    u16* CTL = (u16*)cvT2 + coT;
                    ushort4_t h, l;
                    #pragma unroll
                    for (int j = 0; j < 4; ++j) { h[j] = (u16)p[j]; l[j] = (u16)(p[j] >> 16); }
                    *(ushort4_t*)(CTH + (long long)col * ldct + row) = h;
                    *(ushort4_t*)(CTL + (long long)col * ldct + row) = l;
                }
            }
        }
}

// ---------------- 128x128-tile GEMM: gll + counted-vmcnt pipeline ----------------
// EPI: 0 = fp32 C; 2 = planes; 3 = planes + transposed planes.
// Both plain (cH) and transposed (cT1) outputs are null-guarded in EPI>=2 paths.
// TRIANG: grid x enumerates 3 lower-triangle 128^2 tiles of a symmetric 256^2 output.
template<int EPI, bool TRIPLE, int NTERM, int KSPLIT, bool TRIANG = false>
__global__ __launch_bounds__(256) void gemm_gll(
    Ptr3 aH, Ptr3 aL, Ptr3 bH, Ptr3 bL, Ptr3 cH, Ptr3 cL,
    Ptr3 cT1, Ptr3 cT2, int ldct, long long csT,
    int K, int lda, int ldb, int ldc, int divz,
    long long ash, long long bsh, long long csh,
    long long ksa, long long ksb, long long ksc,
    float scale)
{
    constexpr int XA = (NTERM == 3) ? 128 : 1;
    __shared__ u16 Ahs[2][128][32];
    __shared__ u16 Bhs[2][128][32];
    __shared__ u16 Als[XA][32], Bls[XA][32];   // single-buffered lo planes

    const int gx = gridDim.x, gy = gridDim.y;
    const int nwg = gx * gy * gridDim.z;
    int flat = blockIdx.x + gx * (blockIdx.y + gy * blockIdx.z);
    {
        int q = nwg >> 3;                       // nwg % 8 == 0 guaranteed by caller
        int xcd = flat & 7, idx = flat >> 3;
        flat = xcd * q + idx;
    }
    const int bx = flat % gx;
    const int by = (flat / gx) % gy;
    const int z  = flat / (gx * gy);

    const int zb = z / divz;
    const int rem = z - zb * divz;
    const int zh = rem / KSPLIT, ks = rem - zh * KSPLIT;
    const int Keff = K / KSPLIT;
    const void* avH = TRIPLE ? (zb == 0 ? aH.p0 : zb == 1 ? aH.p1 : aH.p2) : aH.p0;
    const void* avL = TRIPLE ? (zb == 0 ? aL.p0 : zb == 1 ? aL.p1 : aL.p2) : aL.p0;
    const void* bvH = TRIPLE ? (zb == 0 ? bH.p0 : zb == 1 ? bH.p1 : bH.p2) : bH.p0;
    const void* bvL = TRIPLE ? (zb == 0 ? bL.p0 : zb == 1 ? bL.p1 : bL.p2) : bL.p0;
    void* cvH = (void*)(TRIPLE ? (zb == 0 ? cH.p0 : zb == 1 ? cH.p1 : cH.p2) : cH.p0);
    void* cvL = (void*)(TRIPLE ? (zb == 0 ? cL.p0 : zb == 1 ? cL.p1 : cL.p2) : cL.p0);
    void* cvT1 = (void*)(TRIPLE ? (zb == 0 ? cT1.p0 : zb == 1 ? cT1.p1 : cT1.p2) : cT1.p0);
    void* cvT2 = (void*)(TRIPLE ? (zb == 0 ? cT2.p0 : zb == 1 ? cT2.p1 : cT2.p2) : cT2.p0);
    const long long ao = (long long)zh * ash + (long long)ks * ksa;
    const long long bo = (long long)zh * bsh + (long long)ks * ksb;
    const long long co = (long long)zh * csh + (long long)ks * ksc;
    const long long coT = (long long)zh * csT;

    const u16* AHg = (const u16*)avH + ao;
    const u16* ALg = (const u16*)avL + ao;
    const u16* BHg = (const u16*)bvH + bo;
    const u16* BLg = (const u16*)bvL + bo;
    float* Cf  = (float*)cvH + co;
    u16*   CHg = (u16*)cvH + co;
    u16*   CLg = (u16*)cvL + co;

    int m0, n0;
    if constexpr (TRIANG) {
        m0 = (bx >= 1) ? 128 : 0;
        n0 = (bx == 2) ? 128 : 0;
    } else {
        m0 = by * 128; n0 = bx * 128;
    }
    const int tid = threadIdx.x;
    const int lane = tid & 63, w = tid >> 6;
    const int wrow = (w >> 1) * 64, wcol = (w & 1) * 64;
    const int l15 = lane & 15, lg = lane >> 4;

    f32x4 zero = {0.f, 0.f, 0.f, 0.f};
    f32x4 acc[4][4];
    #pragma unroll
    for (int mf = 0; mf < 4; ++mf)
        #pragma unroll
        for (int nf = 0; nf < 4; ++nf) acc[mf][nf] = zero;

    const int ric = lane >> 2;
    const int cc  = lane & 3;

    auto STAGE_HI = [&](int bufsel, int k0) {
        #pragma unroll
        for (int i = 0; i < 2; ++i) {
            int chunk = w * 2 + i;
            int row = chunk * 16 + ric;
            int gcol = ((cc ^ ((row >> 1) & 3)) << 3);
            GLL16(AHg + (long long)(m0 + row) * lda + (k0 + gcol), &Ahs[bufsel][chunk * 16][0]);
            GLL16(BHg + (long long)(n0 + row) * ldb + (k0 + gcol), &Bhs[bufsel][chunk * 16][0]);
        }
    };
    auto STAGE_LO = [&](int k0) {
        #pragma unroll
        for (int i = 0; i < 2; ++i) {
            int chunk = w * 2 + i;
            int row = chunk * 16 + ric;
            int gcol = ((cc ^ ((row >> 1) & 3)) << 3);
            GLL16(ALg + (long long)(m0 + row) * lda + (k0 + gcol), &Als[chunk * 16][0]);
            GLL16(BLg + (long long)(n0 + row) * ldb + (k0 + gcol), &Bls[chunk * 16][0]);
        }
    };

    const int nt = Keff / 32;
    int cur = 0;
    STAGE_HI(0, 0);

    for (int t = 0; t < nt; ++t) {
        if constexpr (NTERM == 3) STAGE_LO(t * 32);
        if (t + 1 < nt) {
            STAGE_HI(cur ^ 1, (t + 1) * 32);
            asm volatile("s_waitcnt vmcnt(4)" ::: "memory");
        } else {
            asm volatile("s_waitcnt vmcnt(0)" ::: "memory");
        }
        __builtin_amdgcn_s_barrier();

        short8 a_h[4], a_l[4];
        #pragma unroll
        for (int mf = 0; mf < 4; ++mf) {
            int ar = wrow + mf * 16 + l15;
            int ac = (lg ^ ((ar >> 1) & 3)) << 3;
            a_h[mf] = *(const short8*)&Ahs[cur][ar][ac];
            if constexpr (NTERM == 3) a_l[mf] = *(const short8*)&Als[ar][ac];
        }
        __builtin_amdgcn_s_setprio(1);
        #pragma unroll
        for (int nf = 0; nf < 4; ++nf) {
            int br = wcol + nf * 16 + l15;
            int bc = (lg ^ ((br >> 1) & 3)) << 3;
            short8 b_h = *(const short8*)&Bhs[cur][br][bc];
            if constexpr (NTERM == 3) {
                short8 b_l = *(const short8*)&Bls[br][bc];
                #pragma unroll
                for (int mf = 0; mf < 4; ++mf) {
                    acc[mf][nf] = __builtin_amdgcn_mfma_f32_16x16x32_bf16(a_h[mf], b_h, acc[mf][nf], 0, 0, 0);
                    acc[mf][nf] = __builtin_amdgcn_mfma_f32_16x16x32_bf16(a_h[mf], b_l, acc[mf][nf], 0, 0, 0);
                    acc[mf][nf] = __builtin_amdgcn_mfma_f32_16x16x32_bf16(a_l[mf], b_h, acc[mf][nf], 0, 0, 0);
                }
            } else {
                #pragma unroll
                for (int mf = 0; mf < 4; ++mf)
                    acc[mf][nf] = __builtin_amdgcn_mfma_f32_16x16x32_bf16(a_h[mf], b_h, acc[mf][nf], 0, 0, 0);
            }
        }
        __builtin_amdgcn_s_setprio(0);
        __builtin_amdgcn_s_barrier();
        cur ^= 1;
    }

    #pragma unroll
    for (int mf = 0; mf < 4; ++mf)
        #pragma unroll
        for (int nf = 0; nf < 4; ++nf) {
            int row = m0 + wrow + mf * 16 + lg * 4;
            int col = n0 + wcol + nf * 16 + l15;
            if constexpr (EPI == 0) {
                #pragma unroll
                for (int j = 0; j < 4; ++j)
                    Cf[(long long)(row + j) * ldc + col] = acc[mf][nf][j] * scale;
            } else {  // EPI 2 or 3
                unsigned p[4];
                #pragma unroll
                for (int j = 0; j < 4; ++j) p[j] = cvt_hl(acc[mf][nf][j] * scale);
                if (cvH) {   // null for members whose plain planes are dead
                    #pragma unroll
                    for (int j = 0; j < 4; ++j) {
                        CHg[(long long)(row + j) * ldc + col] = (u16)p[j];
                        CLg[(long long)(row + j) * ldc + col] = (u16)(p[j] >> 16);
                    }
                }
                if constexpr (EPI == 3) {
                    if (cvT1) {  // null for members that don't need the transpose
                        u16* CTH = (u16*)cvT1 + coT;
                        u16* CTL = (u16*)cvT2 + coT;
                        ushort4_t h, l;
                        #pragma unroll
                        for (int j = 0; j < 4; ++j) { h[j] = (u16)p[j]; l[j] = (u16)(p[j] >> 16); }
                        *(ushort4_t*)(CTH + (long long)col * ldct + row) = h;
                        *(ushort4_t*)(CTL + (long long)col * ldct + row) = l;
                    }
                }
            }
        }
}

// ---------------- merged reduce: loss (both Grams, triangular) + qkv split-K ----------------
#define KS_ 4
#define NKS6_ 2
// blocks [0, 1024): loss reduce; blocks [1024, 1024 + 3*T/1024): qkv reduce
__global__ __launch_bounds__(256) void reduce_all(
    const float* __restrict__ G1, const float* __restrict__ G2,
    int nks, float* __restrict__ lossBase,
    const float* __restrict__ Cpart, Ptr3 dstH, Ptr3 dstL)
{
    __shared__ float red[4];
    int lane = threadIdx.x & 63, wid = threadIdx.x >> 6;
    if (blockIdx.x < 1024) {
        const long long N = (long long)B_ * R_ * R_;
        int seg = blockIdx.x >> 9;                 // 0 or 1 (512 blocks each)
        const float* G = seg ? G2 : G1;
        float* lossDst = lossBase + (seg ? 2 : 0);
        long long i4 = ((long long)(blockIdx.x & 511) * 256 + threadIdx.x) << 2;
        float s = 0.0f;
        if (i4 < N) {
            int e = (int)(i4 & (long long)(R_ * R_ - 1));
            int row = e >> 8, c0 = e & 255;
            // upper-right block (row<128, col>=128) never computed: lower mirror counts x2.
            if (!(row < 128 && c0 >= 128)) {
                float4 g = make_float4(0.f, 0.f, 0.f, 0.f);
                for (int ks = 0; ks < nks; ++ks) {
                    float4 v = *(const float4*)(G + (long long)ks * N + i4);
                    g.x += v.x; g.y += v.y; g.z += v.z; g.w += v.w;
                }
                float wgt = (row >= 128 && c0 < 128) ? 2.0f : 1.0f;
                if (row != c0 + 0) s += wgt * g.x * g.x;
                if (row != c0 + 1) s += wgt * g.y * g.y;
                if (row != c0 + 2) s += wgt * g.z * g.z;
                if (row != c0 + 3) s += wgt * g.w * g.w;
            }
        }
        #pragma unroll
        for (int o = 32; o; o >>= 1) s += __shfl_down(s, o, 64);
        if (lane == 0) red[wid] = s;
        __syncthreads();
        if (threadIdx.x == 0) atomicAdd(lossDst, red[0] + red[1] + red[2] + red[3]);
    } else {
        const long long T = (long long)B_ * R_ * C_;
        long long i4 = (long long)(blockIdx.x - 1024) * 256 + threadIdx.x;
        if (i4 >= 3 * (T >> 2)) return;
        int member = (int)(i4 / (T >> 2));
        long long rem = (i4 - (long long)member * (T >> 2)) << 2;
        float4 a = *(const float4*)(Cpart + (long long)member * T + rem);
        #pragma unroll
        for (int ks = 1; ks < NKS6_; ++ks) {
            float4 b = *(const float4*)(Cpart + (long long)ks * 3 * T + (long long)member * T + rem);
            a.x += b.x; a.y += b.y; a.z += b.z; a.w += b.w;
        }
        unsigned q0 = cvt_hl(a.x), q1 = cvt_hl(a.y), q2 = cvt_hl(a.z), q3 = cvt_hl(a.w);
        ushort4_t h, l;
        h[0]=(u16)q0; h[1]=(u16)q1; h[2]=(u16)q2; h[3]=(u16)q3;
        l[0]=(u16)(q0>>16); l[1]=(u16)(q1>>16); l[2]=(u16)(q2>>16); l[3]=(u16)(q3>>16);
        u16* dH = (u16*)(member == 0 ? dstH.p0 : member == 1 ? dstH.p1 : dstH.p2);
        u16* dL = (u16*)(member == 0 ? dstL.p0 : member == 1 ? dstL.p1 : dstL.p2);
        *(ushort4_t*)(dH + rem) = h;
        *(ushort4_t*)(dL + rem) = l;
    }
}

// ---------------- transpose kernels ----------------
__global__ __launch_bounds__(256) void xpose_f32p3(
    Ptr3 src, Ptr3 dstH, Ptr3 dstL,
    int M, int N, long long ibs, long long obs, int divz)
{
    __shared__ float S[64][65];
    int z = blockIdx.z;
    int m = z / divz, b = z - m * divz;
    const float* ip = (const float*)(m == 0 ? src.p0 : m == 1 ? src.p1 : src.p2)
                      + (long long)b * ibs;
    u16* opH = (u16*)(m == 0 ? dstH.p0 : m == 1 ? dstH.p1 : dstH.p2) + (long long)b * obs;
    u16* opL = (u16*)(m == 0 ? dstL.p0 : m == 1 ? dstL.p1 : dstL.p2) + (long long)b * obs;
    int n0 = blockIdx.x * 64, m0 = blockIdx.y * 64;
    int t = threadIdx.x;
    int c4 = (t & 15) << 2, rq = t >> 4;
    #pragma unroll
    for (int p = 0; p < 4; ++p) {
        int r = p * 16 + rq;
        float4 v = *(const float4*)(ip + (long long)(m0 + r) * N + n0 + c4);
        S[r][c4+0]=v.x; S[r][c4+1]=v.y; S[r][c4+2]=v.z; S[r][c4+3]=v.w;
    }
    __syncthreads();
    #pragma unroll
    for (int p = 0; p < 4; ++p) {
        int nr = p * 16 + rq;
        unsigned q0 = cvt_hl(S[c4+0][nr]), q1 = cvt_hl(S[c4+1][nr]);
        unsigned q2 = cvt_hl(S[c4+2][nr]), q3 = cvt_hl(S[c4+3][nr]);
        ushort4_t h, l;
        h[0]=(u16)q0; h[1]=(u16)q1; h[2]=(u16)q2; h[3]=(u16)q3;
        l[0]=(u16)(q0>>16); l[1]=(u16)(q1>>16); l[2]=(u16)(q2>>16); l[3]=(u16)(q3>>16);
        long long ob = (long long)(n0 + nr) * M + m0 + c4;
        *(ushort4_t*)(opH + ob) = h;
        *(ushort4_t*)(opL + ob) = l;
    }
}

__global__ __launch_bounds__(256) void xpose_u16p(
    const u16* __restrict__ inH, const u16* __restrict__ inL,
    u16* __restrict__ outH, u16* __restrict__ outL,
    int M, int N, long long ibs, long long obs)
{
    __shared__ u16 SH[64][66], SL[64][66];
    const u16* ipH = inH + (long long)blockIdx.z * ibs;
    const u16* ipL = inL + (long long)blockIdx.z * ibs;
    u16* opH = outH + (long long)blockIdx.z * obs;
    u16* opL = outL + (long long)blockIdx.z * obs;
    int n0 = blockIdx.x * 64, m0 = blockIdx.y * 64;
    int t = threadIdx.x;
    int c4 = (t & 15) << 2, rq = t >> 4;
    #pragma unroll
    for (int p = 0; p < 4; ++p) {
        int r = p * 16 + rq;
        long long ib = (long long)(m0 + r) * N + n0 + c4;
        ushort4_t vh = *(const ushort4_t*)(ipH + ib);
        ushort4_t vl = *(const ushort4_t*)(ipL + ib);
        SH[r][c4+0]=vh[0]; SH[r][c4+1]=vh[1]; SH[r][c4+2]=vh[2]; SH[r][c4+3]=vh[3];
        SL[r][c4+0]=vl[0]; SL[r][c4+1]=vl[1]; SL[r][c4+2]=vl[2]; SL[r][c4+3]=vl[3];
    }
    __syncthreads();
    #pragma unroll
    for (int p = 0; p < 4; ++p) {
        int nr = p * 16 + rq;
        ushort4_t h, l;
        h[0]=SH[c4+0][nr]; h[1]=SH[c4+1][nr]; h[2]=SH[c4+2][nr]; h[3]=SH[c4+3][nr];
        l[0]=SL[c4+0][nr]; l[1]=SL[c4+1][nr]; l[2]=SL[c4+2][nr]; l[3]=SL[c4+3][nr];
        long long ob = (long long)(n0 + nr) * M + m0 + c4;
        *(ushort4_t*)(opH + ob) = h;
        *(ushort4_t*)(opL + ob) = l;
    }
}

// ---------------- helpers ----------------
__device__ inline float waveMax(float v) {
    #pragma unroll
    for (int o = 32; o; o >>= 1) v = fmaxf(v, __shfl_xor(v, o, 64));
    return v;
}
__device__ inline float waveSum(float v) {
    #pragma unroll
    for (int o = 32; o; o >>= 1) v += __shfl_xor(v, o, 64);
    return v;
}

// fused: all five weights -> hi/lo planes in one launch; block 0 also zeroes loss accumulators.
__global__ __launch_bounds__(256) void conv_planes5(
    const float* __restrict__ s0, const float* __restrict__ s1, const float* __restrict__ s2,
    const float* __restrict__ s3, const float* __restrict__ s4,
    u16* h0, u16* l0, u16* h1, u16* l1, u16* h2, u16* l2,
    u16* h3, u16* l3, u16* h4, u16* l4,
    float* __restrict__ lossZero)
{
    if (blockIdx.x == 0 && threadIdx.x < 3) lossZero[threadIdx.x] = 0.0f;
    const int N0 = 32768, NW = 65536;
    int i = blockIdx.x * 256 + threadIdx.x;
    if (i >= N0 + 4 * NW) return;
    const float* s; u16* h; u16* l; int off;
    if (i < N0) { s = s0; h = h0; l = l0; off = i; }
    else {
        int j = i - N0, seg = j / NW;
        off = j - seg * NW;
        s = seg == 0 ? s1 : seg == 1 ? s2 : seg == 2 ? s3 : s4;
        h = seg == 0 ? h1 : seg == 1 ? h2 : seg == 2 ? h3 : h4;
        l = seg == 0 ? l1 : seg == 1 ? l2 : seg == 2 ? l3 : l4;
    }
    float4 v = ((const float4*)s)[off];
    unsigned p0 = cvt_hl(v.x), p1 = cvt_hl(v.y), p2 = cvt_hl(v.z), p3 = cvt_hl(v.w);
    ushort4_t hv, lv;
    hv[0]=(u16)p0; hv[1]=(u16)p1; hv[2]=(u16)p2; hv[3]=(u16)p3;
    lv[0]=(u16)(p0>>16); lv[1]=(u16)(p1>>16); lv[2]=(u16)(p2>>16); lv[3]=(u16)(p3>>16);
    ((ushort4_t*)h)[off] = hv;
    ((ushort4_t*)l)[off] = lv;
}

// merged: blocks [0, B*R) do the LT softmax (rows of pScoreT, len L);
// blocks [B*R, B*R + B*L/4) do the R softmax, 4 rows/block, one wave per row.
__global__ __launch_bounds__(256) void softmax_both(
    const float* __restrict__ pT, const float* __restrict__ pScore,
    const int* __restrict__ mask,
    u16* __restrict__ ltH, u16* __restrict__ ltL,
    u16* __restrict__ rH, u16* __restrict__ rL)
{
    __shared__ float sm[4], ss[4];
    int bxid = blockIdx.x;
    int lane = threadIdx.x & 63, wid = threadIdx.x >> 6;
    if (bxid < B_ * R_) {
        int zi = bxid;                // b*R + r
        int b = zi >> 8;
        const float* row = pT + (long long)zi * L_;
        const int* mk = mask + (long long)b * L_ * L_;   // row 0 of [L,L]
        float vals[8];
        float mx = -3.4e38f;
        #pragma unroll
        for (int i = 0; i < 8; ++i) {
            int l = threadIdx.x + i * 256;
            float v = row[l];
            if (mk[l] == 0) v = MASK_NEG;
            vals[i] = v; mx = fmaxf(mx, v);
        }
        mx = waveMax(mx);
        if (lane == 0) sm[wid] = mx;
        __syncthreads();
        mx = fmaxf(fmaxf(sm[0], sm[1]), fmaxf(sm[2], sm[3]));
        float sum = 0.0f;
        #pragma unroll
        for (int i = 0; i < 8; ++i) { float e = __expf(vals[i] - mx); vals[i] = e; sum += e; }
        sum = waveSum(sum);
        if (lane == 0) ss[wid] = sum;
        __syncthreads();
        sum = ss[0] + ss[1] + ss[2] + ss[3];
        float inv = 1.0f / sum;
        long long base = (long long)zi * L_;
        #pragma unroll
        for (int i = 0; i < 8; ++i) {
            unsigned p = cvt_hl(vals[i] * inv);
            ltH[base + threadIdx.x + i * 256] = (u16)p;
            ltL[base + threadIdx.x + i * 256] = (u16)(p >> 16);
        }
    } else {
        // R path: wave-per-row, 4 rows/block, float4 loads, no barriers
        long long z = (long long)(bxid - B_ * R_) * 4 + wid;   // b*L + l
        int b = (int)(z >> 11), l = (int)(z & 2047);
        bool pad = (mask[(long long)b * L_ * L_ + l] == 0);
        float4 v = *(const float4*)(pScore + z * R_ + lane * 4);
        if (pad) { v.x = MASK_NEG; v.y = MASK_NEG; v.z = MASK_NEG; v.w = MASK_NEG; }
        float mx = waveMax(fmaxf(fmaxf(v.x, v.y), fmaxf(v.z, v.w)));
        float e0 = __expf(v.x - mx), e1 = __expf(v.y - mx);
        float e2 = __expf(v.z - mx), e3 = __expf(v.w - mx);
        float inv = 1.0f / waveSum(e0 + e1 + e2 + e3);
        unsigned p0 = cvt_hl(e0 * inv), p1 = cvt_hl(e1 * inv);
        unsigned p2 = cvt_hl(e2 * inv), p3 = cvt_hl(e3 * inv);
        ushort4_t h, lo;
        h[0]=(u16)p0; h[1]=(u16)p1; h[2]=(u16)p2; h[3]=(u16)p3;
        lo[0]=(u16)(p0>>16); lo[1]=(u16)(p1>>16); lo[2]=(u16)(p2>>16); lo[3]=(u16)(p3>>16);
        *(ushort4_t*)(rH + z * R_ + lane * 4) = h;
        *(ushort4_t*)(rL + z * R_ + lane * 4) = lo;
    }
}

// wave-per-row softmax over scores (256 cols), 4 rows/block, + offArr
__global__ __launch_bounds__(256) void softmax_alpha4(
    const float* __restrict__ scores, u16* __restrict__ aH, u16* __restrict__ aL,
    float* __restrict__ offArr)
{
    int lane = threadIdx.x & 63, wid = threadIdx.x >> 6;
    long long row = (long long)blockIdx.x * 4 + wid;  // over B*H*R
    int r = (int)(row & 255);
    float4 v = *(const float4*)(scores + row * 256 + lane * 4);
    float mx = waveMax(fmaxf(fmaxf(v.x, v.y), fmaxf(v.z, v.w)));
    float e0 = __expf(v.x - mx), e1 = __expf(v.y - mx);
    float e2 = __expf(v.z - mx), e3 = __expf(v.w - mx);
    float inv = 1.0f / waveSum(e0 + e1 + e2 + e3);
    float a0 = e0 * inv, a1 = e1 * inv, a2 = e2 * inv, a3 = e3 * inv;
    unsigned p0 = cvt_hl(a0), p1 = cvt_hl(a1), p2 = cvt_hl(a2), p3 = cvt_hl(a3);
    ushort4_t h, lo;
    h[0]=(u16)p0; h[1]=(u16)p1; h[2]=(u16)p2; h[3]=(u16)p3;
    lo[0]=(u16)(p0>>16); lo[1]=(u16)(p1>>16); lo[2]=(u16)(p2>>16); lo[3]=(u16)(p3>>16);
    *(ushort4_t*)(aH + row * 256 + lane * 4) = h;
    *(ushort4_t*)(aL + row * 256 + lane * 4) = lo;
    int c = lane * 4;
    float off = (c + 0 == r ? 0.0f : a0) + (c + 1 == r ? 0.0f : a1)
              + (c + 2 == r ? 0.0f : a2) + (c + 3 == r ? 0.0f : a3);
    off = waveSum(off);
    if (lane == 0) offArr[row] = off;
}

__global__ __launch_bounds__(256) void finalize_loss(
    const float* __restrict__ addLossIn, const float* __restrict__ lossAcc,
    const float* __restrict__ offArr, float* __restrict__ out)
{
    __shared__ float red[4];
    float s = 0.0f;
    for (int i = threadIdx.x; i < B_ * H_ * R_; i += 256) s += offArr[i];
    int lane = threadIdx.x & 63, wid = threadIdx.x >> 6;
    s = waveSum(s);
    if (lane == 0) red[wid] = s;
    __syncthreads();
    if (threadIdx.x == 0) {
        float total = red[0] + red[1] + red[2] + red[3];
        out[0] = addLossIn[0]
               + lossAcc[0] * (1.0f / ((float)B_ * R_ * R_))
               + total      * (1.0f / ((float)B_ * H_ * R_ * R_))
               + lossAcc[2] * (1.0f / ((float)B_ * R_ * R_));
    }
}

// ---------------- launch ----------------
extern "C" void kernel_launch(void* const* d_in, const int* in_sizes, int n_in,
                              void* d_out, int out_size, void* d_ws, size_t ws_size,
                              hipStream_t stream)
{
    const float* qx = (const float*)d_in[0];
    const float* kx = (const float*)d_in[1];
    const float* vx = (const float*)d_in[2];
    const float* addLossIn = (const float*)d_in[3];
    const int* mask = (const int*)d_in[4];
    const float* Wp = (const float*)d_in[5];
    const float* WQ = (const float*)d_in[6];
    const float* WK = (const float*)d_in[7];
    const float* WV = (const float*)d_in[8];
    const float* WO = (const float*)d_in[9];

    float* zOut      = (float*)d_out;                             // [B,L,C]
    float* scoresOut = zOut + (long long)B_ * L_ * C_;            // [B,H,R,R]
    float* lossOut   = scoresOut + (long long)B_ * H_ * R_ * R_;  // [1]

    const long long S = (long long)B_ * L_ * R_;    // 4,194,304
    const long long T = (long long)B_ * R_ * C_;    // 1,048,576
    u16* cur = (u16*)d_ws;
    auto takeU = [&](long long n) { u16* p = cur; cur += n; return p; };
    auto takeF = [&](long long n) { float* p = (float*)cur; cur += 2 * n; return p; };

    float* pScore   = takeF(S);          // [B,L,R]
    float* pScoreT  = takeF(S);          // [B,R,L]
    u16* pAlphaH  = takeU(S);            // [B,R,L]
    u16* pAlphaL  = takeU(S);
    u16* pAlpha_H = takeU(S);            // [B,L,R]
    u16* pAlpha_L = takeU(S);
    u16* pATH     = takeU(S);            // [B,R,L]
    u16* pATL     = takeU(S);
    u16* xTH0 = takeU(2*S); u16* xTL0 = takeU(2*S);   // [B,C,L] = 2S per plane
    u16* xTH1 = takeU(2*S); u16* xTL1 = takeU(2*S);
    u16* xTH2 = takeU(2*S); u16* xTL2 = takeU(2*S);
    const long long llRR = (long long)R_ * R_;
    float* Gpart  = takeF(2LL * KS_ * B_ * llRR);   // [2 losses][KS][B][R][R]
    float* Cpart6 = takeF((long long)NKS6_ * 3 * T); // 6b split-K partials
    u16* qrH = takeU(T); u16* qrL = takeU(T);
    u16* krH = takeU(T); u16* krL = takeU(T);
    u16* vrH = takeU(T); u16* vrL = takeU(T);
    u16* qpH = takeU(T); u16* qpL = takeU(T);
    u16* kpH = takeU(T); u16* kpL = takeU(T);
    u16* vpTH = takeU(T); u16* vpTL = takeU(T);
    u16* z1H = takeU(T); u16* z1L = takeU(T);
    u16* z2TH = takeU(T); u16* z2TL = takeU(T);
    u16* alphaH = takeU(S); u16* alphaL = takeU(S);
    u16* WpH = takeU((long long)R_ * C_); u16* WpL = takeU((long long)R_ * C_);
    u16* WQH = takeU((long long)HD_ * C_); u16* WQL = takeU((long long)HD_ * C_);
    u16* WKH = takeU((long long)HD_ * C_); u16* WKL = takeU((long long)HD_ * C_);
    u16* WVH = takeU((long long)HD_ * C_); u16* WVL = takeU((long long)HD_ * C_);
    u16* WOH = takeU((long long)HD_ * C_); u16* WOL = takeU((long long)HD_ * C_);
    float* loss   = takeF(16);
    float* offArr = takeF(B_ * H_ * R_);

    const Ptr3 N3{nullptr, nullptr, nullptr};
    auto P1 = [](const void* p) { return Ptr3{p, p, p}; };
    const long long llRL = (long long)R_ * L_, llLC = (long long)L_ * C_;
    const long long llRC = (long long)R_ * C_, llRHD = (long long)R_ * HD_;
    const long long llHRR = (long long)H_ * R_ * R_;
    const long long llCL = (long long)C_ * L_;
    float* Gpart2 = Gpart + (long long)KS_ * B_ * llRR;

    // 0) all weights -> planes + loss zeroing, ONE launch (1152 blocks; no memset dispatch)
    conv_planes5<<<1152, 256, 0, stream>>>(
        Wp, WQ, WK, WV, WO,
        WpH, WpL, WQH, WQL, WKH, WKL, WVH, WVL, WOH, WOL,
        loss);

    // 1) pScoreT = Wp @ vx^T AND pScore = transposed, fused epilogue (EPI=3)
    gemm_pl<64, 0, 2, 3, false><<<dim3(L_/64, R_/64, B_), 256, 0, stream>>>(
        P1(WpH), P1(WpL), P1(vx), N3, P1(pScoreT), N3,
        P1(pScore), N3, R_, llRL,
        C_, C_, C_, L_, B_,
        0, llLC, llRL, 0, 0, 0, 0, 0, 0, 1.0f);

    // 3) both softmaxes in ONE launch: 2048 LT blocks + 4096 R blocks (wave/row)
    softmax_both<<<B_ * R_ + B_ * L_ / 4, 256, 0, stream>>>(
        pScoreT, pScore, mask, pAlphaH, pAlphaL, pAlpha_H, pAlpha_L);

    // 3b) pAT = transpose(pAlpha_) planes: [L,R] -> [R,L]
    xpose_u16p<<<dim3(R_/64, L_/64, B_), 256, 0, stream>>>(
        pAlpha_H, pAlpha_L, pATH, pATL, L_, R_, llRL, llRL);

    // 4+5) both loss Grams, triangular (3 of 4 tiles), KS=4: grid (3,1,64)=192 blocks,
    //      K-chunk 512 (nt=16, deep pipeline).
    gemm_gll<0, true, 1, KS_, true><<<dim3(3, 1, 2 * B_ * KS_), 256, 0, stream>>>(
        Ptr3{pAlphaH, pATH, pATH}, N3, Ptr3{pAlphaH, pATH, pATH}, N3,
        Ptr3{Gpart, Gpart2, Gpart2}, N3,
        N3, N3, 0, 0,
        L_, L_, L_, R_, B_ * KS_,
        llRL, llRL, llRR,
        L_ / KS_, L_ / KS_, (long long)B_ * llRR, 1.0f);

    // 6) xT = transpose all three inputs -> planes [C][L] (one launch, z=24)
    //    IMMEDIATELY before 6b: producer->consumer L2 adjacency (R28 lesson)
    xpose_f32p3<<<dim3(C_/64, L_/64, 3 * B_), 256, 0, stream>>>(
        Ptr3{qx, kx, vx}, Ptr3{xTH0, xTH1, xTH2}, Ptr3{xTL0, xTL1, xTL2},
        L_, C_, llLC, llCL, B_);

    // 6b) {q,k,v}r partials = pAlpha @ x : 128^2 gll, KSPLIT=2 -> 384 blocks (nt=32)
    gemm_gll<0, true, 3, NKS6_><<<dim3(C_/128, R_/128, 3 * B_ * NKS6_), 256, 0, stream>>>(
        P1(pAlphaH), P1(pAlphaL),
        Ptr3{xTH0, xTH1, xTH2}, Ptr3{xTL0, xTL1, xTL2},
        Ptr3{Cpart6, Cpart6 + T, Cpart6 + 2 * T}, N3,
        N3, N3, 0, 0,
        L_, L_, L_, C_, B_ * NKS6_,
        llRL, llCL, llRC,
        L_ / NKS6_, L_ / NKS6_, 3 * T, 1.0f);

    // 6c) merged reduce: loss (1024 blocks) + qkv partials (3072 blocks), ONE launch
    reduce_all<<<1024 + (int)(3 * (T >> 2) / 256), 256, 0, stream>>>(
        Gpart, Gpart2, KS_, loss,
        Cpart6, Ptr3{qrH, krH, vrH}, Ptr3{qrL, krL, vrL});

    // 7) projections; vp plain planes are DEAD (only vpT is read) -> null cH for member 2;
    //    fused vpT transpose only for vp (null-guarded cT): grid (4,2,24)
    gemm_gll<3, true, 3, 1><<<dim3(HD_/128, 2, 3 * B_), 256, 0, stream>>>(
        Ptr3{qrH, krH, vrH}, Ptr3{qrL, krL, vrL},
        Ptr3{WQH, WKH, WVH}, Ptr3{WQL, WKL, WVL},
        Ptr3{qpH, kpH, nullptr}, Ptr3{qpL, kpL, nullptr},
        Ptr3{nullptr, nullptr, vpTH}, Ptr3{nullptr, nullptr, vpTL}, R_, llRHD,
        C_, C_, C_, HD_, B_,
        llRC, 0, llRHD,
        0, 0, 0, 1.0f);

    // 8) scores = qp_h @ kp_h^T / 8 : [256,256] x64, K=64 (XCD-swizzled)
    gemm_pl<64, 0, 0, 0, false><<<dim3(4, 4, 64), 256, 0, stream>>>(
        P1(qpH), P1(qpL), P1(kpH), P1(kpL), P1(scoresOut), N3,
        N3, N3, 0, 0,
        DK_, HD_, HD_, R_, 8, 64, 64, llRR, llRHD, llRHD, llHRR,
        0, 0, 0, 0.125f);

    // 9) alpha = softmax(scores) -> planes + offArr (wave/row, 4096 blocks)
    softmax_alpha4<<<B_ * H_ * R_ / 4, 256, 0, stream>>>(scoresOut, alphaH, alphaL, offArr);

    // 10) z1 = alpha @ vp_h : [256,64] x64, K=256 (B = vpT slice, XCD-swizzled)
    gemm_pl<64, 0, 0, 2, false><<<dim3(1, 4, 64), 256, 0, stream>>>(
        P1(alphaH), P1(alphaL), P1(vpTH), P1(vpTL), P1(z1H), P1(z1L),
        N3, N3, 0, 0,
        R_, R_, R_, HD_, 8, llRR, (long long)64 * R_, 64, llHRR, llRHD, llRHD,
        0, 0, 0, 1.0f);

    // 11) z2T only (EPI=5): z2 plain planes are never read; batched grid (8,4,8)
    gemm_pl<64, 0, 0, 5, false><<<dim3(HD_/64, R_/64, B_), 256, 0, stream>>>(
        P1(z1H), P1(z1L), P1(WOH), P1(WOL), N3, N3,
        P1(z2TH), P1(z2TL), R_, llRC,
        HD_, HD_, HD_, C_, B_,
        llRHD, 0, llRC, 0, 0, 0, 0, 0, 0, 1.0f);

    // 12) z = pAlpha_ @ z2 : 128^2 gll counted-vmcnt, grid (4,16,8) = 512 blocks
    gemm_gll<0, false, 3, 1><<<dim3(C_/128, L_/128, B_), 256, 0, stream>>>(
        P1(pAlpha_H), P1(pAlpha_L), P1(z2TH), P1(z2TL), P1(zOut), N3,
        N3, N3, 0, 0,
        R_, R_, R_, C_, B_,
        llRL, llRC, llLC,
        0, 0, 0, 1.0f);

    // 13) addLoss
    finalize_loss<<<1, 256, 0, stream>>>(addLossIn, loss, offArr, lossOut);
}

// Round 33
// 281.827 us; speedup vs baseline: 1.0340x; 1.0067x over previous
//
#include <hip/hip_runtime.h>

#define B_  8
#define L_  2048
#define C_  512
#define R_  256
#define H_  8
#define DK_ 64
#define HD_ 512
#define MASK_NEG (-32767.0f)

typedef __attribute__((ext_vector_type(8))) short short8;
typedef __attribute__((ext_vector_type(8))) unsigned short ushort8;
typedef __attribute__((ext_vector_type(4))) unsigned short ushort4_t;
typedef __attribute__((ext_vector_type(4))) float f32x4;
typedef unsigned short u16;

__device__ inline u16 bf16_rne(float x) {
    unsigned u = __float_as_uint(x);
    return (u16)((u + 0x7FFFu + ((u >> 16) & 1u)) >> 16);
}
__device__ inline unsigned cvt_hl(float x) {
    u16 hh = bf16_rne(x);
    float hf = __uint_as_float(((unsigned)hh) << 16);
    u16 ll = bf16_rne(x - hf);
    return (unsigned)hh | ((unsigned)ll << 16);
}

struct Ptr3 { const void* p0; const void* p1; const void* p2; };

__device__ inline float waveMax(float v) {
    #pragma unroll
    for (int o = 32; o; o >>= 1) v = fmaxf(v, __shfl_xor(v, o, 64));
    return v;
}
__device__ inline float waveSum(float v) {
    #pragma unroll
    for (int o = 32; o; o >>= 1) v += __shfl_xor(v, o, 64);
    return v;
}

// async global->LDS, 16B per lane; LDS dest = wave-uniform base + lane*16
#define GLL16(g, l) __builtin_amdgcn_global_load_lds( \
    (const __attribute__((address_space(1))) void*)(g), \
    (__attribute__((address_space(3))) void*)(l), 16, 0, 0)

// ---------------- 64x64-tile MFMA plane GEMM (small/medium paths) ----------------
// XCD-swizzled (caller guarantees nwg%8==0).
// EPI: 0 = fp32 C; 2 = hi/lo planes; 3 = fp32 C + fp32 C^T; 4 = planes + transposed planes;
//      5 = transposed planes ONLY.
template<int BN, int AMODE, int BMODE, int EPI, bool TRIPLE, int NTERM = 3, int KSPLIT = 1>
__global__ __launch_bounds__(256) void gemm_pl(
    Ptr3 aH, Ptr3 aL, Ptr3 bH, Ptr3 bL, Ptr3 cH, Ptr3 cL,
    Ptr3 cT1, Ptr3 cT2, int ldct, long long csT,
    int K, int lda, int ldb, int ldc, int divz,
    long long ash, long long bsh, long long csh,
    long long asb, long long bsb, long long csb,
    long long ksa, long long ksb, long long ksc,
    float scale)
{
    constexpr int NF = BN / 32;
    constexpr int XA = (NTERM == 3) ? 64 : 1;
    constexpr int XB = (NTERM == 3) ? BN : 1;
    __shared__ u16 Ahs[64][40], Als[XA][40];
    __shared__ u16 Bhs[BN][40], Bls[XB][40];

    const int gx = gridDim.x, gy = gridDim.y;
    const int nwg = gx * gy * gridDim.z;
    int flat = blockIdx.x + gx * (blockIdx.y + gy * blockIdx.z);
    {
        int q = nwg >> 3;
        int xcd = flat & 7, idx = flat >> 3;
        flat = xcd * q + idx;
    }
    const int bx = flat % gx;
    const int by = (flat / gx) % gy;
    const int z  = flat / (gx * gy);

    const int zb = z / divz;
    const int rem = z - zb * divz;
    const int zh = rem / KSPLIT, ks = rem - zh * KSPLIT;
    const int Keff = K / KSPLIT;
    const void* avH = TRIPLE ? (zb == 0 ? aH.p0 : zb == 1 ? aH.p1 : aH.p2) : aH.p0;
    const void* avL = TRIPLE ? (zb == 0 ? aL.p0 : zb == 1 ? aL.p1 : aL.p2) : aL.p0;
    const void* bvH = TRIPLE ? (zb == 0 ? bH.p0 : zb == 1 ? bH.p1 : bH.p2) : bH.p0;
    const void* bvL = TRIPLE ? (zb == 0 ? bL.p0 : zb == 1 ? bL.p1 : bL.p2) : bL.p0;
    void* cvH = (void*)(TRIPLE ? (zb == 0 ? cH.p0 : zb == 1 ? cH.p1 : cH.p2) : cH.p0);
    void* cvL = (void*)(TRIPLE ? (zb == 0 ? cL.p0 : zb == 1 ? cL.p1 : cL.p2) : cL.p0);
    void* cvT1 = (void*)(TRIPLE ? (zb == 0 ? cT1.p0 : zb == 1 ? cT1.p1 : cT1.p2) : cT1.p0);
    void* cvT2 = (void*)(TRIPLE ? (zb == 0 ? cT2.p0 : zb == 1 ? cT2.p1 : cT2.p2) : cT2.p0);
    const long long ao = (TRIPLE ? 0 : (long long)zb * asb) + (long long)zh * ash + (long long)ks * ksa;
    const long long bo = (TRIPLE ? 0 : (long long)zb * bsb) + (long long)zh * bsh + (long long)ks * ksb;
    const long long co = (TRIPLE ? 0 : (long long)zb * csb) + (long long)zh * csh + (long long)ks * ksc;
    const long long coT = (long long)zh * csT;

    const u16*   AHg = (const u16*)avH + ao;
    const u16*   ALg = (const u16*)avL + ao;
    const u16*   BHg = (const u16*)bvH + bo;
    const u16*   BLg = (const u16*)bvL + bo;
    const float* Bfg = (const float*)bvH + bo;
    float* Cf  = (float*)cvH + co;
    u16*   CHg = (u16*)cvH + co;
    u16*   CLg = (u16*)cvL + co;

    const int m0 = by * 64, n0 = bx * BN;
    const int tid = threadIdx.x;
    const int lane = tid & 63, w = tid >> 6;
    const int wrow = (w >> 1) * 32, wcol = (w & 1) * (BN / 2);
    const int l15 = lane & 15, lg = lane >> 4;

    f32x4 zero = {0.f, 0.f, 0.f, 0.f};
    f32x4 acc[2][NF];
    #pragma unroll
    for (int mf = 0; mf < 2; ++mf)
        #pragma unroll
        for (int nf = 0; nf < NF; ++nf) acc[mf][nf] = zero;

    for (int k0 = 0; k0 < Keff; k0 += 32) {
        {
            int row = tid >> 2, kc = (tid & 3) << 3;
            long long off = (long long)(m0 + row) * lda + (k0 + kc);
            *(ushort8*)&Ahs[row][kc] = *(const ushort8*)(AHg + off);
            if constexpr (NTERM == 3)
                *(ushort8*)&Als[row][kc] = *(const ushort8*)(ALg + off);
        }
        if (BMODE == 0) {
            #pragma unroll
            for (int t = tid; t < BN * 4; t += 256) {
                int row = t >> 2, kc = (t & 3) << 3;
                long long off = (long long)(n0 + row) * ldb + (k0 + kc);
                *(ushort8*)&Bhs[row][kc] = *(const ushort8*)(BHg + off);
                if constexpr (NTERM == 3)
                    *(ushort8*)&Bls[row][kc] = *(const ushort8*)(BLg + off);
            }
        } else { // BMODE == 2: fp32 [N][K]
            #pragma unroll
            for (int t = tid; t < BN * 4; t += 256) {
                int row = t >> 2, kc = (t & 3) << 3;
                const float* s = Bfg + (long long)(n0 + row) * ldb + (k0 + kc);
                float4 v0 = *(const float4*)s, v1 = *(const float4*)(s + 4);
                unsigned p0 = cvt_hl(v0.x), p1 = cvt_hl(v0.y), p2 = cvt_hl(v0.z), p3 = cvt_hl(v0.w);
                unsigned p4 = cvt_hl(v1.x), p5 = cvt_hl(v1.y), p6 = cvt_hl(v1.z), p7 = cvt_hl(v1.w);
                ushort8 h, l;
                h[0]=(u16)p0; h[1]=(u16)p1; h[2]=(u16)p2; h[3]=(u16)p3;
                h[4]=(u16)p4; h[5]=(u16)p5; h[6]=(u16)p6; h[7]=(u16)p7;
                l[0]=(u16)(p0>>16); l[1]=(u16)(p1>>16); l[2]=(u16)(p2>>16); l[3]=(u16)(p3>>16);
                l[4]=(u16)(p4>>16); l[5]=(u16)(p5>>16); l[6]=(u16)(p6>>16); l[7]=(u16)(p7>>16);
                *(ushort8*)&Bhs[row][kc] = h;
                if constexpr (NTERM == 3)
                    *(ushort8*)&Bls[row][kc] = l;
            }
        }
        __syncthreads();

        short8 a_h[2], a_l[2];
        a_h[0] = *(const short8*)&Ahs[wrow +      l15][lg * 8];
        a_h[1] = *(const short8*)&Ahs[wrow + 16 + l15][lg * 8];
        if constexpr (NTERM == 3) {
            a_l[0] = *(const short8*)&Als[wrow +      l15][lg * 8];
            a_l[1] = *(const short8*)&Als[wrow + 16 + l15][lg * 8];
        }
        #pragma unroll
        for (int nf = 0; nf < NF; ++nf) {
            short8 b_h = *(const short8*)&Bhs[wcol + nf * 16 + l15][lg * 8];
            if constexpr (NTERM == 3) {
                short8 b_l = *(const short8*)&Bls[wcol + nf * 16 + l15][lg * 8];
                #pragma unroll
                for (int mf = 0; mf < 2; ++mf) {
                    acc[mf][nf] = __builtin_amdgcn_mfma_f32_16x16x32_bf16(a_h[mf], b_h, acc[mf][nf], 0, 0, 0);
                    acc[mf][nf] = __builtin_amdgcn_mfma_f32_16x16x32_bf16(a_h[mf], b_l, acc[mf][nf], 0, 0, 0);
                    acc[mf][nf] = __builtin_amdgcn_mfma_f32_16x16x32_bf16(a_l[mf], b_h, acc[mf][nf], 0, 0, 0);
                }
            } else {
                #pragma unroll
                for (int mf = 0; mf < 2; ++mf)
                    acc[mf][nf] = __builtin_amdgcn_mfma_f32_16x16x32_bf16(a_h[mf], b_h, acc[mf][nf], 0, 0, 0);
            }
        }
        __syncthreads();
    }

    #pragma unroll
    for (int mf = 0; mf < 2; ++mf)
        #pragma unroll
        for (int nf = 0; nf < NF; ++nf) {
            int row = m0 + wrow + mf * 16 + lg * 4;
            int col = n0 + wcol + nf * 16 + l15;
            if constexpr (EPI == 0 || EPI == 3) {
                #pragma unroll
                for (int j = 0; j < 4; ++j)
                    Cf[(long long)(row + j) * ldc + col] = acc[mf][nf][j] * scale;
                if constexpr (EPI == 3) {
                    float* CfT = (float*)cvT1 + coT;
                    float4 v = make_float4(acc[mf][nf][0] * scale, acc[mf][nf][1] * scale,
                                           acc[mf][nf][2] * scale, acc[mf][nf][3] * scale);
                    *(float4*)(CfT + (long long)col * ldct + row) = v;
                }
            } else {  // EPI 2, 4, 5: planes
                unsigned p[4];
                #pragma unroll
                for (int j = 0; j < 4; ++j) {
                    p[j] = cvt_hl(acc[mf][nf][j] * scale);
                    if constexpr (EPI != 5) {
                        CHg[(long long)(row + j) * ldc + col] = (u16)p[j];
                        CLg[(long long)(row + j) * ldc + col] = (u16)(p[j] >> 16);
                    }
                }
                if constexpr (EPI == 4 || EPI == 5) {
                    u16* CTH = (u16*)cvT1 + coT;
                    u16* CTL = (u16*)cvT2 + coT;
                    ushort4_t h, l;
                    #pragma unroll
                    for (int j = 0; j < 4; ++j) { h[j] = (u16)p[j]; l[j] = (u16)(p[j] >> 16); }
                    *(ushort4_t*)(CTH + (long long)col * ldct + row) = h;
                    *(ushort4_t*)(CTL + (long long)col * ldct + row) = l;
                }
            }
        }
}

// ---------------- 128x128-tile GEMM: gll + counted-vmcnt pipeline ----------------
// EPI: 0 = fp32 C; 2 = planes; 3 = planes + transposed planes.
// Both plain (cH) and transposed (cT1) outputs are null-guarded in EPI>=2 paths.
// TRIANG: grid x enumerates 3 lower-triangle 128^2 tiles of a symmetric 256^2 output.
// Optional fused finalize-loss tail (block flat==0; all inputs complete before launch).
template<int EPI, bool TRIPLE, int NTERM, int KSPLIT, bool TRIANG = false>
__global__ __launch_bounds__(256) void gemm_gll(
    Ptr3 aH, Ptr3 aL, Ptr3 bH, Ptr3 bL, Ptr3 cH, Ptr3 cL,
    Ptr3 cT1, Ptr3 cT2, int ldct, long long csT,
    int K, int lda, int ldb, int ldc, int divz,
    long long ash, long long bsh, long long csh,
    long long ksa, long long ksb, long long ksc,
    float scale,
    const float* addLossIn = nullptr, const float* lossAcc = nullptr,
    const float* offArr = nullptr, float* lossOut = nullptr)
{
    constexpr int XA = (NTERM == 3) ? 128 : 1;
    __shared__ u16 Ahs[2][128][32];
    __shared__ u16 Bhs[2][128][32];
    __shared__ u16 Als[XA][32], Bls[XA][32];   // single-buffered lo planes
    __shared__ float red2[4];

    const int gx = gridDim.x, gy = gridDim.y;
    const int nwg = gx * gy * gridDim.z;
    int flat = blockIdx.x + gx * (blockIdx.y + gy * blockIdx.z);
    {
        int q = nwg >> 3;                       // nwg % 8 == 0 guaranteed by caller
        int xcd = flat & 7, idx = flat >> 3;
        flat = xcd * q + idx;
    }
    const int bx = flat % gx;
    const int by = (flat / gx) % gy;
    const int z  = flat / (gx * gy);

    const int zb = z / divz;
    const int rem = z - zb * divz;
    const int zh = rem / KSPLIT, ks = rem - zh * KSPLIT;
    const int Keff = K / KSPLIT;
    const void* avH = TRIPLE ? (zb == 0 ? aH.p0 : zb == 1 ? aH.p1 : aH.p2) : aH.p0;
    const void* avL = TRIPLE ? (zb == 0 ? aL.p0 : zb == 1 ? aL.p1 : aL.p2) : aL.p0;
    const void* bvH = TRIPLE ? (zb == 0 ? bH.p0 : zb == 1 ? bH.p1 : bH.p2) : bH.p0;
    const void* bvL = TRIPLE ? (zb == 0 ? bL.p0 : zb == 1 ? bL.p1 : bL.p2) : bL.p0;
    void* cvH = (void*)(TRIPLE ? (zb == 0 ? cH.p0 : zb == 1 ? cH.p1 : cH.p2) : cH.p0);
    void* cvL = (void*)(TRIPLE ? (zb == 0 ? cL.p0 : zb == 1 ? cL.p1 : cL.p2) : cL.p0);
    void* cvT1 = (void*)(TRIPLE ? (zb == 0 ? cT1.p0 : zb == 1 ? cT1.p1 : cT1.p2) : cT1.p0);
    void* cvT2 = (void*)(TRIPLE ? (zb == 0 ? cT2.p0 : zb == 1 ? cT2.p1 : cT2.p2) : cT2.p0);
    const long long ao = (long long)zh * ash + (long long)ks * ksa;
    const long long bo = (long long)zh * bsh + (long long)ks * ksb;
    const long long co = (long long)zh * csh + (long long)ks * ksc;
    const long long coT = (long long)zh * csT;

    const u16* AHg = (const u16*)avH + ao;
    const u16* ALg = (const u16*)avL + ao;
    const u16* BHg = (const u16*)bvH + bo;
    const u16* BLg = (const u16*)bvL + bo;
    float* Cf  = (float*)cvH + co;
    u16*   CHg = (u16*)cvH + co;
    u16*   CLg = (u16*)cvL + co;

    int m0, n0;
    if constexpr (TRIANG) {
        m0 = (bx >= 1) ? 128 : 0;
        n0 = (bx == 2) ? 128 : 0;
    } else {
        m0 = by * 128; n0 = bx * 128;
    }
    const int tid = threadIdx.x;
    const int lane = tid & 63, w = tid >> 6;
    const int wrow = (w >> 1) * 64, wcol = (w & 1) * 64;
    const int l15 = lane & 15, lg = lane >> 4;

    f32x4 zero = {0.f, 0.f, 0.f, 0.f};
    f32x4 acc[4][4];
    #pragma unroll
    for (int mf = 0; mf < 4; ++mf)
        #pragma unroll
        for (int nf = 0; nf < 4; ++nf) acc[mf][nf] = zero;

    const int ric = lane >> 2;
    const int cc  = lane & 3;

    auto STAGE_HI = [&](int bufsel, int k0) {
        #pragma unroll
        for (int i = 0; i < 2; ++i) {
            int chunk = w * 2 + i;
            int row = chunk * 16 + ric;
            int gcol = ((cc ^ ((row >> 1) & 3)) << 3);
            GLL16(AHg + (long long)(m0 + row) * lda + (k0 + gcol), &Ahs[bufsel][chunk * 16][0]);
            GLL16(BHg + (long long)(n0 + row) * ldb + (k0 + gcol), &Bhs[bufsel][chunk * 16][0]);
        }
    };
    auto STAGE_LO = [&](int k0) {
        #pragma unroll
        for (int i = 0; i < 2; ++i) {
            int chunk = w * 2 + i;
            int row = chunk * 16 + ric;
            int gcol = ((cc ^ ((row >> 1) & 3)) << 3);
            GLL16(ALg + (long long)(m0 + row) * lda + (k0 + gcol), &Als[chunk * 16][0]);
            GLL16(BLg + (long long)(n0 + row) * ldb + (k0 + gcol), &Bls[chunk * 16][0]);
        }
    };

    const int nt = Keff / 32;
    int cur = 0;
    STAGE_HI(0, 0);

    for (int t = 0; t < nt; ++t) {
        if constexpr (NTERM == 3) STAGE_LO(t * 32);
        if (t + 1 < nt) {
            STAGE_HI(cur ^ 1, (t + 1) * 32);
            asm volatile("s_waitcnt vmcnt(4)" ::: "memory");
        } else {
            asm volatile("s_waitcnt vmcnt(0)" ::: "memory");
        }
        __builtin_amdgcn_s_barrier();

        short8 a_h[4], a_l[4];
        #pragma unroll
        for (int mf = 0; mf < 4; ++mf) {
            int ar = wrow + mf * 16 + l15;
            int ac = (lg ^ ((ar >> 1) & 3)) << 3;
            a_h[mf] = *(const short8*)&Ahs[cur][ar][ac];
            if constexpr (NTERM == 3) a_l[mf] = *(const short8*)&Als[ar][ac];
        }
        __builtin_amdgcn_s_setprio(1);
        #pragma unroll
        for (int nf = 0; nf < 4; ++nf) {
            int br = wcol + nf * 16 + l15;
            int bc = (lg ^ ((br >> 1) & 3)) << 3;
            short8 b_h = *(const short8*)&Bhs[cur][br][bc];
            if constexpr (NTERM == 3) {
                short8 b_l = *(const short8*)&Bls[br][bc];
                #pragma unroll
                for (int mf = 0; mf < 4; ++mf) {
                    acc[mf][nf] = __builtin_amdgcn_mfma_f32_16x16x32_bf16(a_h[mf], b_h, acc[mf][nf], 0, 0, 0);
                    acc[mf][nf] = __builtin_amdgcn_mfma_f32_16x16x32_bf16(a_h[mf], b_l, acc[mf][nf], 0, 0, 0);
                    acc[mf][nf] = __builtin_amdgcn_mfma_f32_16x16x32_bf16(a_l[mf], b_h, acc[mf][nf], 0, 0, 0);
                }
            } else {
                #pragma unroll
                for (int mf = 0; mf < 4; ++mf)
                    acc[mf][nf] = __builtin_amdgcn_mfma_f32_16x16x32_bf16(a_h[mf], b_h, acc[mf][nf], 0, 0, 0);
            }
        }
        __builtin_amdgcn_s_setprio(0);
        __builtin_amdgcn_s_barrier();
        cur ^= 1;
    }

    #pragma unroll
    for (int mf = 0; mf < 4; ++mf)
        #pragma unroll
        for (int nf = 0; nf < 4; ++nf) {
            int row = m0 + wrow + mf * 16 + lg * 4;
            int col = n0 + wcol + nf * 16 + l15;
            if constexpr (EPI == 0) {
                #pragma unroll
                for (int j = 0; j < 4; ++j)
                    Cf[(long long)(row + j) * ldc + col] = acc[mf][nf][j] * scale;
            } else {  // EPI 2 or 3
                unsigned p[4];
                #pragma unroll
                for (int j = 0; j < 4; ++j) p[j] = cvt_hl(acc[mf][nf][j] * scale);
                if (cvH) {   // null for members whose plain planes are dead
                    #pragma unroll
                    for (int j = 0; j < 4; ++j) {
                        CHg[(long long)(row + j) * ldc + col] = (u16)p[j];
                        CLg[(long long)(row + j) * ldc + col] = (u16)(p[j] >> 16);
                    }
                }
                if constexpr (EPI == 3) {
                    if (cvT1) {  // null for members that don't need the transpose
                        u16* CTH = (u16*)cvT1 + coT;
                        u16* CTL = (u16*)cvT2 + coT;
                        ushort4_t h, l;
                        #pragma unroll
                        for (int j = 0; j < 4; ++j) { h[j] = (u16)p[j]; l[j] = (u16)(p[j] >> 16); }
                        *(ushort4_t*)(CTH + (long long)col * ldct + row) = h;
                        *(ushort4_t*)(CTL + (long long)col * ldct + row) = l;
                    }
                }
            }
        }

    // fused finalize-loss tail (inputs were complete before this kernel launched)
    if (lossOut != nullptr && flat == 0) {
        float s = 0.0f;
        for (int i = tid; i < B_ * H_ * R_; i += 256) s += offArr[i];
        s = waveSum(s);
        if (lane == 0) red2[w] = s;
        __syncthreads();
        if (tid == 0) {
            float total = red2[0] + red2[1] + red2[2] + red2[3];
            lossOut[0] = addLossIn[0]
                       + lossAcc[0] * (1.0f / ((float)B_ * R_ * R_))
                       + total      * (1.0f / ((float)B_ * H_ * R_ * R_))
                       + lossAcc[2] * (1.0f / ((float)B_ * R_ * R_));
        }
    }
}

// ---------------- merged reduce: loss (both Grams, triangular) + qkv split-K ----------------
#define KS_ 4
#define NKS6_ 2
// blocks [0, 1024): loss reduce; blocks [1024, 1024 + 3*T/1024): qkv reduce
__global__ __launch_bounds__(256) void reduce_all(
    const float* __restrict__ G1, const float* __restrict__ G2,
    int nks, float* __restrict__ lossBase,
    const float* __restrict__ Cpart, Ptr3 dstH, Ptr3 dstL)
{
    __shared__ float red[4];
    int lane = threadIdx.x & 63, wid = threadIdx.x >> 6;
    if (blockIdx.x < 1024) {
        const long long N = (long long)B_ * R_ * R_;
        int seg = blockIdx.x >> 9;                 // 0 or 1 (512 blocks each)
        const float* G = seg ? G2 : G1;
        float* lossDst = lossBase + (seg ? 2 : 0);
        long long i4 = ((long long)(blockIdx.x & 511) * 256 + threadIdx.x) << 2;
        float s = 0.0f;
        if (i4 < N) {
            int e = (int)(i4 & (long long)(R_ * R_ - 1));
            int row = e >> 8, c0 = e & 255;
            // upper-right block (row<128, col>=128) never computed: lower mirror counts x2.
            if (!(row < 128 && c0 >= 128)) {
                float4 g = make_float4(0.f, 0.f, 0.f, 0.f);
                for (int ks = 0; ks < nks; ++ks) {
                    float4 v = *(const float4*)(G + (long long)ks * N + i4);
                    g.x += v.x; g.y += v.y; g.z += v.z; g.w += v.w;
                }
                float wgt = (row >= 128 && c0 < 128) ? 2.0f : 1.0f;
                if (row != c0 + 0) s += wgt * g.x * g.x;
                if (row != c0 + 1) s += wgt * g.y * g.y;
                if (row != c0 + 2) s += wgt * g.z * g.z;
                if (row != c0 + 3) s += wgt * g.w * g.w;
            }
        }
        #pragma unroll
        for (int o = 32; o; o >>= 1) s += __shfl_down(s, o, 64);
        if (lane == 0) red[wid] = s;
        __syncthreads();
        if (threadIdx.x == 0) atomicAdd(lossDst, red[0] + red[1] + red[2] + red[3]);
    } else {
        const long long T = (long long)B_ * R_ * C_;
        long long i4 = (long long)(blockIdx.x - 1024) * 256 + threadIdx.x;
        if (i4 >= 3 * (T >> 2)) return;
        int member = (int)(i4 / (T >> 2));
        long long rem = (i4 - (long long)member * (T >> 2)) << 2;
        float4 a = *(const float4*)(Cpart + (long long)member * T + rem);
        #pragma unroll
        for (int ks = 1; ks < NKS6_; ++ks) {
            float4 b = *(const float4*)(Cpart + (long long)ks * 3 * T + (long long)member * T + rem);
            a.x += b.x; a.y += b.y; a.z += b.z; a.w += b.w;
        }
        unsigned q0 = cvt_hl(a.x), q1 = cvt_hl(a.y), q2 = cvt_hl(a.z), q3 = cvt_hl(a.w);
        ushort4_t h, l;
        h[0]=(u16)q0; h[1]=(u16)q1; h[2]=(u16)q2; h[3]=(u16)q3;
        l[0]=(u16)(q0>>16); l[1]=(u16)(q1>>16); l[2]=(u16)(q2>>16); l[3]=(u16)(q3>>16);
        u16* dH = (u16*)(member == 0 ? dstH.p0 : member == 1 ? dstH.p1 : dstH.p2);
        u16* dL = (u16*)(member == 0 ? dstL.p0 : member == 1 ? dstL.p1 : dstL.p2);
        *(ushort4_t*)(dH + rem) = h;
        *(ushort4_t*)(dL + rem) = l;
    }
}

// ---------------- transpose kernels ----------------
__global__ __launch_bounds__(256) void xpose_f32p3(
    Ptr3 src, Ptr3 dstH, Ptr3 dstL,
    int M, int N, long long ibs, long long obs, int divz)
{
    __shared__ float S[64][65];
    int z = blockIdx.z;
    int m = z / divz, b = z - m * divz;
    const float* ip = (const float*)(m == 0 ? src.p0 : m == 1 ? src.p1 : src.p2)
                      + (long long)b * ibs;
    u16* opH = (u16*)(m == 0 ? dstH.p0 : m == 1 ? dstH.p1 : dstH.p2) + (long long)b * obs;
    u16* opL = (u16*)(m == 0 ? dstL.p0 : m == 1 ? dstL.p1 : dstL.p2) + (long long)b * obs;
    int n0 = blockIdx.x * 64, m0 = blockIdx.y * 64;
    int t = threadIdx.x;
    int c4 = (t & 15) << 2, rq = t >> 4;
    #pragma unroll
    for (int p = 0; p < 4; ++p) {
        int r = p * 16 + rq;
        float4 v = *(const float4*)(ip + (long long)(m0 + r) * N + n0 + c4);
        S[r][c4+0]=v.x; S[r][c4+1]=v.y; S[r][c4+2]=v.z; S[r][c4+3]=v.w;
    }
    __syncthreads();
    #pragma unroll
    for (int p = 0; p < 4; ++p) {
        int nr = p * 16 + rq;
        unsigned q0 = cvt_hl(S[c4+0][nr]), q1 = cvt_hl(S[c4+1][nr]);
        unsigned q2 = cvt_hl(S[c4+2][nr]), q3 = cvt_hl(S[c4+3][nr]);
        ushort4_t h, l;
        h[0]=(u16)q0; h[1]=(u16)q1; h[2]=(u16)q2; h[3]=(u16)q3;
        l[0]=(u16)(q0>>16); l[1]=(u16)(q1>>16); l[2]=(u16)(q2>>16); l[3]=(u16)(q3>>16);
        long long ob = (long long)(n0 + nr) * M + m0 + c4;
        *(ushort4_t*)(opH + ob) = h;
        *(ushort4_t*)(opL + ob) = l;
    }
}

__global__ __launch_bounds__(256) void xpose_u16p(
    const u16* __restrict__ inH, const u16* __restrict__ inL,
    u16* __restrict__ outH, u16* __restrict__ outL,
    int M, int N, long long ibs, long long obs)
{
    __shared__ u16 SH[64][66], SL[64][66];
    const u16* ipH = inH + (long long)blockIdx.z * ibs;
    const u16* ipL = inL + (long long)blockIdx.z * ibs;
    u16* opH = outH + (long long)blockIdx.z * obs;
    u16* opL = outL + (long long)blockIdx.z * obs;
    int n0 = blockIdx.x * 64, m0 = blockIdx.y * 64;
    int t = threadIdx.x;
    int c4 = (t & 15) << 2, rq = t >> 4;
    #pragma unroll
    for (int p = 0; p < 4; ++p) {
        int r = p * 16 + rq;
        long long ib = (long long)(m0 + r) * N + n0 + c4;
        ushort4_t vh = *(const ushort4_t*)(ipH + ib);
        ushort4_t vl = *(const ushort4_t*)(ipL + ib);
        SH[r][c4+0]=vh[0]; SH[r][c4+1]=vh[1]; SH[r][c4+2]=vh[2]; SH[r][c4+3]=vh[3];
        SL[r][c4+0]=vl[0]; SL[r][c4+1]=vl[1]; SL[r][c4+2]=vl[2]; SL[r][c4+3]=vl[3];
    }
    __syncthreads();
    #pragma unroll
    for (int p = 0; p < 4; ++p) {
        int nr = p * 16 + rq;
        ushort4_t h, l;
        h[0]=SH[c4+0][nr]; h[1]=SH[c4+1][nr]; h[2]=SH[c4+2][nr]; h[3]=SH[c4+3][nr];
        l[0]=SL[c4+0][nr]; l[1]=SL[c4+1][nr]; l[2]=SL[c4+2][nr]; l[3]=SL[c4+3][nr];
        long long ob = (long long)(n0 + nr) * M + m0 + c4;
        *(ushort4_t*)(opH + ob) = h;
        *(ushort4_t*)(opL + ob) = l;
    }
}

// fused: all five weights -> hi/lo planes in one launch; block 0 also zeroes loss accumulators.
__global__ __launch_bounds__(256) void conv_planes5(
    const float* __restrict__ s0, const float* __restrict__ s1, const float* __restrict__ s2,
    const float* __restrict__ s3, const float* __restrict__ s4,
    u16* h0, u16* l0, u16* h1, u16* l1, u16* h2, u16* l2,
    u16* h3, u16* l3, u16* h4, u16* l4,
    float* __restrict__ lossZero)
{
    if (blockIdx.x == 0 && threadIdx.x < 3) lossZero[threadIdx.x] = 0.0f;
    const int N0 = 32768, NW = 65536;
    int i = blockIdx.x * 256 + threadIdx.x;
    if (i >= N0 + 4 * NW) return;
    const float* s; u16* h; u16* l; int off;
    if (i < N0) { s = s0; h = h0; l = l0; off = i; }
    else {
        int j = i - N0, seg = j / NW;
        off = j - seg * NW;
        s = seg == 0 ? s1 : seg == 1 ? s2 : seg == 2 ? s3 : s4;
        h = seg == 0 ? h1 : seg == 1 ? h2 : seg == 2 ? h3 : h4;
        l = seg == 0 ? l1 : seg == 1 ? l2 : seg == 2 ? l3 : l4;
    }
    float4 v = ((const float4*)s)[off];
    unsigned p0 = cvt_hl(v.x), p1 = cvt_hl(v.y), p2 = cvt_hl(v.z), p3 = cvt_hl(v.w);
    ushort4_t hv, lv;
    hv[0]=(u16)p0; hv[1]=(u16)p1; hv[2]=(u16)p2; hv[3]=(u16)p3;
    lv[0]=(u16)(p0>>16); lv[1]=(u16)(p1>>16); lv[2]=(u16)(p2>>16); lv[3]=(u16)(p3>>16);
    ((ushort4_t*)h)[off] = hv;
    ((ushort4_t*)l)[off] = lv;
}

// merged: blocks [0, B*R) do the LT softmax (rows of pScoreT, len L);
// blocks [B*R, B*R + B*L/4) do the R softmax, 4 rows/block, one wave per row.
__global__ __launch_bounds__(256) void softmax_both(
    const float* __restrict__ pT, const float* __restrict__ pScore,
    const int* __restrict__ mask,
    u16* __restrict__ ltH, u16* __restrict__ ltL,
    u16* __restrict__ rH, u16* __restrict__ rL)
{
    __shared__ float sm[4], ss[4];
    int bxid = blockIdx.x;
    int lane = threadIdx.x & 63, wid = threadIdx.x >> 6;
    if (bxid < B_ * R_) {
        int zi = bxid;                // b*R + r
        int b = zi >> 8;
        const float* row = pT + (long long)zi * L_;
        const int* mk = mask + (long long)b * L_ * L_;   // row 0 of [L,L]
        float vals[8];
        float mx = -3.4e38f;
        #pragma unroll
        for (int i = 0; i < 8; ++i) {
            int l = threadIdx.x + i * 256;
            float v = row[l];
            if (mk[l] == 0) v = MASK_NEG;
            vals[i] = v; mx = fmaxf(mx, v);
        }
        mx = waveMax(mx);
        if (lane == 0) sm[wid] = mx;
        __syncthreads();
        mx = fmaxf(fmaxf(sm[0], sm[1]), fmaxf(sm[2], sm[3]));
        float sum = 0.0f;
        #pragma unroll
        for (int i = 0; i < 8; ++i) { float e = __expf(vals[i] - mx); vals[i] = e; sum += e; }
        sum = waveSum(sum);
        if (lane == 0) ss[wid] = sum;
        __syncthreads();
        sum = ss[0] + ss[1] + ss[2] + ss[3];
        float inv = 1.0f / sum;
        long long base = (long long)zi * L_;
        #pragma unroll
        for (int i = 0; i < 8; ++i) {
            unsigned p = cvt_hl(vals[i] * inv);
            ltH[base + threadIdx.x + i * 256] = (u16)p;
            ltL[base + threadIdx.x + i * 256] = (u16)(p >> 16);
        }
    } else {
        // R path: wave-per-row, 4 rows/block, float4 loads, no barriers
        long long z = (long long)(bxid - B_ * R_) * 4 + wid;   // b*L + l
        int b = (int)(z >> 11), l = (int)(z & 2047);
        bool pad = (mask[(long long)b * L_ * L_ + l] == 0);
        float4 v = *(const float4*)(pScore + z * R_ + lane * 4);
        if (pad) { v.x = MASK_NEG; v.y = MASK_NEG; v.z = MASK_NEG; v.w = MASK_NEG; }
        float mx = waveMax(fmaxf(fmaxf(v.x, v.y), fmaxf(v.z, v.w)));
        float e0 = __expf(v.x - mx), e1 = __expf(v.y - mx);
        float e2 = __expf(v.z - mx), e3 = __expf(v.w - mx);
        float inv = 1.0f / waveSum(e0 + e1 + e2 + e3);
        unsigned p0 = cvt_hl(e0 * inv), p1 = cvt_hl(e1 * inv);
        unsigned p2 = cvt_hl(e2 * inv), p3 = cvt_hl(e3 * inv);
        ushort4_t h, lo;
        h[0]=(u16)p0; h[1]=(u16)p1; h[2]=(u16)p2; h[3]=(u16)p3;
        lo[0]=(u16)(p0>>16); lo[1]=(u16)(p1>>16); lo[2]=(u16)(p2>>16); lo[3]=(u16)(p3>>16);
        *(ushort4_t*)(rH + z * R_ + lane * 4) = h;
        *(ushort4_t*)(rL + z * R_ + lane * 4) = lo;
    }
}

// wave-per-row softmax over scores (256 cols), 4 rows/block, + offArr
__global__ __launch_bounds__(256) void softmax_alpha4(
    const float* __restrict__ scores, u16* __restrict__ aH, u16* __restrict__ aL,
    float* __restrict__ offArr)
{
    int lane = threadIdx.x & 63, wid = threadIdx.x >> 6;
    long long row = (long long)blockIdx.x * 4 + wid;  // over B*H*R
    int r = (int)(row & 255);
    float4 v = *(const float4*)(scores + row * 256 + lane * 4);
    float mx = waveMax(fmaxf(fmaxf(v.x, v.y), fmaxf(v.z, v.w)));
    float e0 = __expf(v.x - mx), e1 = __expf(v.y - mx);
    float e2 = __expf(v.z - mx), e3 = __expf(v.w - mx);
    float inv = 1.0f / waveSum(e0 + e1 + e2 + e3);
    float a0 = e0 * inv, a1 = e1 * inv, a2 = e2 * inv, a3 = e3 * inv;
    unsigned p0 = cvt_hl(a0), p1 = cvt_hl(a1), p2 = cvt_hl(a2), p3 = cvt_hl(a3);
    ushort4_t h, lo;
    h[0]=(u16)p0; h[1]=(u16)p1; h[2]=(u16)p2; h[3]=(u16)p3;
    lo[0]=(u16)(p0>>16); lo[1]=(u16)(p1>>16); lo[2]=(u16)(p2>>16); lo[3]=(u16)(p3>>16);
    *(ushort4_t*)(aH + row * 256 + lane * 4) = h;
    *(ushort4_t*)(aL + row * 256 + lane * 4) = lo;
    int c = lane * 4;
    float off = (c + 0 == r ? 0.0f : a0) + (c + 1 == r ? 0.0f : a1)
              + (c + 2 == r ? 0.0f : a2) + (c + 3 == r ? 0.0f : a3);
    off = waveSum(off);
    if (lane == 0) offArr[row] = off;
}

// ---------------- launch ----------------
extern "C" void kernel_launch(void* const* d_in, const int* in_sizes, int n_in,
                              void* d_out, int out_size, void* d_ws, size_t ws_size,
                              hipStream_t stream)
{
    const float* qx = (const float*)d_in[0];
    const float* kx = (const float*)d_in[1];
    const float* vx = (const float*)d_in[2];
    const float* addLossIn = (const float*)d_in[3];
    const int* mask = (const int*)d_in[4];
    const float* Wp = (const float*)d_in[5];
    const float* WQ = (const float*)d_in[6];
    const float* WK = (const float*)d_in[7];
    const float* WV = (const float*)d_in[8];
    const float* WO = (const float*)d_in[9];

    float* zOut      = (float*)d_out;                             // [B,L,C]
    float* scoresOut = zOut + (long long)B_ * L_ * C_;            // [B,H,R,R]
    float* lossOut   = scoresOut + (long long)B_ * H_ * R_ * R_;  // [1]

    const long long S = (long long)B_ * L_ * R_;    // 4,194,304
    const long long T = (long long)B_ * R_ * C_;    // 1,048,576
    u16* cur = (u16*)d_ws;
    auto takeU = [&](long long n) { u16* p = cur; cur += n; return p; };
    auto takeF = [&](long long n) { float* p = (float*)cur; cur += 2 * n; return p; };

    float* pScore   = takeF(S);          // [B,L,R]
    float* pScoreT  = takeF(S);          // [B,R,L]
    u16* pAlphaH  = takeU(S);            // [B,R,L]
    u16* pAlphaL  = takeU(S);
    u16* pAlpha_H = takeU(S);            // [B,L,R]
    u16* pAlpha_L = takeU(S);
    u16* pATH     = takeU(S);            // [B,R,L]
    u16* pATL     = takeU(S);
    u16* xTH0 = takeU(2*S); u16* xTL0 = takeU(2*S);   // [B,C,L] = 2S per plane
    u16* xTH1 = takeU(2*S); u16* xTL1 = takeU(2*S);
    u16* xTH2 = takeU(2*S); u16* xTL2 = takeU(2*S);
    const long long llRR = (long long)R_ * R_;
    float* Gpart  = takeF(2LL * KS_ * B_ * llRR);   // [2 losses][KS][B][R][R]
    float* Cpart6 = takeF((long long)NKS6_ * 3 * T); // 6b split-K partials
    u16* qrH = takeU(T); u16* qrL = takeU(T);
    u16* krH = takeU(T); u16* krL = takeU(T);
    u16* vrH = takeU(T); u16* vrL = takeU(T);
    u16* qpH = takeU(T); u16* qpL = takeU(T);
    u16* kpH = takeU(T); u16* kpL = takeU(T);
    u16* vpTH = takeU(T); u16* vpTL = takeU(T);
    u16* z1H = takeU(T); u16* z1L = takeU(T);
    u16* z2TH = takeU(T); u16* z2TL = takeU(T);
    u16* alphaH = takeU(S); u16* alphaL = takeU(S);
    u16* WpH = takeU((long long)R_ * C_); u16* WpL = takeU((long long)R_ * C_);
    u16* WQH = takeU((long long)HD_ * C_); u16* WQL = takeU((long long)HD_ * C_);
    u16* WKH = takeU((long long)HD_ * C_); u16* WKL = takeU((long long)HD_ * C_);
    u16* WVH = takeU((long long)HD_ * C_); u16* WVL = takeU((long long)HD_ * C_);
    u16* WOH = takeU((long long)HD_ * C_); u16* WOL = takeU((long long)HD_ * C_);
    float* loss   = takeF(16);
    float* offArr = takeF(B_ * H_ * R_);

    const Ptr3 N3{nullptr, nullptr, nullptr};
    auto P1 = [](const void* p) { return Ptr3{p, p, p}; };
    const long long llRL = (long long)R_ * L_, llLC = (long long)L_ * C_;
    const long long llRC = (long long)R_ * C_, llRHD = (long long)R_ * HD_;
    const long long llHRR = (long long)H_ * R_ * R_;
    const long long llCL = (long long)C_ * L_;
    float* Gpart2 = Gpart + (long long)KS_ * B_ * llRR;

    // 0) all weights -> planes + loss zeroing, ONE launch (1152 blocks; no memset dispatch)
    conv_planes5<<<1152, 256, 0, stream>>>(
        Wp, WQ, WK, WV, WO,
        WpH, WpL, WQH, WQL, WKH, WKL, WVH, WVL, WOH, WOL,
        loss);

    // 1) pScoreT = Wp @ vx^T AND pScore = transposed, fused epilogue (EPI=3)
    gemm_pl<64, 0, 2, 3, false><<<dim3(L_/64, R_/64, B_), 256, 0, stream>>>(
        P1(WpH), P1(WpL), P1(vx), N3, P1(pScoreT), N3,
        P1(pScore), N3, R_, llRL,
        C_, C_, C_, L_, B_,
        0, llLC, llRL, 0, 0, 0, 0, 0, 0, 1.0f);

    // 3) both softmaxes in ONE launch: 2048 LT blocks + 4096 R blocks (wave/row)
    softmax_both<<<B_ * R_ + B_ * L_ / 4, 256, 0, stream>>>(
        pScoreT, pScore, mask, pAlphaH, pAlphaL, pAlpha_H, pAlpha_L);

    // 3b) pAT = transpose(pAlpha_) planes: [L,R] -> [R,L]
    xpose_u16p<<<dim3(R_/64, L_/64, B_), 256, 0, stream>>>(
        pAlpha_H, pAlpha_L, pATH, pATL, L_, R_, llRL, llRL);

    // 4+5) both loss Grams, triangular (3 of 4 tiles), KS=4: grid (3,1,64)=192 blocks,
    //      K-chunk 512 (nt=16, deep pipeline).
    gemm_gll<0, true, 1, KS_, true><<<dim3(3, 1, 2 * B_ * KS_), 256, 0, stream>>>(
        Ptr3{pAlphaH, pATH, pATH}, N3, Ptr3{pAlphaH, pATH, pATH}, N3,
        Ptr3{Gpart, Gpart2, Gpart2}, N3,
        N3, N3, 0, 0,
        L_, L_, L_, R_, B_ * KS_,
        llRL, llRL, llRR,
        L_ / KS_, L_ / KS_, (long long)B_ * llRR, 1.0f);

    // 6) xT = transpose all three inputs -> planes [C][L] (one launch, z=24)
    //    IMMEDIATELY before 6b: producer->consumer L2 adjacency (R28 lesson)
    xpose_f32p3<<<dim3(C_/64, L_/64, 3 * B_), 256, 0, stream>>>(
        Ptr3{qx, kx, vx}, Ptr3{xTH0, xTH1, xTH2}, Ptr3{xTL0, xTL1, xTL2},
        L_, C_, llLC, llCL, B_);

    // 6b) {q,k,v}r partials = pAlpha @ x : 128^2 gll, KSPLIT=2 -> 384 blocks (nt=32)
    gemm_gll<0, true, 3, NKS6_><<<dim3(C_/128, R_/128, 3 * B_ * NKS6_), 256, 0, stream>>>(
        P1(pAlphaH), P1(pAlphaL),
        Ptr3{xTH0, xTH1, xTH2}, Ptr3{xTL0, xTL1, xTL2},
        Ptr3{Cpart6, Cpart6 + T, Cpart6 + 2 * T}, N3,
        N3, N3, 0, 0,
        L_, L_, L_, C_, B_ * NKS6_,
        llRL, llCL, llRC,
        L_ / NKS6_, L_ / NKS6_, 3 * T, 1.0f);

    // 6c) merged reduce: loss (1024 blocks) + qkv partials (3072 blocks), ONE launch
    reduce_all<<<1024 + (int)(3 * (T >> 2) / 256), 256, 0, stream>>>(
        Gpart, Gpart2, KS_, loss,
        Cpart6, Ptr3{qrH, krH, vrH}, Ptr3{qrL, krL, vrL});

    // 7) projections; vp plain planes are DEAD (only vpT is read) -> null cH for member 2;
    //    fused vpT transpose only for vp (null-guarded cT): grid (4,2,24)
    gemm_gll<3, true, 3, 1><<<dim3(HD_/128, 2, 3 * B_), 256, 0, stream>>>(
        Ptr3{qrH, krH, vrH}, Ptr3{qrL, krL, vrL},
        Ptr3{WQH, WKH, WVH}, Ptr3{WQL, WKL, WVL},
        Ptr3{qpH, kpH, nullptr}, Ptr3{qpL, kpL, nullptr},
        Ptr3{nullptr, nullptr, vpTH}, Ptr3{nullptr, nullptr, vpTL}, R_, llRHD,
        C_, C_, C_, HD_, B_,
        llRC, 0, llRHD,
        0, 0, 0, 1.0f);

    // 8) scores = qp_h @ kp_h^T / 8 : [256,256] x64, K=64 (XCD-swizzled)
    gemm_pl<64, 0, 0, 0, false><<<dim3(4, 4, 64), 256, 0, stream>>>(
        P1(qpH), P1(qpL), P1(kpH), P1(kpL), P1(scoresOut), N3,
        N3, N3, 0, 0,
        DK_, HD_, HD_, R_, 8, 64, 64, llRR, llRHD, llRHD, llHRR,
        0, 0, 0, 0.125f);

    // 9) alpha = softmax(scores) -> planes + offArr (wave/row, 4096 blocks)
    softmax_alpha4<<<B_ * H_ * R_ / 4, 256, 0, stream>>>(scoresOut, alphaH, alphaL, offArr);

    // 10) z1 = alpha @ vp_h : [256,64] x64, K=256 (B = vpT slice, XCD-swizzled)
    gemm_pl<64, 0, 0, 2, false><<<dim3(1, 4, 64), 256, 0, stream>>>(
        P1(alphaH), P1(alphaL), P1(vpTH), P1(vpTL), P1(z1H), P1(z1L),
        N3, N3, 0, 0,
        R_, R_, R_, HD_, 8, llRR, (long long)64 * R_, 64, llHRR, llRHD, llRHD,
        0, 0, 0, 1.0f);

    // 11) z2T only (EPI=5): z2 plain planes are never read; batched grid (8,4,8)
    gemm_pl<64, 0, 0, 5, false><<<dim3(HD_/64, R_/64, B_), 256, 0, stream>>>(
        P1(z1H), P1(z1L), P1(WOH), P1(WOL), N3, N3,
        P1(z2TH), P1(z2TL), R_, llRC,
        HD_, HD_, HD_, C_, B_,
        llRHD, 0, llRC, 0, 0, 0, 0, 0, 0, 1.0f);

    // 12) z = pAlpha_ @ z2 + fused finalize-loss tail (block 0): no separate launch
    gemm_gll<0, false, 3, 1><<<dim3(C_/128, L_/128, B_), 256, 0, stream>>>(
        P1(pAlpha_H), P1(pAlpha_L), P1(z2TH), P1(z2TL), P1(zOut), N3,
        N3, N3, 0, 0,
        R_, R_, R_, C_, B_,
        llRL, llRC, llLC,
        0, 0, 0, 1.0f,
        addLossIn, loss, offArr, lossOut);
}

// Round 34
// 280.718 us; speedup vs baseline: 1.0381x; 1.0040x over previous
//
#include <hip/hip_runtime.h>

#define B_  8
#define L_  2048
#define C_  512
#define R_  256
#define H_  8
#define DK_ 64
#define HD_ 512
#define MASK_NEG (-32767.0f)

typedef __attribute__((ext_vector_type(8))) short short8;
typedef __attribute__((ext_vector_type(8))) unsigned short ushort8;
typedef __attribute__((ext_vector_type(4))) unsigned short ushort4_t;
typedef __attribute__((ext_vector_type(4))) float f32x4;
typedef unsigned short u16;

__device__ inline u16 bf16_rne(float x) {
    unsigned u = __float_as_uint(x);
    return (u16)((u + 0x7FFFu + ((u >> 16) & 1u)) >> 16);
}
__device__ inline unsigned cvt_hl(float x) {
    u16 hh = bf16_rne(x);
    float hf = __uint_as_float(((unsigned)hh) << 16);
    u16 ll = bf16_rne(x - hf);
    return (unsigned)hh | ((unsigned)ll << 16);
}

struct Ptr3 { const void* p0; const void* p1; const void* p2; };

__device__ inline float waveMax(float v) {
    #pragma unroll
    for (int o = 32; o; o >>= 1) v = fmaxf(v, __shfl_xor(v, o, 64));
    return v;
}
__device__ inline float waveSum(float v) {
    #pragma unroll
    for (int o = 32; o; o >>= 1) v += __shfl_xor(v, o, 64);
    return v;
}

// async global->LDS, 16B per lane; LDS dest = wave-uniform base + lane*16
#define GLL16(g, l) __builtin_amdgcn_global_load_lds( \
    (const __attribute__((address_space(1))) void*)(g), \
    (__attribute__((address_space(3))) void*)(l), 16, 0, 0)

// ---------------- 64x64-tile MFMA plane GEMM (small/medium paths) ----------------
// XCD-swizzled (caller guarantees nwg%8==0).
// EPI: 0 = fp32 C; 2 = hi/lo planes; 3 = fp32 C + fp32 C^T; 4 = planes + transposed planes;
//      5 = transposed planes ONLY.
template<int BN, int AMODE, int BMODE, int EPI, bool TRIPLE, int NTERM = 3, int KSPLIT = 1>
__global__ __launch_bounds__(256) void gemm_pl(
    Ptr3 aH, Ptr3 aL, Ptr3 bH, Ptr3 bL, Ptr3 cH, Ptr3 cL,
    Ptr3 cT1, Ptr3 cT2, int ldct, long long csT,
    int K, int lda, int ldb, int ldc, int divz,
    long long ash, long long bsh, long long csh,
    long long asb, long long bsb, long long csb,
    long long ksa, long long ksb, long long ksc,
    float scale)
{
    constexpr int NF = BN / 32;
    constexpr int XA = (NTERM == 3) ? 64 : 1;
    constexpr int XB = (NTERM == 3) ? BN : 1;
    __shared__ u16 Ahs[64][40], Als[XA][40];
    __shared__ u16 Bhs[BN][40], Bls[XB][40];

    const int gx = gridDim.x, gy = gridDim.y;
    const int nwg = gx * gy * gridDim.z;
    int flat = blockIdx.x + gx * (blockIdx.y + gy * blockIdx.z);
    {
        int q = nwg >> 3;
        int xcd = flat & 7, idx = flat >> 3;
        flat = xcd * q + idx;
    }
    const int bx = flat % gx;
    const int by = (flat / gx) % gy;
    const int z  = flat / (gx * gy);

    const int zb = z / divz;
    const int rem = z - zb * divz;
    const int zh = rem / KSPLIT, ks = rem - zh * KSPLIT;
    const int Keff = K / KSPLIT;
    const void* avH = TRIPLE ? (zb == 0 ? aH.p0 : zb == 1 ? aH.p1 : aH.p2) : aH.p0;
    const void* avL = TRIPLE ? (zb == 0 ? aL.p0 : zb == 1 ? aL.p1 : aL.p2) : aL.p0;
    const void* bvH = TRIPLE ? (zb == 0 ? bH.p0 : zb == 1 ? bH.p1 : bH.p2) : bH.p0;
    const void* bvL = TRIPLE ? (zb == 0 ? bL.p0 : zb == 1 ? bL.p1 : bL.p2) : bL.p0;
    void* cvH = (void*)(TRIPLE ? (zb == 0 ? cH.p0 : zb == 1 ? cH.p1 : cH.p2) : cH.p0);
    void* cvL = (void*)(TRIPLE ? (zb == 0 ? cL.p0 : zb == 1 ? cL.p1 : cL.p2) : cL.p0);
    void* cvT1 = (void*)(TRIPLE ? (zb == 0 ? cT1.p0 : zb == 1 ? cT1.p1 : cT1.p2) : cT1.p0);
    void* cvT2 = (void*)(TRIPLE ? (zb == 0 ? cT2.p0 : zb == 1 ? cT2.p1 : cT2.p2) : cT2.p0);
    const long long ao = (TRIPLE ? 0 : (long long)zb * asb) + (long long)zh * ash + (long long)ks * ksa;
    const long long bo = (TRIPLE ? 0 : (long long)zb * bsb) + (long long)zh * bsh + (long long)ks * ksb;
    const long long co = (TRIPLE ? 0 : (long long)zb * csb) + (long long)zh * csh + (long long)ks * ksc;
    const long long coT = (long long)zh * csT;

    const u16*   AHg = (const u16*)avH + ao;
    const u16*   ALg = (const u16*)avL + ao;
    const u16*   BHg = (const u16*)bvH + bo;
    const u16*   BLg = (const u16*)bvL + bo;
    const float* Bfg = (const float*)bvH + bo;
    float* Cf  = (float*)cvH + co;
    u16*   CHg = (u16*)cvH + co;
    u16*   CLg = (u16*)cvL + co;

    const int m0 = by * 64, n0 = bx * BN;
    const int tid = threadIdx.x;
    const int lane = tid & 63, w = tid >> 6;
    const int wrow = (w >> 1) * 32, wcol = (w & 1) * (BN / 2);
    const int l15 = lane & 15, lg = lane >> 4;

    f32x4 zero = {0.f, 0.f, 0.f, 0.f};
    f32x4 acc[2][NF];
    #pragma unroll
    for (int mf = 0; mf < 2; ++mf)
        #pragma unroll
        for (int nf = 0; nf < NF; ++nf) acc[mf][nf] = zero;

    for (int k0 = 0; k0 < Keff; k0 += 32) {
        {
            int row = tid >> 2, kc = (tid & 3) << 3;
            long long off = (long long)(m0 + row) * lda + (k0 + kc);
            *(ushort8*)&Ahs[row][kc] = *(const ushort8*)(AHg + off);
            if constexpr (NTERM == 3)
                *(ushort8*)&Als[row][kc] = *(const ushort8*)(ALg + off);
        }
        if (BMODE == 0) {
            #pragma unroll
            for (int t = tid; t < BN * 4; t += 256) {
                int row = t >> 2, kc = (t & 3) << 3;
                long long off = (long long)(n0 + row) * ldb + (k0 + kc);
                *(ushort8*)&Bhs[row][kc] = *(const ushort8*)(BHg + off);
                if constexpr (NTERM == 3)
                    *(ushort8*)&Bls[row][kc] = *(const ushort8*)(BLg + off);
            }
        } else { // BMODE == 2: fp32 [N][K]
            #pragma unroll
            for (int t = tid; t < BN * 4; t += 256) {
                int row = t >> 2, kc = (t & 3) << 3;
                const float* s = Bfg + (long long)(n0 + row) * ldb + (k0 + kc);
                float4 v0 = *(const float4*)s, v1 = *(const float4*)(s + 4);
                unsigned p0 = cvt_hl(v0.x), p1 = cvt_hl(v0.y), p2 = cvt_hl(v0.z), p3 = cvt_hl(v0.w);
                unsigned p4 = cvt_hl(v1.x), p5 = cvt_hl(v1.y), p6 = cvt_hl(v1.z), p7 = cvt_hl(v1.w);
                ushort8 h, l;
                h[0]=(u16)p0; h[1]=(u16)p1; h[2]=(u16)p2; h[3]=(u16)p3;
                h[4]=(u16)p4; h[5]=(u16)p5; h[6]=(u16)p6; h[7]=(u16)p7;
                l[0]=(u16)(p0>>16); l[1]=(u16)(p1>>16); l[2]=(u16)(p2>>16); l[3]=(u16)(p3>>16);
                l[4]=(u16)(p4>>16); l[5]=(u16)(p5>>16); l[6]=(u16)(p6>>16); l[7]=(u16)(p7>>16);
                *(ushort8*)&Bhs[row][kc] = h;
                if constexpr (NTERM == 3)
                    *(ushort8*)&Bls[row][kc] = l;
            }
        }
        __syncthreads();

        short8 a_h[2], a_l[2];
        a_h[0] = *(const short8*)&Ahs[wrow +      l15][lg * 8];
        a_h[1] = *(const short8*)&Ahs[wrow + 16 + l15][lg * 8];
        if constexpr (NTERM == 3) {
            a_l[0] = *(const short8*)&Als[wrow +      l15][lg * 8];
            a_l[1] = *(const short8*)&Als[wrow + 16 + l15][lg * 8];
        }
        #pragma unroll
        for (int nf = 0; nf < NF; ++nf) {
            short8 b_h = *(const short8*)&Bhs[wcol + nf * 16 + l15][lg * 8];
            if constexpr (NTERM == 3) {
                short8 b_l = *(const short8*)&Bls[wcol + nf * 16 + l15][lg * 8];
                #pragma unroll
                for (int mf = 0; mf < 2; ++mf) {
                    acc[mf][nf] = __builtin_amdgcn_mfma_f32_16x16x32_bf16(a_h[mf], b_h, acc[mf][nf], 0, 0, 0);
                    acc[mf][nf] = __builtin_amdgcn_mfma_f32_16x16x32_bf16(a_h[mf], b_l, acc[mf][nf], 0, 0, 0);
                    acc[mf][nf] = __builtin_amdgcn_mfma_f32_16x16x32_bf16(a_l[mf], b_h, acc[mf][nf], 0, 0, 0);
                }
            } else {
                #pragma unroll
                for (int mf = 0; mf < 2; ++mf)
                    acc[mf][nf] = __builtin_amdgcn_mfma_f32_16x16x32_bf16(a_h[mf], b_h, acc[mf][nf], 0, 0, 0);
            }
        }
        __syncthreads();
    }

    #pragma unroll
    for (int mf = 0; mf < 2; ++mf)
        #pragma unroll
        for (int nf = 0; nf < NF; ++nf) {
            int row = m0 + wrow + mf * 16 + lg * 4;
            int col = n0 + wcol + nf * 16 + l15;
            if constexpr (EPI == 0 || EPI == 3) {
                #pragma unroll
                for (int j = 0; j < 4; ++j)
                    Cf[(long long)(row + j) * ldc + col] = acc[mf][nf][j] * scale;
                if constexpr (EPI == 3) {
                    float* CfT = (float*)cvT1 + coT;
                    float4 v = make_float4(acc[mf][nf][0] * scale, acc[mf][nf][1] * scale,
                                           acc[mf][nf][2] * scale, acc[mf][nf][3] * scale);
                    *(float4*)(CfT + (long long)col * ldct + row) = v;
                }
            } else {  // EPI 2, 4, 5: planes
                unsigned p[4];
                #pragma unroll
                for (int j = 0; j < 4; ++j) {
                    p[j] = cvt_hl(acc[mf][nf][j] * scale);
                    if constexpr (EPI != 5) {
                        CHg[(long long)(row + j) * ldc + col] = (u16)p[j];
                        CLg[(long long)(row + j) * ldc + col] = (u16)(p[j] >> 16);
                    }
                }
                if constexpr (EPI == 4 || EPI == 5) {
                    u16* CTH = (u16*)cvT1 + coT;
                    u16* CTL = (u16*)cvT2 + coT;
                    ushort4_t h, l;
                    #pragma unroll
                    for (int j = 0; j < 4; ++j) { h[j] = (u16)p[j]; l[j] = (u16)(p[j] >> 16); }
                    *(ushort4_t*)(CTH + (long long)col * ldct + row) = h;
                    *(ushort4_t*)(CTL + (long long)col * ldct + row) = l;
                }
            }
        }
}

// ---------------- 128x128-tile GEMM: gll + counted-vmcnt pipeline ----------------
// EPI: 0 = fp32 C; 2 = planes; 3 = planes + transposed planes.
// Both plain (cH) and transposed (cT1) outputs are null-guarded in EPI>=2 paths.
// TRIANG: grid x enumerates 3 lower-triangle 128^2 tiles of a symmetric 256^2 output.
// Optional fused finalize-loss tail (block flat==0; all inputs complete before launch).
template<int EPI, bool TRIPLE, int NTERM, int KSPLIT, bool TRIANG = false>
__global__ __launch_bounds__(256) void gemm_gll(
    Ptr3 aH, Ptr3 aL, Ptr3 bH, Ptr3 bL, Ptr3 cH, Ptr3 cL,
    Ptr3 cT1, Ptr3 cT2, int ldct, long long csT,
    int K, int lda, int ldb, int ldc, int divz,
    long long ash, long long bsh, long long csh,
    long long ksa, long long ksb, long long ksc,
    float scale,
    const float* addLossIn = nullptr, const float* lossAcc = nullptr,
    const float* offArr = nullptr, float* lossOut = nullptr)
{
    constexpr int XA = (NTERM == 3) ? 128 : 1;
    __shared__ u16 Ahs[2][128][32];
    __shared__ u16 Bhs[2][128][32];
    __shared__ u16 Als[XA][32], Bls[XA][32];   // single-buffered lo planes
    __shared__ float red2[4];

    const int gx = gridDim.x, gy = gridDim.y;
    const int nwg = gx * gy * gridDim.z;
    int flat = blockIdx.x + gx * (blockIdx.y + gy * blockIdx.z);
    {
        int q = nwg >> 3;                       // nwg % 8 == 0 guaranteed by caller
        int xcd = flat & 7, idx = flat >> 3;
        flat = xcd * q + idx;
    }
    const int bx = flat % gx;
    const int by = (flat / gx) % gy;
    const int z  = flat / (gx * gy);

    const int zb = z / divz;
    const int rem = z - zb * divz;
    const int zh = rem / KSPLIT, ks = rem - zh * KSPLIT;
    const int Keff = K / KSPLIT;
    const void* avH = TRIPLE ? (zb == 0 ? aH.p0 : zb == 1 ? aH.p1 : aH.p2) : aH.p0;
    const void* avL = TRIPLE ? (zb == 0 ? aL.p0 : zb == 1 ? aL.p1 : aL.p2) : aL.p0;
    const void* bvH = TRIPLE ? (zb == 0 ? bH.p0 : zb == 1 ? bH.p1 : bH.p2) : bH.p0;
    const void* bvL = TRIPLE ? (zb == 0 ? bL.p0 : zb == 1 ? bL.p1 : bL.p2) : bL.p0;
    void* cvH = (void*)(TRIPLE ? (zb == 0 ? cH.p0 : zb == 1 ? cH.p1 : cH.p2) : cH.p0);
    void* cvL = (void*)(TRIPLE ? (zb == 0 ? cL.p0 : zb == 1 ? cL.p1 : cL.p2) : cL.p0);
    void* cvT1 = (void*)(TRIPLE ? (zb == 0 ? cT1.p0 : zb == 1 ? cT1.p1 : cT1.p2) : cT1.p0);
    void* cvT2 = (void*)(TRIPLE ? (zb == 0 ? cT2.p0 : zb == 1 ? cT2.p1 : cT2.p2) : cT2.p0);
    const long long ao = (long long)zh * ash + (long long)ks * ksa;
    const long long bo = (long long)zh * bsh + (long long)ks * ksb;
    const long long co = (long long)zh * csh + (long long)ks * ksc;
    const long long coT = (long long)zh * csT;

    const u16* AHg = (const u16*)avH + ao;
    const u16* ALg = (const u16*)avL + ao;
    const u16* BHg = (const u16*)bvH + bo;
    const u16* BLg = (const u16*)bvL + bo;
    float* Cf  = (float*)cvH + co;
    u16*   CHg = (u16*)cvH + co;
    u16*   CLg = (u16*)cvL + co;

    int m0, n0;
    if constexpr (TRIANG) {
        m0 = (bx >= 1) ? 128 : 0;
        n0 = (bx == 2) ? 128 : 0;
    } else {
        m0 = by * 128; n0 = bx * 128;
    }
    const int tid = threadIdx.x;
    const int lane = tid & 63, w = tid >> 6;
    const int wrow = (w >> 1) * 64, wcol = (w & 1) * 64;
    const int l15 = lane & 15, lg = lane >> 4;

    f32x4 zero = {0.f, 0.f, 0.f, 0.f};
    f32x4 acc[4][4];
    #pragma unroll
    for (int mf = 0; mf < 4; ++mf)
        #pragma unroll
        for (int nf = 0; nf < 4; ++nf) acc[mf][nf] = zero;

    const int ric = lane >> 2;
    const int cc  = lane & 3;

    auto STAGE_HI = [&](int bufsel, int k0) {
        #pragma unroll
        for (int i = 0; i < 2; ++i) {
            int chunk = w * 2 + i;
            int row = chunk * 16 + ric;
            int gcol = ((cc ^ ((row >> 1) & 3)) << 3);
            GLL16(AHg + (long long)(m0 + row) * lda + (k0 + gcol), &Ahs[bufsel][chunk * 16][0]);
            GLL16(BHg + (long long)(n0 + row) * ldb + (k0 + gcol), &Bhs[bufsel][chunk * 16][0]);
        }
    };
    auto STAGE_LO = [&](int k0) {
        #pragma unroll
        for (int i = 0; i < 2; ++i) {
            int chunk = w * 2 + i;
            int row = chunk * 16 + ric;
            int gcol = ((cc ^ ((row >> 1) & 3)) << 3);
            GLL16(ALg + (long long)(m0 + row) * lda + (k0 + gcol), &Als[chunk * 16][0]);
            GLL16(BLg + (long long)(n0 + row) * ldb + (k0 + gcol), &Bls[chunk * 16][0]);
        }
    };

    const int nt = Keff / 32;
    int cur = 0;
    STAGE_HI(0, 0);

    for (int t = 0; t < nt; ++t) {
        if constexpr (NTERM == 3) STAGE_LO(t * 32);
        if (t + 1 < nt) {
            STAGE_HI(cur ^ 1, (t + 1) * 32);
            asm volatile("s_waitcnt vmcnt(4)" ::: "memory");
        } else {
            asm volatile("s_waitcnt vmcnt(0)" ::: "memory");
        }
        __builtin_amdgcn_s_barrier();

        short8 a_h[4], a_l[4];
        #pragma unroll
        for (int mf = 0; mf < 4; ++mf) {
            int ar = wrow + mf * 16 + l15;
            int ac = (lg ^ ((ar >> 1) & 3)) << 3;
            a_h[mf] = *(const short8*)&Ahs[cur][ar][ac];
            if constexpr (NTERM == 3) a_l[mf] = *(const short8*)&Als[ar][ac];
        }
        __builtin_amdgcn_s_setprio(1);
        #pragma unroll
        for (int nf = 0; nf < 4; ++nf) {
            int br = wcol + nf * 16 + l15;
            int bc = (lg ^ ((br >> 1) & 3)) << 3;
            short8 b_h = *(const short8*)&Bhs[cur][br][bc];
            if constexpr (NTERM == 3) {
                short8 b_l = *(const short8*)&Bls[br][bc];
                #pragma unroll
                for (int mf = 0; mf < 4; ++mf) {
                    acc[mf][nf] = __builtin_amdgcn_mfma_f32_16x16x32_bf16(a_h[mf], b_h, acc[mf][nf], 0, 0, 0);
                    acc[mf][nf] = __builtin_amdgcn_mfma_f32_16x16x32_bf16(a_h[mf], b_l, acc[mf][nf], 0, 0, 0);
                    acc[mf][nf] = __builtin_amdgcn_mfma_f32_16x16x32_bf16(a_l[mf], b_h, acc[mf][nf], 0, 0, 0);
                }
            } else {
                #pragma unroll
                for (int mf = 0; mf < 4; ++mf)
                    acc[mf][nf] = __builtin_amdgcn_mfma_f32_16x16x32_bf16(a_h[mf], b_h, acc[mf][nf], 0, 0, 0);
            }
        }
        __builtin_amdgcn_s_setprio(0);
        __builtin_amdgcn_s_barrier();
        cur ^= 1;
    }

    #pragma unroll
    for (int mf = 0; mf < 4; ++mf)
        #pragma unroll
        for (int nf = 0; nf < 4; ++nf) {
            int row = m0 + wrow + mf * 16 + lg * 4;
            int col = n0 + wcol + nf * 16 + l15;
            if constexpr (EPI == 0) {
                #pragma unroll
                for (int j = 0; j < 4; ++j)
                    Cf[(long long)(row + j) * ldc + col] = acc[mf][nf][j] * scale;
            } else {  // EPI 2 or 3
                unsigned p[4];
                #pragma unroll
                for (int j = 0; j < 4; ++j) p[j] = cvt_hl(acc[mf][nf][j] * scale);
                if (cvH) {   // null for members whose plain planes are dead
                    #pragma unroll
                    for (int j = 0; j < 4; ++j) {
                        CHg[(long long)(row + j) * ldc + col] = (u16)p[j];
                        CLg[(long long)(row + j) * ldc + col] = (u16)(p[j] >> 16);
                    }
                }
                if constexpr (EPI == 3) {
                    if (cvT1) {  // null for members that don't need the transpose
                        u16* CTH = (u16*)cvT1 + coT;
                        u16* CTL = (u16*)cvT2 + coT;
                        ushort4_t h, l;
                        #pragma unroll
                        for (int j = 0; j < 4; ++j) { h[j] = (u16)p[j]; l[j] = (u16)(p[j] >> 16); }
                        *(ushort4_t*)(CTH + (long long)col * ldct + row) = h;
                        *(ushort4_t*)(CTL + (long long)col * ldct + row) = l;
                    }
                }
            }
        }

    // fused finalize-loss tail (inputs were complete before this kernel launched)
    if (lossOut != nullptr && flat == 0) {
        float s = 0.0f;
        for (int i = tid; i < B_ * H_ * R_; i += 256) s += offArr[i];
        s = waveSum(s);
        if (lane == 0) red2[w] = s;
        __syncthreads();
        if (tid == 0) {
            float total = red2[0] + red2[1] + red2[2] + red2[3];
            lossOut[0] = addLossIn[0]
                       + lossAcc[0] * (1.0f / ((float)B_ * R_ * R_))
                       + total      * (1.0f / ((float)B_ * H_ * R_ * R_))
                       + lossAcc[2] * (1.0f / ((float)B_ * R_ * R_));
        }
    }
}

// ---------------- fused softmax+PV: alpha stays in LDS, z1 planes out ----------------
// grid = 8 q-tiles(32 rows) x 64 heads = 512 blocks (2/CU). Bit-identical to the old
// softmax_alpha4 + step-10 gemm_pl pair (same alpha bf16 values, same MFMA order).
__global__ __launch_bounds__(256) void softmax_pv(
    const float* __restrict__ scores,
    const u16* __restrict__ vpTH, const u16* __restrict__ vpTL,
    u16* __restrict__ z1H, u16* __restrict__ z1L,
    float* __restrict__ offArr)
{
    __shared__ u16 AH[32][264], AL[32][264];   // alpha planes (pad 8 -> 2-way conflicts, free)
    __shared__ u16 BH[64][40], BL[64][40];     // vpT K-chunk tiles (gemm_pl padding)
    const int hd = blockIdx.x >> 3;            // b*H + h
    const int qt = blockIdx.x & 7;
    const int q0 = qt * 32;
    const int b  = hd >> 3, h = hd & 7;
    const int tid = threadIdx.x;
    const int lane = tid & 63, w = tid >> 6;
    const int l15 = lane & 15, lg = lane >> 4;

    // phase 1: softmax on 32 rows (wave-per-row, 8 rows/wave), alpha -> LDS + offArr
    const float* srow = scores + ((long long)hd * 256 + q0) * 256;
    #pragma unroll
    for (int i = 0; i < 8; ++i) {
        int rr = w * 8 + i;
        float4 v = *(const float4*)(srow + (long long)rr * 256 + lane * 4);
        float mx = waveMax(fmaxf(fmaxf(v.x, v.y), fmaxf(v.z, v.w)));
        float e0 = __expf(v.x - mx), e1 = __expf(v.y - mx);
        float e2 = __expf(v.z - mx), e3 = __expf(v.w - mx);
        float inv = 1.0f / waveSum(e0 + e1 + e2 + e3);
        float a0 = e0 * inv, a1 = e1 * inv, a2 = e2 * inv, a3 = e3 * inv;
        unsigned p0 = cvt_hl(a0), p1 = cvt_hl(a1), p2 = cvt_hl(a2), p3 = cvt_hl(a3);
        ushort4_t hv, lv;
        hv[0]=(u16)p0; hv[1]=(u16)p1; hv[2]=(u16)p2; hv[3]=(u16)p3;
        lv[0]=(u16)(p0>>16); lv[1]=(u16)(p1>>16); lv[2]=(u16)(p2>>16); lv[3]=(u16)(p3>>16);
        *(ushort4_t*)&AH[rr][lane * 4] = hv;
        *(ushort4_t*)&AL[rr][lane * 4] = lv;
        int rdiag = q0 + rr;
        int c = lane * 4;
        float off = (c + 0 == rdiag ? 0.0f : a0) + (c + 1 == rdiag ? 0.0f : a1)
                  + (c + 2 == rdiag ? 0.0f : a2) + (c + 3 == rdiag ? 0.0f : a3);
        off = waveSum(off);
        if (lane == 0) offArr[(long long)hd * 256 + q0 + rr] = off;
    }

    // phase 2: z1[32,64] = alpha @ vpT-head-slice (3-term), K=256 in 32-chunks
    const long long llRHD = (long long)R_ * HD_;
    const u16* BHg = vpTH + (long long)b * llRHD + (long long)h * 64 * R_;
    const u16* BLg = vpTL + (long long)b * llRHD + (long long)h * 64 * R_;
    f32x4 zero = {0.f, 0.f, 0.f, 0.f};
    f32x4 acc[2];
    acc[0] = zero; acc[1] = zero;
    for (int k0 = 0; k0 < 256; k0 += 32) {
        {   // stage B tile [64 rows][32 K] (hi+lo)
            int row = tid >> 2, kc = (tid & 3) << 3;
            long long off = (long long)row * R_ + (k0 + kc);
            *(ushort8*)&BH[row][kc] = *(const ushort8*)(BHg + off);
            *(ushort8*)&BL[row][kc] = *(const ushort8*)(BLg + off);
        }
        __syncthreads();   // also guards phase-1 alpha LDS writes on first iteration

        short8 a_h[2], a_l[2];
        #pragma unroll
        for (int mf = 0; mf < 2; ++mf) {
            a_h[mf] = *(const short8*)&AH[mf * 16 + l15][k0 + lg * 8];
            a_l[mf] = *(const short8*)&AL[mf * 16 + l15][k0 + lg * 8];
        }
        short8 b_h = *(const short8*)&BH[w * 16 + l15][lg * 8];
        short8 b_l = *(const short8*)&BL[w * 16 + l15][lg * 8];
        #pragma unroll
        for (int mf = 0; mf < 2; ++mf) {
            acc[mf] = __builtin_amdgcn_mfma_f32_16x16x32_bf16(a_h[mf], b_h, acc[mf], 0, 0, 0);
            acc[mf] = __builtin_amdgcn_mfma_f32_16x16x32_bf16(a_h[mf], b_l, acc[mf], 0, 0, 0);
            acc[mf] = __builtin_amdgcn_mfma_f32_16x16x32_bf16(a_l[mf], b_h, acc[mf], 0, 0, 0);
        }
        __syncthreads();
    }

    // epilogue: z1 planes (EPI=2 layout of the old step 10)
    u16* CH = z1H + (long long)b * llRHD + (long long)h * 64;
    u16* CL = z1L + (long long)b * llRHD + (long long)h * 64;
    #pragma unroll
    for (int mf = 0; mf < 2; ++mf) {
        int lrow = mf * 16 + lg * 4;
        int lcol = w * 16 + l15;
        #pragma unroll
        for (int j = 0; j < 4; ++j) {
            unsigned p = cvt_hl(acc[mf][j]);
            CH[(long long)(q0 + lrow + j) * HD_ + lcol] = (u16)p;
            CL[(long long)(q0 + lrow + j) * HD_ + lcol] = (u16)(p >> 16);
        }
    }
}

// ---------------- merged reduce: loss (both Grams, triangular) + qkv split-K ----------------
#define KS_ 4
#define NKS6_ 2
// blocks [0, 1024): loss reduce; blocks [1024, 1024 + 3*T/1024): qkv reduce
__global__ __launch_bounds__(256) void reduce_all(
    const float* __restrict__ G1, const float* __restrict__ G2,
    int nks, float* __restrict__ lossBase,
    const float* __restrict__ Cpart, Ptr3 dstH, Ptr3 dstL)
{
    __shared__ float red[4];
    int lane = threadIdx.x & 63, wid = threadIdx.x >> 6;
    if (blockIdx.x < 1024) {
        const long long N = (long long)B_ * R_ * R_;
        int seg = blockIdx.x >> 9;                 // 0 or 1 (512 blocks each)
        const float* G = seg ? G2 : G1;
        float* lossDst = lossBase + (seg ? 2 : 0);
        long long i4 = ((long long)(blockIdx.x & 511) * 256 + threadIdx.x) << 2;
        float s = 0.0f;
        if (i4 < N) {
            int e = (int)(i4 & (long long)(R_ * R_ - 1));
            int row = e >> 8, c0 = e & 255;
            // upper-right block (row<128, col>=128) never computed: lower mirror counts x2.
            if (!(row < 128 && c0 >= 128)) {
                float4 g = make_float4(0.f, 0.f, 0.f, 0.f);
                for (int ks = 0; ks < nks; ++ks) {
                    float4 v = *(const float4*)(G + (long long)ks * N + i4);
                    g.x += v.x; g.y += v.y; g.z += v.z; g.w += v.w;
                }
                float wgt = (row >= 128 && c0 < 128) ? 2.0f : 1.0f;
                if (row != c0 + 0) s += wgt * g.x * g.x;
                if (row != c0 + 1) s += wgt * g.y * g.y;
                if (row != c0 + 2) s += wgt * g.z * g.z;
                if (row != c0 + 3) s += wgt * g.w * g.w;
            }
        }
        #pragma unroll
        for (int o = 32; o; o >>= 1) s += __shfl_down(s, o, 64);
        if (lane == 0) red[wid] = s;
        __syncthreads();
        if (threadIdx.x == 0) atomicAdd(lossDst, red[0] + red[1] + red[2] + red[3]);
    } else {
        const long long T = (long long)B_ * R_ * C_;
        long long i4 = (long long)(blockIdx.x - 1024) * 256 + threadIdx.x;
        if (i4 >= 3 * (T >> 2)) return;
        int member = (int)(i4 / (T >> 2));
        long long rem = (i4 - (long long)member * (T >> 2)) << 2;
        float4 a = *(const float4*)(Cpart + (long long)member * T + rem);
        #pragma unroll
        for (int ks = 1; ks < NKS6_; ++ks) {
            float4 b = *(const float4*)(Cpart + (long long)ks * 3 * T + (long long)member * T + rem);
            a.x += b.x; a.y += b.y; a.z += b.z; a.w += b.w;
        }
        unsigned q0 = cvt_hl(a.x), q1 = cvt_hl(a.y), q2 = cvt_hl(a.z), q3 = cvt_hl(a.w);
        ushort4_t h, l;
        h[0]=(u16)q0; h[1]=(u16)q1; h[2]=(u16)q2; h[3]=(u16)q3;
        l[0]=(u16)(q0>>16); l[1]=(u16)(q1>>16); l[2]=(u16)(q2>>16); l[3]=(u16)(q3>>16);
        u16* dH = (u16*)(member == 0 ? dstH.p0 : member == 1 ? dstH.p1 : dstH.p2);
        u16* dL = (u16*)(member == 0 ? dstL.p0 : member == 1 ? dstL.p1 : dstL.p2);
        *(ushort4_t*)(dH + rem) = h;
        *(ushort4_t*)(dL + rem) = l;
    }
}

// ---------------- transpose kernels ----------------
__global__ __launch_bounds__(256) void xpose_f32p3(
    Ptr3 src, Ptr3 dstH, Ptr3 dstL,
    int M, int N, long long ibs, long long obs, int divz)
{
    __shared__ float S[64][65];
    int z = blockIdx.z;
    int m = z / divz, b = z - m * divz;
    const float* ip = (const float*)(m == 0 ? src.p0 : m == 1 ? src.p1 : src.p2)
                      + (long long)b * ibs;
    u16* opH = (u16*)(m == 0 ? dstH.p0 : m == 1 ? dstH.p1 : dstH.p2) + (long long)b * obs;
    u16* opL = (u16*)(m == 0 ? dstL.p0 : m == 1 ? dstL.p1 : dstL.p2) + (long long)b * obs;
    int n0 = blockIdx.x * 64, m0 = blockIdx.y * 64;
    int t = threadIdx.x;
    int c4 = (t & 15) << 2, rq = t >> 4;
    #pragma unroll
    for (int p = 0; p < 4; ++p) {
        int r = p * 16 + rq;
        float4 v = *(const float4*)(ip + (long long)(m0 + r) * N + n0 + c4);
        S[r][c4+0]=v.x; S[r][c4+1]=v.y; S[r][c4+2]=v.z; S[r][c4+3]=v.w;
    }
    __syncthreads();
    #pragma unroll
    for (int p = 0; p < 4; ++p) {
        int nr = p * 16 + rq;
        unsigned q0 = cvt_hl(S[c4+0][nr]), q1 = cvt_hl(S[c4+1][nr]);
        unsigned q2 = cvt_hl(S[c4+2][nr]), q3 = cvt_hl(S[c4+3][nr]);
        ushort4_t h, l;
        h[0]=(u16)q0; h[1]=(u16)q1; h[2]=(u16)q2; h[3]=(u16)q3;
        l[0]=(u16)(q0>>16); l[1]=(u16)(q1>>16); l[2]=(u16)(q2>>16); l[3]=(u16)(q3>>16);
        long long ob = (long long)(n0 + nr) * M + m0 + c4;
        *(ushort4_t*)(opH + ob) = h;
        *(ushort4_t*)(opL + ob) = l;
    }
}

__global__ __launch_bounds__(256) void xpose_u16p(
    const u16* __restrict__ inH, const u16* __restrict__ inL,
    u16* __restrict__ outH, u16* __restrict__ outL,
    int M, int N, long long ibs, long long obs)
{
    __shared__ u16 SH[64][66], SL[64][66];
    const u16* ipH = inH + (long long)blockIdx.z * ibs;
    const u16* ipL = inL + (long long)blockIdx.z * ibs;
    u16* opH = outH + (long long)blockIdx.z * obs;
    u16* opL = outL + (long long)blockIdx.z * obs;
    int n0 = blockIdx.x * 64, m0 = blockIdx.y * 64;
    int t = threadIdx.x;
    int c4 = (t & 15) << 2, rq = t >> 4;
    #pragma unroll
    for (int p = 0; p < 4; ++p) {
        int r = p * 16 + rq;
        long long ib = (long long)(m0 + r) * N + n0 + c4;
        ushort4_t vh = *(const ushort4_t*)(ipH + ib);
        ushort4_t vl = *(const ushort4_t*)(ipL + ib);
        SH[r][c4+0]=vh[0]; SH[r][c4+1]=vh[1]; SH[r][c4+2]=vh[2]; SH[r][c4+3]=vh[3];
        SL[r][c4+0]=vl[0]; SL[r][c4+1]=vl[1]; SL[r][c4+2]=vl[2]; SL[r][c4+3]=vl[3];
    }
    __syncthreads();
    #pragma unroll
    for (int p = 0; p < 4; ++p) {
        int nr = p * 16 + rq;
        ushort4_t h, l;
        h[0]=SH[c4+0][nr]; h[1]=SH[c4+1][nr]; h[2]=SH[c4+2][nr]; h[3]=SH[c4+3][nr];
        l[0]=SL[c4+0][nr]; l[1]=SL[c4+1][nr]; l[2]=SL[c4+2][nr]; l[3]=SL[c4+3][nr];
        long long ob = (long long)(n0 + nr) * M + m0 + c4;
        *(ushort4_t*)(opH + ob) = h;
        *(ushort4_t*)(opL + ob) = l;
    }
}

// fused: all five weights -> hi/lo planes in one launch; block 0 also zeroes loss accumulators.
__global__ __launch_bounds__(256) void conv_planes5(
    const float* __restrict__ s0, const float* __restrict__ s1, const float* __restrict__ s2,
    const float* __restrict__ s3, const float* __restrict__ s4,
    u16* h0, u16* l0, u16* h1, u16* l1, u16* h2, u16* l2,
    u16* h3, u16* l3, u16* h4, u16* l4,
    float* __restrict__ lossZero)
{
    if (blockIdx.x == 0 && threadIdx.x < 3) lossZero[threadIdx.x] = 0.0f;
    const int N0 = 32768, NW = 65536;
    int i = blockIdx.x * 256 + threadIdx.x;
    if (i >= N0 + 4 * NW) return;
    const float* s; u16* h; u16* l; int off;
    if (i < N0) { s = s0; h = h0; l = l0; off = i; }
    else {
        int j = i - N0, seg = j / NW;
        off = j - seg * NW;
        s = seg == 0 ? s1 : seg == 1 ? s2 : seg == 2 ? s3 : s4;
        h = seg == 0 ? h1 : seg == 1 ? h2 : seg == 2 ? h3 : h4;
        l = seg == 0 ? l1 : seg == 1 ? l2 : seg == 2 ? l3 : l4;
    }
    float4 v = ((const float4*)s)[off];
    unsigned p0 = cvt_hl(v.x), p1 = cvt_hl(v.y), p2 = cvt_hl(v.z), p3 = cvt_hl(v.w);
    ushort4_t hv, lv;
    hv[0]=(u16)p0; hv[1]=(u16)p1; hv[2]=(u16)p2; hv[3]=(u16)p3;
    lv[0]=(u16)(p0>>16); lv[1]=(u16)(p1>>16); lv[2]=(u16)(p2>>16); lv[3]=(u16)(p3>>16);
    ((ushort4_t*)h)[off] = hv;
    ((ushort4_t*)l)[off] = lv;
}

// merged: blocks [0, B*R) do the LT softmax (rows of pScoreT, len L);
// blocks [B*R, B*R + B*L/4) do the R softmax, 4 rows/block, one wave per row.
__global__ __launch_bounds__(256) void softmax_both(
    const float* __restrict__ pT, const float* __restrict__ pScore,
    const int* __restrict__ mask,
    u16* __restrict__ ltH, u16* __restrict__ ltL,
    u16* __restrict__ rH, u16* __restrict__ rL)
{
    __shared__ float sm[4], ss[4];
    int bxid = blockIdx.x;
    int lane = threadIdx.x & 63, wid = threadIdx.x >> 6;
    if (bxid < B_ * R_) {
        int zi = bxid;                // b*R + r
        int b = zi >> 8;
        const float* row = pT + (long long)zi * L_;
        const int* mk = mask + (long long)b * L_ * L_;   // row 0 of [L,L]
        float vals[8];
        float mx = -3.4e38f;
        #pragma unroll
        for (int i = 0; i < 8; ++i) {
            int l = threadIdx.x + i * 256;
            float v = row[l];
            if (mk[l] == 0) v = MASK_NEG;
            vals[i] = v; mx = fmaxf(mx, v);
        }
        mx = waveMax(mx);
        if (lane == 0) sm[wid] = mx;
        __syncthreads();
        mx = fmaxf(fmaxf(sm[0], sm[1]), fmaxf(sm[2], sm[3]));
        float sum = 0.0f;
        #pragma unroll
        for (int i = 0; i < 8; ++i) { float e = __expf(vals[i] - mx); vals[i] = e; sum += e; }
        sum = waveSum(sum);
        if (lane == 0) ss[wid] = sum;
        __syncthreads();
        sum = ss[0] + ss[1] + ss[2] + ss[3];
        float inv = 1.0f / sum;
        long long base = (long long)zi * L_;
        #pragma unroll
        for (int i = 0; i < 8; ++i) {
            unsigned p = cvt_hl(vals[i] * inv);
            ltH[base + threadIdx.x + i * 256] = (u16)p;
            ltL[base + threadIdx.x + i * 256] = (u16)(p >> 16);
        }
    } else {
        // R path: wave-per-row, 4 rows/block, float4 loads, no barriers
        long long z = (long long)(bxid - B_ * R_) * 4 + wid;   // b*L + l
        int b = (int)(z >> 11), l = (int)(z & 2047);
        bool pad = (mask[(long long)b * L_ * L_ + l] == 0);
        float4 v = *(const float4*)(pScore + z * R_ + lane * 4);
        if (pad) { v.x = MASK_NEG; v.y = MASK_NEG; v.z = MASK_NEG; v.w = MASK_NEG; }
        float mx = waveMax(fmaxf(fmaxf(v.x, v.y), fmaxf(v.z, v.w)));
        float e0 = __expf(v.x - mx), e1 = __expf(v.y - mx);
        float e2 = __expf(v.z - mx), e3 = __expf(v.w - mx);
        float inv = 1.0f / waveSum(e0 + e1 + e2 + e3);
        unsigned p0 = cvt_hl(e0 * inv), p1 = cvt_hl(e1 * inv);
        unsigned p2 = cvt_hl(e2 * inv), p3 = cvt_hl(e3 * inv);
        ushort4_t h, lo;
        h[0]=(u16)p0; h[1]=(u16)p1; h[2]=(u16)p2; h[3]=(u16)p3;
        lo[0]=(u16)(p0>>16); lo[1]=(u16)(p1>>16); lo[2]=(u16)(p2>>16); lo[3]=(u16)(p3>>16);
        *(ushort4_t*)(rH + z * R_ + lane * 4) = h;
        *(ushort4_t*)(rL + z * R_ + lane * 4) = lo;
    }
}

// ---------------- launch ----------------
extern "C" void kernel_launch(void* const* d_in, const int* in_sizes, int n_in,
                              void* d_out, int out_size, void* d_ws, size_t ws_size,
                              hipStream_t stream)
{
    const float* qx = (const float*)d_in[0];
    const float* kx = (const float*)d_in[1];
    const float* vx = (const float*)d_in[2];
    const float* addLossIn = (const float*)d_in[3];
    const int* mask = (const int*)d_in[4];
    const float* Wp = (const float*)d_in[5];
    const float* WQ = (const float*)d_in[6];
    const float* WK = (const float*)d_in[7];
    const float* WV = (const float*)d_in[8];
    const float* WO = (const float*)d_in[9];

    float* zOut      = (float*)d_out;                             // [B,L,C]
    float* scoresOut = zOut + (long long)B_ * L_ * C_;            // [B,H,R,R]
    float* lossOut   = scoresOut + (long long)B_ * H_ * R_ * R_;  // [1]

    const long long S = (long long)B_ * L_ * R_;    // 4,194,304
    const long long T = (long long)B_ * R_ * C_;    // 1,048,576
    u16* cur = (u16*)d_ws;
    auto takeU = [&](long long n) { u16* p = cur; cur += n; return p; };
    auto takeF = [&](long long n) { float* p = (float*)cur; cur += 2 * n; return p; };

    float* pScore   = takeF(S);          // [B,L,R]
    float* pScoreT  = takeF(S);          // [B,R,L]
    u16* pAlphaH  = takeU(S);            // [B,R,L]
    u16* pAlphaL  = takeU(S);
    u16* pAlpha_H = takeU(S);            // [B,L,R]
    u16* pAlpha_L = takeU(S);
    u16* pATH     = takeU(S);            // [B,R,L]
    u16* pATL     = takeU(S);
    u16* xTH0 = takeU(2*S); u16* xTL0 = takeU(2*S);   // [B,C,L] = 2S per plane
    u16* xTH1 = takeU(2*S); u16* xTL1 = takeU(2*S);
    u16* xTH2 = takeU(2*S); u16* xTL2 = takeU(2*S);
    const long long llRR = (long long)R_ * R_;
    float* Gpart  = takeF(2LL * KS_ * B_ * llRR);   // [2 losses][KS][B][R][R]
    float* Cpart6 = takeF((long long)NKS6_ * 3 * T); // 6b split-K partials
    u16* qrH = takeU(T); u16* qrL = takeU(T);
    u16* krH = takeU(T); u16* krL = takeU(T);
    u16* vrH = takeU(T); u16* vrL = takeU(T);
    u16* qpH = takeU(T); u16* qpL = takeU(T);
    u16* kpH = takeU(T); u16* kpL = takeU(T);
    u16* vpTH = takeU(T); u16* vpTL = takeU(T);
    u16* z1H = takeU(T); u16* z1L = takeU(T);
    u16* z2TH = takeU(T); u16* z2TL = takeU(T);
    u16* WpH = takeU((long long)R_ * C_); u16* WpL = takeU((long long)R_ * C_);
    u16* WQH = takeU((long long)HD_ * C_); u16* WQL = takeU((long long)HD_ * C_);
    u16* WKH = takeU((long long)HD_ * C_); u16* WKL = takeU((long long)HD_ * C_);
    u16* WVH = takeU((long long)HD_ * C_); u16* WVL = takeU((long long)HD_ * C_);
    u16* WOH = takeU((long long)HD_ * C_); u16* WOL = takeU((long long)HD_ * C_);
    float* loss   = takeF(16);
    float* offArr = takeF(B_ * H_ * R_);

    const Ptr3 N3{nullptr, nullptr, nullptr};
    auto P1 = [](const void* p) { return Ptr3{p, p, p}; };
    const long long llRL = (long long)R_ * L_, llLC = (long long)L_ * C_;
    const long long llRC = (long long)R_ * C_, llRHD = (long long)R_ * HD_;
    const long long llHRR = (long long)H_ * R_ * R_;
    const long long llCL = (long long)C_ * L_;
    float* Gpart2 = Gpart + (long long)KS_ * B_ * llRR;

    // 0) all weights -> planes + loss zeroing, ONE launch (1152 blocks; no memset dispatch)
    conv_planes5<<<1152, 256, 0, stream>>>(
        Wp, WQ, WK, WV, WO,
        WpH, WpL, WQH, WQL, WKH, WKL, WVH, WVL, WOH, WOL,
        loss);

    // 1) pScoreT = Wp @ vx^T AND pScore = transposed, fused epilogue (EPI=3)
    gemm_pl<64, 0, 2, 3, false><<<dim3(L_/64, R_/64, B_), 256, 0, stream>>>(
        P1(WpH), P1(WpL), P1(vx), N3, P1(pScoreT), N3,
        P1(pScore), N3, R_, llRL,
        C_, C_, C_, L_, B_,
        0, llLC, llRL, 0, 0, 0, 0, 0, 0, 1.0f);

    // 3) both softmaxes in ONE launch: 2048 LT blocks + 4096 R blocks (wave/row)
    softmax_both<<<B_ * R_ + B_ * L_ / 4, 256, 0, stream>>>(
        pScoreT, pScore, mask, pAlphaH, pAlphaL, pAlpha_H, pAlpha_L);

    // 3b) pAT = transpose(pAlpha_) planes: [L,R] -> [R,L]
    xpose_u16p<<<dim3(R_/64, L_/64, B_), 256, 0, stream>>>(
        pAlpha_H, pAlpha_L, pATH, pATL, L_, R_, llRL, llRL);

    // 4+5) both loss Grams, triangular (3 of 4 tiles), KS=4: grid (3,1,64)=192 blocks,
    //      K-chunk 512 (nt=16, deep pipeline).
    gemm_gll<0, true, 1, KS_, true><<<dim3(3, 1, 2 * B_ * KS_), 256, 0, stream>>>(
        Ptr3{pAlphaH, pATH, pATH}, N3, Ptr3{pAlphaH, pATH, pATH}, N3,
        Ptr3{Gpart, Gpart2, Gpart2}, N3,
        N3, N3, 0, 0,
        L_, L_, L_, R_, B_ * KS_,
        llRL, llRL, llRR,
        L_ / KS_, L_ / KS_, (long long)B_ * llRR, 1.0f);

    // 6) xT = transpose all three inputs -> planes [C][L] (one launch, z=24)
    //    IMMEDIATELY before 6b: producer->consumer L2 adjacency (R28 lesson)
    xpose_f32p3<<<dim3(C_/64, L_/64, 3 * B_), 256, 0, stream>>>(
        Ptr3{qx, kx, vx}, Ptr3{xTH0, xTH1, xTH2}, Ptr3{xTL0, xTL1, xTL2},
        L_, C_, llLC, llCL, B_);

    // 6b) {q,k,v}r partials = pAlpha @ x : 128^2 gll, KSPLIT=2 -> 384 blocks (nt=32)
    gemm_gll<0, true, 3, NKS6_><<<dim3(C_/128, R_/128, 3 * B_ * NKS6_), 256, 0, stream>>>(
        P1(pAlphaH), P1(pAlphaL),
        Ptr3{xTH0, xTH1, xTH2}, Ptr3{xTL0, xTL1, xTL2},
        Ptr3{Cpart6, Cpart6 + T, Cpart6 + 2 * T}, N3,
        N3, N3, 0, 0,
        L_, L_, L_, C_, B_ * NKS6_,
        llRL, llCL, llRC,
        L_ / NKS6_, L_ / NKS6_, 3 * T, 1.0f);

    // 6c) merged reduce: loss (1024 blocks) + qkv partials (3072 blocks), ONE launch
    reduce_all<<<1024 + (int)(3 * (T >> 2) / 256), 256, 0, stream>>>(
        Gpart, Gpart2, KS_, loss,
        Cpart6, Ptr3{qrH, krH, vrH}, Ptr3{qrL, krL, vrL});

    // 7) projections; vp plain planes are DEAD (only vpT is read) -> null cH for member 2;
    //    fused vpT transpose only for vp (null-guarded cT): grid (4,2,24)
    gemm_gll<3, true, 3, 1><<<dim3(HD_/128, 2, 3 * B_), 256, 0, stream>>>(
        Ptr3{qrH, krH, vrH}, Ptr3{qrL, krL, vrL},
        Ptr3{WQH, WKH, WVH}, Ptr3{WQL, WKL, WVL},
        Ptr3{qpH, kpH, nullptr}, Ptr3{qpL, kpL, nullptr},
        Ptr3{nullptr, nullptr, vpTH}, Ptr3{nullptr, nullptr, vpTL}, R_, llRHD,
        C_, C_, C_, HD_, B_,
        llRC, 0, llRHD,
        0, 0, 0, 1.0f);

    // 8) scores = qp_h @ kp_h^T / 8 : [256,256] x64, K=64 (XCD-swizzled)
    gemm_pl<64, 0, 0, 0, false><<<dim3(4, 4, 64), 256, 0, stream>>>(
        P1(qpH), P1(qpL), P1(kpH), P1(kpL), P1(scoresOut), N3,
        N3, N3, 0, 0,
        DK_, HD_, HD_, R_, 8, 64, 64, llRR, llRHD, llRHD, llHRR,
        0, 0, 0, 0.125f);

    // 9+10) fused softmax + PV: alpha stays in LDS; z1 planes + offArr out (512 blocks)
    softmax_pv<<<B_ * H_ * R_ / 32, 256, 0, stream>>>(
        scoresOut, vpTH, vpTL, z1H, z1L, offArr);

    // 11) z2T only (EPI=5): z2 plain planes are never read; batched grid (8,4,8)
    gemm_pl<64, 0, 0, 5, false><<<dim3(HD_/64, R_/64, B_), 256, 0, stream>>>(
        P1(z1H), P1(z1L), P1(WOH), P1(WOL), N3, N3,
        P1(z2TH), P1(z2TL), R_, llRC,
        HD_, HD_, HD_, C_, B_,
        llRHD, 0, llRC, 0, 0, 0, 0, 0, 0, 1.0f);

    // 12) z = pAlpha_ @ z2 + fused finalize-loss tail (block 0): no separate launch
    gemm_gll<0, false, 3, 1><<<dim3(C_/128, L_/128, B_), 256, 0, stream>>>(
        P1(pAlpha_H), P1(pAlpha_L), P1(z2TH), P1(z2TL), P1(zOut), N3,
        N3, N3, 0, 0,
        R_, R_, R_, C_, B_,
        llRL, llRC, llLC,
        0, 0, 0, 1.0f,
        addLossIn, loss, offArr, lossOut);
}